// Round 1
// baseline (1873.039 us; speedup 1.0000x reference)
//
#include <hip/hip_runtime.h>
#include <hip/hip_bf16.h>

#define NN 100000
#define NE 1600000
#define NG 2048

// ---------------- CSR build ----------------

__global__ void k_count(const int* __restrict__ dst, int* __restrict__ counts) {
    int e = blockIdx.x * 256 + threadIdx.x;
    if (e < NE) atomicAdd(&counts[dst[e]], 1);
}

__global__ void k_bsum(const int* __restrict__ counts, int* __restrict__ bsum) {
    __shared__ int s[256];
    int t = threadIdx.x;
    int i = blockIdx.x * 256 + t;
    s[t] = (i < NN) ? counts[i] : 0;
    __syncthreads();
    for (int off = 128; off > 0; off >>= 1) {
        if (t < off) s[t] += s[t + off];
        __syncthreads();
    }
    if (t == 0) bsum[blockIdx.x] = s[0];
}

__global__ void k_scan512(int* __restrict__ data, int n) {
    __shared__ int s[512];
    int t = threadIdx.x;
    int v = (t < n) ? data[t] : 0;
    s[t] = v;
    __syncthreads();
    for (int off = 1; off < 512; off <<= 1) {
        int add = (t >= off) ? s[t - off] : 0;
        __syncthreads();
        s[t] += add;
        __syncthreads();
    }
    if (t < n) data[t] = s[t] - v;  // exclusive
}

__global__ void k_scan_counts(const int* __restrict__ counts, const int* __restrict__ bsum,
                              int* __restrict__ row_ptr, int* __restrict__ cursor) {
    __shared__ int s[256];
    int t = threadIdx.x, i = blockIdx.x * 256 + t;
    int v = (i < NN) ? counts[i] : 0;
    s[t] = v;
    __syncthreads();
    for (int off = 1; off < 256; off <<= 1) {
        int add = (t >= off) ? s[t - off] : 0;
        __syncthreads();
        s[t] += add;
        __syncthreads();
    }
    int excl = s[t] - v + bsum[blockIdx.x];
    if (i < NN) { row_ptr[i] = excl; cursor[i] = excl; }
    if (i == NN - 1) row_ptr[NN] = excl + v;
}

__global__ void k_fill(const int* __restrict__ src, const int* __restrict__ dst,
                       const float* __restrict__ ea, int* __restrict__ cursor,
                       float4* __restrict__ csr) {
    int e = blockIdx.x * 256 + threadIdx.x;
    if (e >= NE) return;
    int d = dst[e];
    int p = atomicAdd(&cursor[d], 1);
    csr[p] = make_float4(__int_as_float(src[e]), ea[3 * e], ea[3 * e + 1], ea[3 * e + 2]);
}

// ---------------- Layer 1 aggregation (gather, 32 ch) ----------------
// block = 256 threads = 8 nodes x 32 lanes (lane = channel)

__global__ __launch_bounds__(256) void k_agg1(
        const float* __restrict__ x, const float4* __restrict__ csr,
        const int* __restrict__ row_ptr,
        const float* __restrict__ We1, const float* __restrict__ be1,
        float* __restrict__ agg1) {
    int lane = threadIdx.x & 31;
    int node = blockIdx.x * 8 + (threadIdx.x >> 5);
    float w0 = We1[lane], w1 = We1[32 + lane], w2 = We1[64 + lane], b = be1[lane];
    int p0 = row_ptr[node], p1 = row_ptr[node + 1];
    float acc = 0.f;
    for (int p = p0; p < p1; ++p) {
        float4 ed = csr[p];
        int s = __float_as_int(ed.x);
        float el = fmaf(ed.y, w0, fmaf(ed.z, w1, fmaf(ed.w, w2, b)));
        acc += fmaxf(x[s * 32 + lane] + el, 0.f);
    }
    agg1[node * 32 + lane] = acc;
}

// ---------------- Layer 2 aggregation (gather, 128 ch) ----------------
// block = 256 threads = 2 nodes x 128 lanes

__global__ __launch_bounds__(256) void k_agg2(
        const float* __restrict__ h1, const float4* __restrict__ csr,
        const int* __restrict__ row_ptr,
        const float* __restrict__ We2, const float* __restrict__ be2,
        float* __restrict__ agg2) {
    int lane = threadIdx.x & 127;
    int node = blockIdx.x * 2 + (threadIdx.x >> 7);
    float w0 = We2[lane], w1 = We2[128 + lane], w2 = We2[256 + lane], b = be2[lane];
    int p0 = row_ptr[node], p1 = row_ptr[node + 1];
    float acc = 0.f;
    for (int p = p0; p < p1; ++p) {
        float4 ed = csr[p];
        int s = __float_as_int(ed.x);
        float el = fmaf(ed.y, w0, fmaf(ed.z, w1, fmaf(ed.w, w2, b)));
        acc += fmaxf(h1[s * 128 + lane] + el, 0.f);
    }
    agg2[node * 128 + lane] = acc;
}

// ---------------- MLP 1: h1 = relu(relu((x+agg1)@W1a+b1a)@W1b+b1b) ----------------
// block = 256 threads, 32 nodes. thread: node = t>>3, 16 channels at (t&7)*16

__global__ __launch_bounds__(256) void k_mlp1(
        const float* __restrict__ x, const float* __restrict__ agg1,
        const float* __restrict__ W1a, const float* __restrict__ b1a,
        const float* __restrict__ W1b, const float* __restrict__ b1b,
        float* __restrict__ h1out) {
    __shared__ float in_s[32][36];    // 32 in-ch, padded vs bank conflicts
    __shared__ float hid_s[32][132];  // 128 hidden, padded
    int t = threadIdx.x;
    int nbase = blockIdx.x * 32;

    for (int i = t; i < 32 * 32; i += 256) {
        int n = i >> 5, c = i & 31;
        int gn = nbase + n;
        in_s[n][c] = x[gn * 32 + c] + agg1[gn * 32 + c];
    }
    __syncthreads();

    int n = t >> 3, cb = (t & 7) * 16;
    float acc[16];
#pragma unroll
    for (int j = 0; j < 16; ++j) acc[j] = b1a[cb + j];
    for (int k = 0; k < 32; ++k) {
        float iv = in_s[n][k];
        const float4* wr = (const float4*)&W1a[k * 128 + cb];
        float4 wa = wr[0], wb = wr[1], wc = wr[2], wd = wr[3];
        acc[0] = fmaf(iv, wa.x, acc[0]);  acc[1] = fmaf(iv, wa.y, acc[1]);
        acc[2] = fmaf(iv, wa.z, acc[2]);  acc[3] = fmaf(iv, wa.w, acc[3]);
        acc[4] = fmaf(iv, wb.x, acc[4]);  acc[5] = fmaf(iv, wb.y, acc[5]);
        acc[6] = fmaf(iv, wb.z, acc[6]);  acc[7] = fmaf(iv, wb.w, acc[7]);
        acc[8] = fmaf(iv, wc.x, acc[8]);  acc[9] = fmaf(iv, wc.y, acc[9]);
        acc[10] = fmaf(iv, wc.z, acc[10]); acc[11] = fmaf(iv, wc.w, acc[11]);
        acc[12] = fmaf(iv, wd.x, acc[12]); acc[13] = fmaf(iv, wd.y, acc[13]);
        acc[14] = fmaf(iv, wd.z, acc[14]); acc[15] = fmaf(iv, wd.w, acc[15]);
    }
#pragma unroll
    for (int j = 0; j < 16; ++j) hid_s[n][cb + j] = fmaxf(acc[j], 0.f);
    __syncthreads();

    float acc2[16];
#pragma unroll
    for (int j = 0; j < 16; ++j) acc2[j] = b1b[cb + j];
    for (int h = 0; h < 128; ++h) {
        float hv = hid_s[n][h];
        const float4* wr = (const float4*)&W1b[h * 128 + cb];
        float4 wa = wr[0], wb = wr[1], wc = wr[2], wd = wr[3];
        acc2[0] = fmaf(hv, wa.x, acc2[0]);  acc2[1] = fmaf(hv, wa.y, acc2[1]);
        acc2[2] = fmaf(hv, wa.z, acc2[2]);  acc2[3] = fmaf(hv, wa.w, acc2[3]);
        acc2[4] = fmaf(hv, wb.x, acc2[4]);  acc2[5] = fmaf(hv, wb.y, acc2[5]);
        acc2[6] = fmaf(hv, wb.z, acc2[6]);  acc2[7] = fmaf(hv, wb.w, acc2[7]);
        acc2[8] = fmaf(hv, wc.x, acc2[8]);  acc2[9] = fmaf(hv, wc.y, acc2[9]);
        acc2[10] = fmaf(hv, wc.z, acc2[10]); acc2[11] = fmaf(hv, wc.w, acc2[11]);
        acc2[12] = fmaf(hv, wd.x, acc2[12]); acc2[13] = fmaf(hv, wd.y, acc2[13]);
        acc2[14] = fmaf(hv, wd.z, acc2[14]); acc2[15] = fmaf(hv, wd.w, acc2[15]);
    }
    int gn = nbase + n;
    float4 o0 = make_float4(fmaxf(acc2[0], 0.f), fmaxf(acc2[1], 0.f), fmaxf(acc2[2], 0.f), fmaxf(acc2[3], 0.f));
    float4 o1 = make_float4(fmaxf(acc2[4], 0.f), fmaxf(acc2[5], 0.f), fmaxf(acc2[6], 0.f), fmaxf(acc2[7], 0.f));
    float4 o2 = make_float4(fmaxf(acc2[8], 0.f), fmaxf(acc2[9], 0.f), fmaxf(acc2[10], 0.f), fmaxf(acc2[11], 0.f));
    float4 o3 = make_float4(fmaxf(acc2[12], 0.f), fmaxf(acc2[13], 0.f), fmaxf(acc2[14], 0.f), fmaxf(acc2[15], 0.f));
    float4* out4 = (float4*)&h1out[gn * 128 + cb];
    out4[0] = o0; out4[1] = o1; out4[2] = o2; out4[3] = o3;
}

// ---------------- MLP 2 + fused global_add_pool ----------------

__global__ __launch_bounds__(256) void k_mlp2(
        const float* __restrict__ h1, const float* __restrict__ agg2,
        const float* __restrict__ W2a, const float* __restrict__ b2a,
        const float* __restrict__ W2b, const float* __restrict__ b2b,
        const int* __restrict__ batch, float* __restrict__ pooled) {
    __shared__ float in_s[32][132];
    __shared__ float hid_s[32][132];
    __shared__ int bidx_s[32];
    int t = threadIdx.x;
    int nbase = blockIdx.x * 32;

    if (t < 32) bidx_s[t] = batch[nbase + t];
    for (int i = t; i < 32 * 32; i += 256) {   // 32 nodes x 32 float4
        int n = i >> 5, c4 = i & 31;
        int gn = nbase + n;
        float4 a = ((const float4*)h1)[gn * 32 + c4];
        float4 g = ((const float4*)agg2)[gn * 32 + c4];
        in_s[n][c4 * 4 + 0] = a.x + g.x;
        in_s[n][c4 * 4 + 1] = a.y + g.y;
        in_s[n][c4 * 4 + 2] = a.z + g.z;
        in_s[n][c4 * 4 + 3] = a.w + g.w;
    }
    __syncthreads();

    int n = t >> 3, cb = (t & 7) * 16;
    float acc[16];
#pragma unroll
    for (int j = 0; j < 16; ++j) acc[j] = b2a[cb + j];
    for (int k = 0; k < 128; ++k) {
        float iv = in_s[n][k];
        const float4* wr = (const float4*)&W2a[k * 128 + cb];
        float4 wa = wr[0], wb = wr[1], wc = wr[2], wd = wr[3];
        acc[0] = fmaf(iv, wa.x, acc[0]);  acc[1] = fmaf(iv, wa.y, acc[1]);
        acc[2] = fmaf(iv, wa.z, acc[2]);  acc[3] = fmaf(iv, wa.w, acc[3]);
        acc[4] = fmaf(iv, wb.x, acc[4]);  acc[5] = fmaf(iv, wb.y, acc[5]);
        acc[6] = fmaf(iv, wb.z, acc[6]);  acc[7] = fmaf(iv, wb.w, acc[7]);
        acc[8] = fmaf(iv, wc.x, acc[8]);  acc[9] = fmaf(iv, wc.y, acc[9]);
        acc[10] = fmaf(iv, wc.z, acc[10]); acc[11] = fmaf(iv, wc.w, acc[11]);
        acc[12] = fmaf(iv, wd.x, acc[12]); acc[13] = fmaf(iv, wd.y, acc[13]);
        acc[14] = fmaf(iv, wd.z, acc[14]); acc[15] = fmaf(iv, wd.w, acc[15]);
    }
#pragma unroll
    for (int j = 0; j < 16; ++j) hid_s[n][cb + j] = fmaxf(acc[j], 0.f);
    __syncthreads();

    float acc2[16];
#pragma unroll
    for (int j = 0; j < 16; ++j) acc2[j] = b2b[cb + j];
    for (int h = 0; h < 128; ++h) {
        float hv = hid_s[n][h];
        const float4* wr = (const float4*)&W2b[h * 128 + cb];
        float4 wa = wr[0], wb = wr[1], wc = wr[2], wd = wr[3];
        acc2[0] = fmaf(hv, wa.x, acc2[0]);  acc2[1] = fmaf(hv, wa.y, acc2[1]);
        acc2[2] = fmaf(hv, wa.z, acc2[2]);  acc2[3] = fmaf(hv, wa.w, acc2[3]);
        acc2[4] = fmaf(hv, wb.x, acc2[4]);  acc2[5] = fmaf(hv, wb.y, acc2[5]);
        acc2[6] = fmaf(hv, wb.z, acc2[6]);  acc2[7] = fmaf(hv, wb.w, acc2[7]);
        acc2[8] = fmaf(hv, wc.x, acc2[8]);  acc2[9] = fmaf(hv, wc.y, acc2[9]);
        acc2[10] = fmaf(hv, wc.z, acc2[10]); acc2[11] = fmaf(hv, wc.w, acc2[11]);
        acc2[12] = fmaf(hv, wd.x, acc2[12]); acc2[13] = fmaf(hv, wd.y, acc2[13]);
        acc2[14] = fmaf(hv, wd.z, acc2[14]); acc2[15] = fmaf(hv, wd.w, acc2[15]);
    }
    // h2 tile back into in_s (done with inputs)
#pragma unroll
    for (int j = 0; j < 16; ++j) in_s[n][cb + j] = fmaxf(acc2[j], 0.f);
    __syncthreads();

    // fused pool: batch is sorted -> run-length reduce over the 32 nodes
    if (t < 128) {
        int c = t;
        float run = 0.f;
        int cur = bidx_s[0];
        for (int i = 0; i < 32; ++i) {
            int b = bidx_s[i];
            if (b != cur) { atomicAdd(&pooled[cur * 128 + c], run); run = 0.f; cur = b; }
            run += in_s[i][c];
        }
        atomicAdd(&pooled[cur * 128 + c], run);
    }
}

// ---------------- Readout: relu(pooled@Wm1+bm1)@Wm2+bm2 ----------------

__global__ __launch_bounds__(128) void k_readout(
        const float* __restrict__ pooled, const float* __restrict__ Wm1,
        const float* __restrict__ bm1, const float* __restrict__ Wm2,
        const float* __restrict__ bm2, float* __restrict__ out) {
    __shared__ float row[128];
    __shared__ float red[128];
    int g = blockIdx.x, t = threadIdx.x;
    row[t] = pooled[g * 128 + t];
    __syncthreads();
    float acc = bm1[t];
    for (int c = 0; c < 128; ++c) acc = fmaf(row[c], Wm1[c * 128 + t], acc);
    float term = fmaxf(acc, 0.f) * Wm2[t];
    red[t] = term;
    __syncthreads();
    for (int off = 64; off > 0; off >>= 1) {
        if (t < off) red[t] += red[t + off];
        __syncthreads();
    }
    if (t == 0) out[g] = red[0] + bm2[0];
}

// ---------------- Launch ----------------

extern "C" void kernel_launch(void* const* d_in, const int* in_sizes, int n_in,
                              void* d_out, int out_size, void* d_ws, size_t ws_size,
                              hipStream_t stream) {
    const float* x    = (const float*)d_in[0];
    const int* eidx   = (const int*)d_in[1];
    const float* ea   = (const float*)d_in[2];
    const int* batch  = (const int*)d_in[3];
    const float* We1  = (const float*)d_in[4];
    const float* be1  = (const float*)d_in[5];
    const float* W1a  = (const float*)d_in[6];
    const float* b1a  = (const float*)d_in[7];
    const float* W1b  = (const float*)d_in[8];
    const float* b1b  = (const float*)d_in[9];
    const float* We2  = (const float*)d_in[10];
    const float* be2  = (const float*)d_in[11];
    const float* W2a  = (const float*)d_in[12];
    const float* b2a  = (const float*)d_in[13];
    const float* W2b  = (const float*)d_in[14];
    const float* b2b  = (const float*)d_in[15];
    const float* Wm1  = (const float*)d_in[16];
    const float* bm1  = (const float*)d_in[17];
    const float* Wm2  = (const float*)d_in[18];
    const float* bm2  = (const float*)d_in[19];
    float* out = (float*)d_out;

    const int* src = eidx;
    const int* dst = eidx + NE;

    char* w = (char*)d_ws;
    auto alloc = [&](size_t bytes) { void* p = (void*)w; w += (bytes + 255) & ~(size_t)255; return p; };
    int* counts    = (int*)alloc(NN * 4);
    int* row_ptr   = (int*)alloc((NN + 1) * 4);
    int* cursor    = (int*)alloc(NN * 4);
    int* bsum      = (int*)alloc(512 * 4);
    float4* csr    = (float4*)alloc((size_t)NE * 16);
    float* agg1    = (float*)alloc((size_t)NN * 32 * 4);
    float* h1      = (float*)alloc((size_t)NN * 128 * 4);
    float* agg2    = (float*)alloc((size_t)NN * 128 * 4);
    float* pooled  = (float*)alloc((size_t)NG * 128 * 4);

    hipMemsetAsync(counts, 0, NN * 4, stream);
    hipMemsetAsync(pooled, 0, (size_t)NG * 128 * 4, stream);

    const int EB = (NE + 255) / 256;       // 6250
    const int NB = (NN + 255) / 256;       // 391

    k_count<<<EB, 256, 0, stream>>>(dst, counts);
    k_bsum<<<NB, 256, 0, stream>>>(counts, bsum);
    k_scan512<<<1, 512, 0, stream>>>(bsum, NB);
    k_scan_counts<<<NB, 256, 0, stream>>>(counts, bsum, row_ptr, cursor);
    k_fill<<<EB, 256, 0, stream>>>(src, dst, ea, cursor, csr);

    k_agg1<<<NN / 8, 256, 0, stream>>>(x, csr, row_ptr, We1, be1, agg1);
    k_mlp1<<<NN / 32, 256, 0, stream>>>(x, agg1, W1a, b1a, W1b, b1b, h1);
    k_agg2<<<NN / 2, 256, 0, stream>>>(h1, csr, row_ptr, We2, be2, agg2);
    k_mlp2<<<NN / 32, 256, 0, stream>>>(h1, agg2, W2a, b2a, W2b, b2b, batch, pooled);
    k_readout<<<NG, 128, 0, stream>>>(pooled, Wm1, bm1, Wm2, bm2, out);
}

// Round 4
// 773.820 us; speedup vs baseline: 2.4205x; 2.4205x over previous
//
#include <hip/hip_runtime.h>
#include <hip/hip_bf16.h>

#define NN 100000
#define NE 1600000
#define NG 2048

typedef __attribute__((ext_vector_type(8))) short short8v;
typedef __attribute__((ext_vector_type(4))) float f32x4;

__device__ inline ushort f2bf(float f) {
    // round-to-nearest-even f32 -> bf16
    uint u = __float_as_uint(f);
    uint r = (u + 0x7fffu + ((u >> 16) & 1u)) >> 16;
    return (ushort)r;
}
__device__ inline float bf2f(ushort h) {
    return __uint_as_float(((uint)h) << 16);
}

#define MFMA_BF16 __builtin_amdgcn_mfma_f32_16x16x32_bf16

// ---------------- CSR build ----------------

__global__ void k_count(const int* __restrict__ dst, int* __restrict__ counts) {
    int e = blockIdx.x * 256 + threadIdx.x;
    if (e < NE) atomicAdd(&counts[dst[e]], 1);
}

__global__ void k_bsum(const int* __restrict__ counts, int* __restrict__ bsum) {
    __shared__ int s[256];
    int t = threadIdx.x;
    int i = blockIdx.x * 256 + t;
    s[t] = (i < NN) ? counts[i] : 0;
    __syncthreads();
    for (int off = 128; off > 0; off >>= 1) {
        if (t < off) s[t] += s[t + off];
        __syncthreads();
    }
    if (t == 0) bsum[blockIdx.x] = s[0];
}

__global__ void k_scan512(int* __restrict__ data, int n) {
    __shared__ int s[512];
    int t = threadIdx.x;
    int v = (t < n) ? data[t] : 0;
    s[t] = v;
    __syncthreads();
    for (int off = 1; off < 512; off <<= 1) {
        int add = (t >= off) ? s[t - off] : 0;
        __syncthreads();
        s[t] += add;
        __syncthreads();
    }
    if (t < n) data[t] = s[t] - v;  // exclusive
}

__global__ void k_scan_counts(const int* __restrict__ counts, const int* __restrict__ bsum,
                              int* __restrict__ row_ptr, int* __restrict__ cursor) {
    __shared__ int s[256];
    int t = threadIdx.x, i = blockIdx.x * 256 + t;
    int v = (i < NN) ? counts[i] : 0;
    s[t] = v;
    __syncthreads();
    for (int off = 1; off < 256; off <<= 1) {
        int add = (t >= off) ? s[t - off] : 0;
        __syncthreads();
        s[t] += add;
        __syncthreads();
    }
    int excl = s[t] - v + bsum[blockIdx.x];
    if (i < NN) { row_ptr[i] = excl; cursor[i] = excl; }
    if (i == NN - 1) row_ptr[NN] = excl + v;
}

__global__ void k_fill(const int* __restrict__ src, const int* __restrict__ dst,
                       const float* __restrict__ ea, int* __restrict__ cursor,
                       float4* __restrict__ csr) {
    int e = blockIdx.x * 256 + threadIdx.x;
    if (e >= NE) return;
    int d = dst[e];
    int p = atomicAdd(&cursor[d], 1);
    csr[p] = make_float4(__int_as_float(src[e]), ea[3 * e], ea[3 * e + 1], ea[3 * e + 2]);
}

// ---------------- weight prep: f32 [K][C] -> bf16 hi/lo transposed [C][K] ----------------

__global__ void k_prep(const float* __restrict__ W1a, const float* __restrict__ W1b,
                       const float* __restrict__ W2a, const float* __restrict__ W2b,
                       ushort* __restrict__ W1a_hi, ushort* __restrict__ W1a_lo,
                       ushort* __restrict__ W1b_hi, ushort* __restrict__ W1b_lo,
                       ushort* __restrict__ W2a_hi, ushort* __restrict__ W2a_lo,
                       ushort* __restrict__ W2b_hi, ushort* __restrict__ W2b_lo) {
    int i = blockIdx.x * 256 + threadIdx.x;
    float v; ushort* ph; ushort* pl; int idx;
    if (i < 4096) {                       // W1a: 32x128
        int k = i >> 7, c = i & 127;
        v = W1a[i]; ph = W1a_hi; pl = W1a_lo; idx = c * 32 + k;
    } else if (i < 20480) {               // W1b: 128x128
        int j = i - 4096; int k = j >> 7, c = j & 127;
        v = W1b[j]; ph = W1b_hi; pl = W1b_lo; idx = c * 128 + k;
    } else if (i < 36864) {               // W2a
        int j = i - 20480; int k = j >> 7, c = j & 127;
        v = W2a[j]; ph = W2a_hi; pl = W2a_lo; idx = c * 128 + k;
    } else if (i < 53248) {               // W2b
        int j = i - 36864; int k = j >> 7, c = j & 127;
        v = W2b[j]; ph = W2b_hi; pl = W2b_lo; idx = c * 128 + k;
    } else return;
    ushort h = f2bf(v);
    ph[idx] = h;
    pl[idx] = f2bf(v - bf2f(h));
}

// ---------------- Layer 1 aggregation (gather, 32 ch) ----------------

__global__ __launch_bounds__(256) void k_agg1(
        const float* __restrict__ x, const float4* __restrict__ csr,
        const int* __restrict__ row_ptr,
        const float* __restrict__ We1, const float* __restrict__ be1,
        float* __restrict__ agg1) {
    int lane = threadIdx.x & 31;
    int node = blockIdx.x * 8 + (threadIdx.x >> 5);
    float w0 = We1[lane], w1 = We1[32 + lane], w2 = We1[64 + lane], b = be1[lane];
    int p0 = row_ptr[node], p1 = row_ptr[node + 1];
    float acc = 0.f;
    for (int p = p0; p < p1; ++p) {
        float4 ed = csr[p];
        int s = __float_as_int(ed.x);
        float el = fmaf(ed.y, w0, fmaf(ed.z, w1, fmaf(ed.w, w2, b)));
        acc += fmaxf(x[s * 32 + lane] + el, 0.f);
    }
    agg1[node * 32 + lane] = acc;
}

// ---------------- Layer 2 aggregation (gather, 128 ch) ----------------

__global__ __launch_bounds__(256) void k_agg2(
        const float* __restrict__ h1, const float4* __restrict__ csr,
        const int* __restrict__ row_ptr,
        const float* __restrict__ We2, const float* __restrict__ be2,
        float* __restrict__ agg2) {
    int lane = threadIdx.x & 127;
    int node = blockIdx.x * 2 + (threadIdx.x >> 7);
    float w0 = We2[lane], w1 = We2[128 + lane], w2 = We2[256 + lane], b = be2[lane];
    int p0 = row_ptr[node], p1 = row_ptr[node + 1];
    float acc = 0.f;
    for (int p = p0; p < p1; ++p) {
        float4 ed = csr[p];
        int s = __float_as_int(ed.x);
        float el = fmaf(ed.y, w0, fmaf(ed.z, w1, fmaf(ed.w, w2, b)));
        acc += fmaxf(h1[s * 128 + lane] + el, 0.f);
    }
    agg2[node * 128 + lane] = acc;
}

// ---------------- MLP 1 (split-bf16 MFMA): h1 = relu(relu((x+agg1)@W1a+b1a)@W1b+b1b) ----
// 32 nodes/block, 4 waves; wave w owns out-ch [w*32, w*32+32), m-tiles 0..1.
// Split precision: v = hi + lo (both bf16); a.w ~ ah*wh + al*wh + ah*wl.
// LDS: A_hi/A_lo [32][40], W region 20480 B (phase A: hi+lo [128][40]; phase B: [128][72] panel),
//      H_hi/H_lo [32][136]. All strides are multiples of 16 B.

#define M1_AHI 0
#define M1_ALO 2560
#define M1_W   5120
#define M1_HHI 25600
#define M1_HLO 34304
#define M1_SMEM 43008

__global__ __launch_bounds__(256) void k_mlp1(
        const float* __restrict__ x, const float* __restrict__ agg1,
        const ushort* __restrict__ W1a_hi, const ushort* __restrict__ W1a_lo,
        const float* __restrict__ b1a,
        const ushort* __restrict__ W1b_hi, const ushort* __restrict__ W1b_lo,
        const float* __restrict__ b1b,
        float* __restrict__ h1out) {
    __shared__ __align__(16) char smem[M1_SMEM];
    ushort* A_hi = (ushort*)(smem + M1_AHI);   // [32][40]
    ushort* A_lo = (ushort*)(smem + M1_ALO);   // [32][40]
    ushort* W_s  = (ushort*)(smem + M1_W);     // 10240 ushorts
    ushort* H_hi = (ushort*)(smem + M1_HHI);   // [32][136]
    ushort* H_lo = (ushort*)(smem + M1_HLO);   // [32][136]
    int t = threadIdx.x;
    int nbase = blockIdx.x * 32;

    // stage A = x + agg1, split hi/lo
    if (t < 128) {
        int n = t >> 2, cc = (t & 3) * 8;
        int gn = nbase + n;
        short8v vh = {0,0,0,0,0,0,0,0}, vl = {0,0,0,0,0,0,0,0};
        if (gn < NN) {
            const float4* xp = (const float4*)&x[gn * 32 + cc];
            const float4* gp = (const float4*)&agg1[gn * 32 + cc];
            float s[8];
            float4 x0 = xp[0], x1 = xp[1], g0 = gp[0], g1 = gp[1];
            s[0]=x0.x+g0.x; s[1]=x0.y+g0.y; s[2]=x0.z+g0.z; s[3]=x0.w+g0.w;
            s[4]=x1.x+g1.x; s[5]=x1.y+g1.y; s[6]=x1.z+g1.z; s[7]=x1.w+g1.w;
#pragma unroll
            for (int j = 0; j < 8; ++j) {
                ushort h = f2bf(s[j]);
                vh[j] = (short)h;
                vl[j] = (short)f2bf(s[j] - bf2f(h));
            }
        }
        *(short8v*)&A_hi[n * 40 + cc] = vh;
        *(short8v*)&A_lo[n * 40 + cc] = vl;
    }
    // stage W1a hi (first 5120 ush) + lo (next 5120): [128][40] each
    for (int i = t; i < 1024; i += 256) {
        int half = i >> 9, j = i & 511;
        int r = j >> 2, ko = (j & 3) * 8;
        const ushort* srcw = half ? W1a_lo : W1a_hi;
        *(short8v*)&W_s[half * 5120 + r * 40 + ko] = *(const short8v*)&srcw[r * 32 + ko];
    }
    __syncthreads();

    int w = t >> 6, l = t & 63;
    int cl = l & 15, kq = l >> 4;

    f32x4 acc[2][2];
#pragma unroll
    for (int mt = 0; mt < 2; ++mt) { acc[mt][0] = f32x4{0.f,0.f,0.f,0.f}; acc[mt][1] = f32x4{0.f,0.f,0.f,0.f}; }

    // phase A: K=32, single k-step, 3-term split
    {
        int kof = kq * 8;
        short8v bh0 = *(short8v*)&W_s[(w * 32 + cl) * 40 + kof];
        short8v bh1 = *(short8v*)&W_s[(w * 32 + 16 + cl) * 40 + kof];
        short8v bl0 = *(short8v*)&W_s[5120 + (w * 32 + cl) * 40 + kof];
        short8v bl1 = *(short8v*)&W_s[5120 + (w * 32 + 16 + cl) * 40 + kof];
#pragma unroll
        for (int mt = 0; mt < 2; ++mt) {
            short8v ah = *(short8v*)&A_hi[(mt * 16 + cl) * 40 + kof];
            short8v al = *(short8v*)&A_lo[(mt * 16 + cl) * 40 + kof];
            acc[mt][0] = MFMA_BF16(ah, bh0, acc[mt][0], 0, 0, 0);
            acc[mt][0] = MFMA_BF16(al, bh0, acc[mt][0], 0, 0, 0);
            acc[mt][0] = MFMA_BF16(ah, bl0, acc[mt][0], 0, 0, 0);
            acc[mt][1] = MFMA_BF16(ah, bh1, acc[mt][1], 0, 0, 0);
            acc[mt][1] = MFMA_BF16(al, bh1, acc[mt][1], 0, 0, 0);
            acc[mt][1] = MFMA_BF16(ah, bl1, acc[mt][1], 0, 0, 0);
        }
    }
    // epilogue A -> H (bias+relu, split)
    {
        float bb0 = b1a[w * 32 + cl], bb1 = b1a[w * 32 + 16 + cl];
#pragma unroll
        for (int mt = 0; mt < 2; ++mt)
#pragma unroll
            for (int j = 0; j < 4; ++j) {
                int row = mt * 16 + kq * 4 + j;
                float v0 = fmaxf(acc[mt][0][j] + bb0, 0.f);
                float v1 = fmaxf(acc[mt][1][j] + bb1, 0.f);
                ushort h0 = f2bf(v0), h1v = f2bf(v1);
                H_hi[row * 136 + w * 32 + cl]      = h0;
                H_lo[row * 136 + w * 32 + cl]      = f2bf(v0 - bf2f(h0));
                H_hi[row * 136 + w * 32 + 16 + cl] = h1v;
                H_lo[row * 136 + w * 32 + 16 + cl] = f2bf(v1 - bf2f(h1v));
            }
    }
    __syncthreads();

    // phase B: K=128 from H, W1b in two 64-K panels; hi-pass then lo-pass per panel
#pragma unroll
    for (int mt = 0; mt < 2; ++mt) { acc[mt][0] = f32x4{0.f,0.f,0.f,0.f}; acc[mt][1] = f32x4{0.f,0.f,0.f,0.f}; }
    for (int p = 0; p < 2; ++p) {
        for (int i = t; i < 1024; i += 256) {
            int r = i >> 3, ko = (i & 7) * 8;
            *(short8v*)&W_s[r * 72 + ko] = *(const short8v*)&W1b_hi[r * 128 + p * 64 + ko];
        }
        __syncthreads();
        short8v ahk[2][2];
#pragma unroll
        for (int ksl = 0; ksl < 2; ++ksl) {
            int kofW = ksl * 32 + kq * 8;
            int kofH = p * 64 + kofW;
            short8v bh0 = *(short8v*)&W_s[(w * 32 + cl) * 72 + kofW];
            short8v bh1 = *(short8v*)&W_s[(w * 32 + 16 + cl) * 72 + kofW];
#pragma unroll
            for (int mt = 0; mt < 2; ++mt) {
                ahk[ksl][mt] = *(short8v*)&H_hi[(mt * 16 + cl) * 136 + kofH];
                short8v al   = *(short8v*)&H_lo[(mt * 16 + cl) * 136 + kofH];
                acc[mt][0] = MFMA_BF16(ahk[ksl][mt], bh0, acc[mt][0], 0, 0, 0);
                acc[mt][0] = MFMA_BF16(al, bh0, acc[mt][0], 0, 0, 0);
                acc[mt][1] = MFMA_BF16(ahk[ksl][mt], bh1, acc[mt][1], 0, 0, 0);
                acc[mt][1] = MFMA_BF16(al, bh1, acc[mt][1], 0, 0, 0);
            }
        }
        __syncthreads();
        for (int i = t; i < 1024; i += 256) {
            int r = i >> 3, ko = (i & 7) * 8;
            *(short8v*)&W_s[r * 72 + ko] = *(const short8v*)&W1b_lo[r * 128 + p * 64 + ko];
        }
        __syncthreads();
#pragma unroll
        for (int ksl = 0; ksl < 2; ++ksl) {
            int kofW = ksl * 32 + kq * 8;
            short8v bl0 = *(short8v*)&W_s[(w * 32 + cl) * 72 + kofW];
            short8v bl1 = *(short8v*)&W_s[(w * 32 + 16 + cl) * 72 + kofW];
#pragma unroll
            for (int mt = 0; mt < 2; ++mt) {
                acc[mt][0] = MFMA_BF16(ahk[ksl][mt], bl0, acc[mt][0], 0, 0, 0);
                acc[mt][1] = MFMA_BF16(ahk[ksl][mt], bl1, acc[mt][1], 0, 0, 0);
            }
        }
        __syncthreads();
    }
    // epilogue B -> h1out (f32, bias+relu)
    {
        float c0 = b1b[w * 32 + cl], c1 = b1b[w * 32 + 16 + cl];
#pragma unroll
        for (int mt = 0; mt < 2; ++mt)
#pragma unroll
            for (int j = 0; j < 4; ++j) {
                int gn = nbase + mt * 16 + kq * 4 + j;
                if (gn < NN) {
                    h1out[gn * 128 + w * 32 + cl]      = fmaxf(acc[mt][0][j] + c0, 0.f);
                    h1out[gn * 128 + w * 32 + 16 + cl] = fmaxf(acc[mt][1][j] + c1, 0.f);
                }
            }
    }
}

// ---------------- MLP 2 (split-bf16 MFMA) + fused global_add_pool ----------------
// LDS: A_hi@0, A_lo@8704 ([32][136] each); W@17408 ([128][72]); H_hi@35840, H_lo@44544;
//      batch@53248. P f32 [32][132] aliases A region after final barrier (16896 <= 17408).

#define M2_AHI 0
#define M2_ALO 8704
#define M2_W   17408
#define M2_HHI 35840
#define M2_HLO 44544
#define M2_B   53248
#define M2_SMEM 53376

__global__ __launch_bounds__(256) void k_mlp2(
        const float* __restrict__ h1, const float* __restrict__ agg2,
        const ushort* __restrict__ W2a_hi, const ushort* __restrict__ W2a_lo,
        const float* __restrict__ b2a,
        const ushort* __restrict__ W2b_hi, const ushort* __restrict__ W2b_lo,
        const float* __restrict__ b2b,
        const int* __restrict__ batch, float* __restrict__ pooled) {
    __shared__ __align__(16) char smem[M2_SMEM];
    ushort* A_hi = (ushort*)(smem + M2_AHI);
    ushort* A_lo = (ushort*)(smem + M2_ALO);
    ushort* W_s  = (ushort*)(smem + M2_W);
    ushort* H_hi = (ushort*)(smem + M2_HHI);
    ushort* H_lo = (ushort*)(smem + M2_HLO);
    int* batch_s = (int*)(smem + M2_B);
    int t = threadIdx.x;
    int nbase = blockIdx.x * 32;

    if (t < 32) batch_s[t] = (nbase + t < NN) ? batch[nbase + t] : -1;

    // stage A = h1 + agg2, split hi/lo
    for (int i = t; i < 512; i += 256) {
        int n = i >> 4, cc = (i & 15) * 8;
        int gn = nbase + n;
        short8v vh = {0,0,0,0,0,0,0,0}, vl = {0,0,0,0,0,0,0,0};
        if (gn < NN) {
            const float4* hp = (const float4*)&h1[gn * 128 + cc];
            const float4* gp = (const float4*)&agg2[gn * 128 + cc];
            float s[8];
            float4 a0 = hp[0], a1 = hp[1], g0 = gp[0], g1 = gp[1];
            s[0]=a0.x+g0.x; s[1]=a0.y+g0.y; s[2]=a0.z+g0.z; s[3]=a0.w+g0.w;
            s[4]=a1.x+g1.x; s[5]=a1.y+g1.y; s[6]=a1.z+g1.z; s[7]=a1.w+g1.w;
#pragma unroll
            for (int j = 0; j < 8; ++j) {
                ushort h = f2bf(s[j]);
                vh[j] = (short)h;
                vl[j] = (short)f2bf(s[j] - bf2f(h));
            }
        }
        *(short8v*)&A_hi[n * 136 + cc] = vh;
        *(short8v*)&A_lo[n * 136 + cc] = vl;
    }

    int w = t >> 6, l = t & 63;
    int cl = l & 15, kq = l >> 4;

    f32x4 acc[2][2];
#pragma unroll
    for (int mt = 0; mt < 2; ++mt) { acc[mt][0] = f32x4{0.f,0.f,0.f,0.f}; acc[mt][1] = f32x4{0.f,0.f,0.f,0.f}; }

    // phase A: (h1+agg2) @ W2a, two 64-K panels, hi-pass + lo-pass
    for (int p = 0; p < 2; ++p) {
        for (int i = t; i < 1024; i += 256) {
            int r = i >> 3, ko = (i & 7) * 8;
            *(short8v*)&W_s[r * 72 + ko] = *(const short8v*)&W2a_hi[r * 128 + p * 64 + ko];
        }
        __syncthreads();
        short8v ahk[2][2];
#pragma unroll
        for (int ksl = 0; ksl < 2; ++ksl) {
            int kofW = ksl * 32 + kq * 8;
            int kofA = p * 64 + kofW;
            short8v bh0 = *(short8v*)&W_s[(w * 32 + cl) * 72 + kofW];
            short8v bh1 = *(short8v*)&W_s[(w * 32 + 16 + cl) * 72 + kofW];
#pragma unroll
            for (int mt = 0; mt < 2; ++mt) {
                ahk[ksl][mt] = *(short8v*)&A_hi[(mt * 16 + cl) * 136 + kofA];
                short8v al   = *(short8v*)&A_lo[(mt * 16 + cl) * 136 + kofA];
                acc[mt][0] = MFMA_BF16(ahk[ksl][mt], bh0, acc[mt][0], 0, 0, 0);
                acc[mt][0] = MFMA_BF16(al, bh0, acc[mt][0], 0, 0, 0);
                acc[mt][1] = MFMA_BF16(ahk[ksl][mt], bh1, acc[mt][1], 0, 0, 0);
                acc[mt][1] = MFMA_BF16(al, bh1, acc[mt][1], 0, 0, 0);
            }
        }
        __syncthreads();
        for (int i = t; i < 1024; i += 256) {
            int r = i >> 3, ko = (i & 7) * 8;
            *(short8v*)&W_s[r * 72 + ko] = *(const short8v*)&W2a_lo[r * 128 + p * 64 + ko];
        }
        __syncthreads();
#pragma unroll
        for (int ksl = 0; ksl < 2; ++ksl) {
            int kofW = ksl * 32 + kq * 8;
            short8v bl0 = *(short8v*)&W_s[(w * 32 + cl) * 72 + kofW];
            short8v bl1 = *(short8v*)&W_s[(w * 32 + 16 + cl) * 72 + kofW];
#pragma unroll
            for (int mt = 0; mt < 2; ++mt) {
                acc[mt][0] = MFMA_BF16(ahk[ksl][mt], bl0, acc[mt][0], 0, 0, 0);
                acc[mt][1] = MFMA_BF16(ahk[ksl][mt], bl1, acc[mt][1], 0, 0, 0);
            }
        }
        __syncthreads();
    }
    // epilogue A -> H (bias+relu, split)
    {
        float bb0 = b2a[w * 32 + cl], bb1 = b2a[w * 32 + 16 + cl];
#pragma unroll
        for (int mt = 0; mt < 2; ++mt)
#pragma unroll
            for (int j = 0; j < 4; ++j) {
                int row = mt * 16 + kq * 4 + j;
                float v0 = fmaxf(acc[mt][0][j] + bb0, 0.f);
                float v1 = fmaxf(acc[mt][1][j] + bb1, 0.f);
                ushort h0 = f2bf(v0), h1v = f2bf(v1);
                H_hi[row * 136 + w * 32 + cl]      = h0;
                H_lo[row * 136 + w * 32 + cl]      = f2bf(v0 - bf2f(h0));
                H_hi[row * 136 + w * 32 + 16 + cl] = h1v;
                H_lo[row * 136 + w * 32 + 16 + cl] = f2bf(v1 - bf2f(h1v));
            }
    }
    __syncthreads();

    // phase B: hid @ W2b
#pragma unroll
    for (int mt = 0; mt < 2; ++mt) { acc[mt][0] = f32x4{0.f,0.f,0.f,0.f}; acc[mt][1] = f32x4{0.f,0.f,0.f,0.f}; }
    for (int p = 0; p < 2; ++p) {
        for (int i = t; i < 1024; i += 256) {
            int r = i >> 3, ko = (i & 7) * 8;
            *(short8v*)&W_s[r * 72 + ko] = *(const short8v*)&W2b_hi[r * 128 + p * 64 + ko];
        }
        __syncthreads();
        short8v ahk[2][2];
#pragma unroll
        for (int ksl = 0; ksl < 2; ++ksl) {
            int kofW = ksl * 32 + kq * 8;
            int kofH = p * 64 + kofW;
            short8v bh0 = *(short8v*)&W_s[(w * 32 + cl) * 72 + kofW];
            short8v bh1 = *(short8v*)&W_s[(w * 32 + 16 + cl) * 72 + kofW];
#pragma unroll
            for (int mt = 0; mt < 2; ++mt) {
                ahk[ksl][mt] = *(short8v*)&H_hi[(mt * 16 + cl) * 136 + kofH];
                short8v al   = *(short8v*)&H_lo[(mt * 16 + cl) * 136 + kofH];
                acc[mt][0] = MFMA_BF16(ahk[ksl][mt], bh0, acc[mt][0], 0, 0, 0);
                acc[mt][0] = MFMA_BF16(al, bh0, acc[mt][0], 0, 0, 0);
                acc[mt][1] = MFMA_BF16(ahk[ksl][mt], bh1, acc[mt][1], 0, 0, 0);
                acc[mt][1] = MFMA_BF16(al, bh1, acc[mt][1], 0, 0, 0);
            }
        }
        __syncthreads();
        for (int i = t; i < 1024; i += 256) {
            int r = i >> 3, ko = (i & 7) * 8;
            *(short8v*)&W_s[r * 72 + ko] = *(const short8v*)&W2b_lo[r * 128 + p * 64 + ko];
        }
        __syncthreads();
#pragma unroll
        for (int ksl = 0; ksl < 2; ++ksl) {
            int kofW = ksl * 32 + kq * 8;
            short8v bl0 = *(short8v*)&W_s[(w * 32 + cl) * 72 + kofW];
            short8v bl1 = *(short8v*)&W_s[(w * 32 + 16 + cl) * 72 + kofW];
#pragma unroll
            for (int mt = 0; mt < 2; ++mt) {
                acc[mt][0] = MFMA_BF16(ahk[ksl][mt], bl0, acc[mt][0], 0, 0, 0);
                acc[mt][1] = MFMA_BF16(ahk[ksl][mt], bl1, acc[mt][1], 0, 0, 0);
            }
        }
        __syncthreads();
    }
    // epilogue B -> f32 tile P (aliases A region; all A reads done), then pool
    float* P = (float*)smem;  // [32][132]
    {
        float c0 = b2b[w * 32 + cl], c1 = b2b[w * 32 + 16 + cl];
#pragma unroll
        for (int mt = 0; mt < 2; ++mt)
#pragma unroll
            for (int j = 0; j < 4; ++j) {
                int row = mt * 16 + kq * 4 + j;
                P[row * 132 + w * 32 + cl]      = fmaxf(acc[mt][0][j] + c0, 0.f);
                P[row * 132 + w * 32 + 16 + cl] = fmaxf(acc[mt][1][j] + c1, 0.f);
            }
    }
    __syncthreads();

    // pool: batch sorted; two halves of 16 nodes, run-length + atomics
    {
        int c = t & 127, half = t >> 7;
        int i0 = half * 16;
        float run = 0.f;
        int cur = batch_s[i0];
        if (cur >= 0) {
            for (int i = i0; i < i0 + 16; ++i) {
                int b = batch_s[i];
                if (b < 0) break;
                if (b != cur) { atomicAdd(&pooled[cur * 128 + c], run); run = 0.f; cur = b; }
                run += P[i * 132 + c];
            }
            atomicAdd(&pooled[cur * 128 + c], run);
        }
    }
}

// ---------------- Readout: relu(pooled@Wm1+bm1)@Wm2+bm2 ----------------

__global__ __launch_bounds__(128) void k_readout(
        const float* __restrict__ pooled, const float* __restrict__ Wm1,
        const float* __restrict__ bm1, const float* __restrict__ Wm2,
        const float* __restrict__ bm2, float* __restrict__ out) {
    __shared__ float row[128];
    __shared__ float red[128];
    int g = blockIdx.x, t = threadIdx.x;
    row[t] = pooled[g * 128 + t];
    __syncthreads();
    float acc = bm1[t];
    for (int c = 0; c < 128; ++c) acc = fmaf(row[c], Wm1[c * 128 + t], acc);
    float term = fmaxf(acc, 0.f) * Wm2[t];
    red[t] = term;
    __syncthreads();
    for (int off = 64; off > 0; off >>= 1) {
        if (t < off) red[t] += red[t + off];
        __syncthreads();
    }
    if (t == 0) out[g] = red[0] + bm2[0];
}

// ---------------- Launch ----------------

extern "C" void kernel_launch(void* const* d_in, const int* in_sizes, int n_in,
                              void* d_out, int out_size, void* d_ws, size_t ws_size,
                              hipStream_t stream) {
    const float* x    = (const float*)d_in[0];
    const int* eidx   = (const int*)d_in[1];
    const float* ea   = (const float*)d_in[2];
    const int* batch  = (const int*)d_in[3];
    const float* We1  = (const float*)d_in[4];
    const float* be1  = (const float*)d_in[5];
    const float* W1a  = (const float*)d_in[6];
    const float* b1a  = (const float*)d_in[7];
    const float* W1b  = (const float*)d_in[8];
    const float* b1b  = (const float*)d_in[9];
    const float* We2  = (const float*)d_in[10];
    const float* be2  = (const float*)d_in[11];
    const float* W2a  = (const float*)d_in[12];
    const float* b2a  = (const float*)d_in[13];
    const float* W2b  = (const float*)d_in[14];
    const float* b2b  = (const float*)d_in[15];
    const float* Wm1  = (const float*)d_in[16];
    const float* bm1  = (const float*)d_in[17];
    const float* Wm2  = (const float*)d_in[18];
    const float* bm2  = (const float*)d_in[19];
    float* out = (float*)d_out;

    const int* src = eidx;
    const int* dst = eidx + NE;

    char* w = (char*)d_ws;
    auto alloc = [&](size_t bytes) { void* p = (void*)w; w += (bytes + 255) & ~(size_t)255; return p; };
    int* counts    = (int*)alloc(NN * 4);
    int* row_ptr   = (int*)alloc((NN + 1) * 4);
    int* cursor    = (int*)alloc(NN * 4);
    int* bsum      = (int*)alloc(512 * 4);
    float4* csr    = (float4*)alloc((size_t)NE * 16);
    float* agg1    = (float*)alloc((size_t)NN * 32 * 4);
    float* h1      = (float*)alloc((size_t)NN * 128 * 4);
    float* agg2    = (float*)alloc((size_t)NN * 128 * 4);
    float* pooled  = (float*)alloc((size_t)NG * 128 * 4);
    ushort* W1a_hi = (ushort*)alloc(4096 * 2);
    ushort* W1a_lo = (ushort*)alloc(4096 * 2);
    ushort* W1b_hi = (ushort*)alloc(16384 * 2);
    ushort* W1b_lo = (ushort*)alloc(16384 * 2);
    ushort* W2a_hi = (ushort*)alloc(16384 * 2);
    ushort* W2a_lo = (ushort*)alloc(16384 * 2);
    ushort* W2b_hi = (ushort*)alloc(16384 * 2);
    ushort* W2b_lo = (ushort*)alloc(16384 * 2);

    hipMemsetAsync(counts, 0, NN * 4, stream);
    hipMemsetAsync(pooled, 0, (size_t)NG * 128 * 4, stream);

    const int EB = (NE + 255) / 256;       // 6250
    const int NB = (NN + 255) / 256;       // 391
    const int MB = (NN + 31) / 32;         // 3125

    k_prep<<<208, 256, 0, stream>>>(W1a, W1b, W2a, W2b,
                                    W1a_hi, W1a_lo, W1b_hi, W1b_lo,
                                    W2a_hi, W2a_lo, W2b_hi, W2b_lo);
    k_count<<<EB, 256, 0, stream>>>(dst, counts);
    k_bsum<<<NB, 256, 0, stream>>>(counts, bsum);
    k_scan512<<<1, 512, 0, stream>>>(bsum, NB);
    k_scan_counts<<<NB, 256, 0, stream>>>(counts, bsum, row_ptr, cursor);
    k_fill<<<EB, 256, 0, stream>>>(src, dst, ea, cursor, csr);

    k_agg1<<<NN / 8, 256, 0, stream>>>(x, csr, row_ptr, We1, be1, agg1);
    k_mlp1<<<MB, 256, 0, stream>>>(x, agg1, W1a_hi, W1a_lo, b1a, W1b_hi, W1b_lo, b1b, h1);
    k_agg2<<<NN / 2, 256, 0, stream>>>(h1, csr, row_ptr, We2, be2, agg2);
    k_mlp2<<<MB, 256, 0, stream>>>(h1, agg2, W2a_hi, W2a_lo, b2a, W2b_hi, W2b_lo, b2b, batch, pooled);
    k_readout<<<NG, 128, 0, stream>>>(pooled, Wm1, bm1, Wm2, bm2, out);
}

// Round 5
// 593.153 us; speedup vs baseline: 3.1578x; 1.3046x over previous
//
#include <hip/hip_runtime.h>
#include <hip/hip_bf16.h>

#define NN 100000
#define NE 1600000
#define NG 2048

typedef __attribute__((ext_vector_type(8))) short short8v;
typedef __attribute__((ext_vector_type(4))) float f32x4;

__device__ inline ushort f2bf(float f) {
    // round-to-nearest-even f32 -> bf16
    uint u = __float_as_uint(f);
    uint r = (u + 0x7fffu + ((u >> 16) & 1u)) >> 16;
    return (ushort)r;
}
__device__ inline float bf2f(ushort h) {
    return __uint_as_float(((uint)h) << 16);
}

#define MFMA_BF16 __builtin_amdgcn_mfma_f32_16x16x32_bf16

// ---------------- CSR build ----------------

__global__ void k_count(const int* __restrict__ dst, int* __restrict__ counts) {
    int e = blockIdx.x * 256 + threadIdx.x;
    if (e < NE) atomicAdd(&counts[dst[e]], 1);
}

__global__ void k_bsum(const int* __restrict__ counts, int* __restrict__ bsum) {
    __shared__ int s[256];
    int t = threadIdx.x;
    int i = blockIdx.x * 256 + t;
    s[t] = (i < NN) ? counts[i] : 0;
    __syncthreads();
    for (int off = 128; off > 0; off >>= 1) {
        if (t < off) s[t] += s[t + off];
        __syncthreads();
    }
    if (t == 0) bsum[blockIdx.x] = s[0];
}

__global__ void k_scan512(int* __restrict__ data, int n) {
    __shared__ int s[512];
    int t = threadIdx.x;
    int v = (t < n) ? data[t] : 0;
    s[t] = v;
    __syncthreads();
    for (int off = 1; off < 512; off <<= 1) {
        int add = (t >= off) ? s[t - off] : 0;
        __syncthreads();
        s[t] += add;
        __syncthreads();
    }
    if (t < n) data[t] = s[t] - v;  // exclusive
}

__global__ void k_scan_counts(const int* __restrict__ counts, const int* __restrict__ bsum,
                              int* __restrict__ row_ptr, int* __restrict__ cursor) {
    __shared__ int s[256];
    int t = threadIdx.x, i = blockIdx.x * 256 + t;
    int v = (i < NN) ? counts[i] : 0;
    s[t] = v;
    __syncthreads();
    for (int off = 1; off < 256; off <<= 1) {
        int add = (t >= off) ? s[t - off] : 0;
        __syncthreads();
        s[t] += add;
        __syncthreads();
    }
    int excl = s[t] - v + bsum[blockIdx.x];
    if (i < NN) { row_ptr[i] = excl; cursor[i] = excl; }
    if (i == NN - 1) row_ptr[NN] = excl + v;
}

__global__ void k_fill(const int* __restrict__ src, const int* __restrict__ dst,
                       const float* __restrict__ ea, int* __restrict__ cursor,
                       float4* __restrict__ csr) {
    int e = blockIdx.x * 256 + threadIdx.x;
    if (e >= NE) return;
    int d = dst[e];
    int p = atomicAdd(&cursor[d], 1);
    csr[p] = make_float4(__int_as_float(src[e]), ea[3 * e], ea[3 * e + 1], ea[3 * e + 2]);
}

// ---------------- weight prep: f32 [K][C] -> bf16 hi/lo transposed [C][K] ----------------

__global__ void k_prep(const float* __restrict__ W1a, const float* __restrict__ W1b,
                       const float* __restrict__ W2a, const float* __restrict__ W2b,
                       ushort* __restrict__ W1a_hi, ushort* __restrict__ W1a_lo,
                       ushort* __restrict__ W1b_hi, ushort* __restrict__ W1b_lo,
                       ushort* __restrict__ W2a_hi, ushort* __restrict__ W2a_lo,
                       ushort* __restrict__ W2b_hi, ushort* __restrict__ W2b_lo) {
    int i = blockIdx.x * 256 + threadIdx.x;
    float v; ushort* ph; ushort* pl; int idx;
    if (i < 4096) {                       // W1a: 32x128
        int k = i >> 7, c = i & 127;
        v = W1a[i]; ph = W1a_hi; pl = W1a_lo; idx = c * 32 + k;
    } else if (i < 20480) {               // W1b: 128x128
        int j = i - 4096; int k = j >> 7, c = j & 127;
        v = W1b[j]; ph = W1b_hi; pl = W1b_lo; idx = c * 128 + k;
    } else if (i < 36864) {               // W2a
        int j = i - 20480; int k = j >> 7, c = j & 127;
        v = W2a[j]; ph = W2a_hi; pl = W2a_lo; idx = c * 128 + k;
    } else if (i < 53248) {               // W2b
        int j = i - 36864; int k = j >> 7, c = j & 127;
        v = W2b[j]; ph = W2b_hi; pl = W2b_lo; idx = c * 128 + k;
    } else return;
    ushort h = f2bf(v);
    ph[idx] = h;
    pl[idx] = f2bf(v - bf2f(h));
}

// ---------------- Layer 1 aggregation (gather, 32 ch), 4-deep pipelined ----------------

__global__ __launch_bounds__(256) void k_agg1(
        const float* __restrict__ x, const float4* __restrict__ csr,
        const int* __restrict__ row_ptr,
        const float* __restrict__ We1, const float* __restrict__ be1,
        float* __restrict__ agg1) {
    int lane = threadIdx.x & 31;
    int node = blockIdx.x * 8 + (threadIdx.x >> 5);
    float w0 = We1[lane], w1 = We1[32 + lane], w2 = We1[64 + lane], b = be1[lane];
    int p0 = row_ptr[node], p1 = row_ptr[node + 1];
    float acc = 0.f;
    int p = p0;
    for (; p + 4 <= p1; p += 4) {
        float4 e0 = csr[p], e1 = csr[p + 1], e2 = csr[p + 2], e3 = csr[p + 3];
        int s0 = __float_as_int(e0.x), s1 = __float_as_int(e1.x);
        int s2 = __float_as_int(e2.x), s3 = __float_as_int(e3.x);
        float v0 = x[s0 * 32 + lane];
        float v1 = x[s1 * 32 + lane];
        float v2 = x[s2 * 32 + lane];
        float v3 = x[s3 * 32 + lane];
        float el0 = fmaf(e0.y, w0, fmaf(e0.z, w1, fmaf(e0.w, w2, b)));
        float el1 = fmaf(e1.y, w0, fmaf(e1.z, w1, fmaf(e1.w, w2, b)));
        float el2 = fmaf(e2.y, w0, fmaf(e2.z, w1, fmaf(e2.w, w2, b)));
        float el3 = fmaf(e3.y, w0, fmaf(e3.z, w1, fmaf(e3.w, w2, b)));
        acc += fmaxf(v0 + el0, 0.f);
        acc += fmaxf(v1 + el1, 0.f);
        acc += fmaxf(v2 + el2, 0.f);
        acc += fmaxf(v3 + el3, 0.f);
    }
    for (; p < p1; ++p) {
        float4 ed = csr[p];
        int s = __float_as_int(ed.x);
        float el = fmaf(ed.y, w0, fmaf(ed.z, w1, fmaf(ed.w, w2, b)));
        acc += fmaxf(x[s * 32 + lane] + el, 0.f);
    }
    agg1[node * 32 + lane] = acc;
}

// ---------------- Layer 2 aggregation (gather, 128 ch), 4-deep pipelined ----------------

__global__ __launch_bounds__(256) void k_agg2(
        const float* __restrict__ h1, const float4* __restrict__ csr,
        const int* __restrict__ row_ptr,
        const float* __restrict__ We2, const float* __restrict__ be2,
        float* __restrict__ agg2) {
    int lane = threadIdx.x & 127;
    int node = blockIdx.x * 2 + (threadIdx.x >> 7);
    float w0 = We2[lane], w1 = We2[128 + lane], w2 = We2[256 + lane], b = be2[lane];
    int p0 = row_ptr[node], p1 = row_ptr[node + 1];
    float acc = 0.f;
    int p = p0;
    for (; p + 4 <= p1; p += 4) {
        float4 e0 = csr[p], e1 = csr[p + 1], e2 = csr[p + 2], e3 = csr[p + 3];
        int s0 = __float_as_int(e0.x), s1 = __float_as_int(e1.x);
        int s2 = __float_as_int(e2.x), s3 = __float_as_int(e3.x);
        float v0 = h1[s0 * 128 + lane];
        float v1 = h1[s1 * 128 + lane];
        float v2 = h1[s2 * 128 + lane];
        float v3 = h1[s3 * 128 + lane];
        float el0 = fmaf(e0.y, w0, fmaf(e0.z, w1, fmaf(e0.w, w2, b)));
        float el1 = fmaf(e1.y, w0, fmaf(e1.z, w1, fmaf(e1.w, w2, b)));
        float el2 = fmaf(e2.y, w0, fmaf(e2.z, w1, fmaf(e2.w, w2, b)));
        float el3 = fmaf(e3.y, w0, fmaf(e3.z, w1, fmaf(e3.w, w2, b)));
        acc += fmaxf(v0 + el0, 0.f);
        acc += fmaxf(v1 + el1, 0.f);
        acc += fmaxf(v2 + el2, 0.f);
        acc += fmaxf(v3 + el3, 0.f);
    }
    for (; p < p1; ++p) {
        float4 ed = csr[p];
        int s = __float_as_int(ed.x);
        float el = fmaf(ed.y, w0, fmaf(ed.z, w1, fmaf(ed.w, w2, b)));
        acc += fmaxf(h1[s * 128 + lane] + el, 0.f);
    }
    agg2[node * 128 + lane] = acc;
}

// ---------------- MLP 1 (split-bf16 MFMA): h1 = relu(relu((x+agg1)@W1a+b1a)@W1b+b1b) ----
// 32 nodes/block, 4 waves; wave w owns out-ch [w*32, w*32+32), m-tiles 0..1.
// Split precision: v = hi + lo (both bf16); a.w ~ ah*wh + al*wh + ah*wl.

#define M1_AHI 0
#define M1_ALO 2560
#define M1_W   5120
#define M1_HHI 25600
#define M1_HLO 34304
#define M1_SMEM 43008

__global__ __launch_bounds__(256) void k_mlp1(
        const float* __restrict__ x, const float* __restrict__ agg1,
        const ushort* __restrict__ W1a_hi, const ushort* __restrict__ W1a_lo,
        const float* __restrict__ b1a,
        const ushort* __restrict__ W1b_hi, const ushort* __restrict__ W1b_lo,
        const float* __restrict__ b1b,
        float* __restrict__ h1out) {
    __shared__ __align__(16) char smem[M1_SMEM];
    ushort* A_hi = (ushort*)(smem + M1_AHI);   // [32][40]
    ushort* A_lo = (ushort*)(smem + M1_ALO);   // [32][40]
    ushort* W_s  = (ushort*)(smem + M1_W);     // 10240 ushorts
    ushort* H_hi = (ushort*)(smem + M1_HHI);   // [32][136]
    ushort* H_lo = (ushort*)(smem + M1_HLO);   // [32][136]
    int t = threadIdx.x;
    int nbase = blockIdx.x * 32;

    // stage A = x + agg1, split hi/lo
    if (t < 128) {
        int n = t >> 2, cc = (t & 3) * 8;
        int gn = nbase + n;
        short8v vh = {0,0,0,0,0,0,0,0}, vl = {0,0,0,0,0,0,0,0};
        if (gn < NN) {
            const float4* xp = (const float4*)&x[gn * 32 + cc];
            const float4* gp = (const float4*)&agg1[gn * 32 + cc];
            float s[8];
            float4 x0 = xp[0], x1 = xp[1], g0 = gp[0], g1 = gp[1];
            s[0]=x0.x+g0.x; s[1]=x0.y+g0.y; s[2]=x0.z+g0.z; s[3]=x0.w+g0.w;
            s[4]=x1.x+g1.x; s[5]=x1.y+g1.y; s[6]=x1.z+g1.z; s[7]=x1.w+g1.w;
#pragma unroll
            for (int j = 0; j < 8; ++j) {
                ushort h = f2bf(s[j]);
                vh[j] = (short)h;
                vl[j] = (short)f2bf(s[j] - bf2f(h));
            }
        }
        *(short8v*)&A_hi[n * 40 + cc] = vh;
        *(short8v*)&A_lo[n * 40 + cc] = vl;
    }
    // stage W1a hi (first 5120 ush) + lo (next 5120): [128][40] each
    for (int i = t; i < 1024; i += 256) {
        int half = i >> 9, j = i & 511;
        int r = j >> 2, ko = (j & 3) * 8;
        const ushort* srcw = half ? W1a_lo : W1a_hi;
        *(short8v*)&W_s[half * 5120 + r * 40 + ko] = *(const short8v*)&srcw[r * 32 + ko];
    }
    __syncthreads();

    int w = t >> 6, l = t & 63;
    int cl = l & 15, kq = l >> 4;

    f32x4 acc[2][2];
#pragma unroll
    for (int mt = 0; mt < 2; ++mt) { acc[mt][0] = f32x4{0.f,0.f,0.f,0.f}; acc[mt][1] = f32x4{0.f,0.f,0.f,0.f}; }

    // phase A: K=32, single k-step, 3-term split
    {
        int kof = kq * 8;
        short8v bh0 = *(short8v*)&W_s[(w * 32 + cl) * 40 + kof];
        short8v bh1 = *(short8v*)&W_s[(w * 32 + 16 + cl) * 40 + kof];
        short8v bl0 = *(short8v*)&W_s[5120 + (w * 32 + cl) * 40 + kof];
        short8v bl1 = *(short8v*)&W_s[5120 + (w * 32 + 16 + cl) * 40 + kof];
#pragma unroll
        for (int mt = 0; mt < 2; ++mt) {
            short8v ah = *(short8v*)&A_hi[(mt * 16 + cl) * 40 + kof];
            short8v al = *(short8v*)&A_lo[(mt * 16 + cl) * 40 + kof];
            acc[mt][0] = MFMA_BF16(ah, bh0, acc[mt][0], 0, 0, 0);
            acc[mt][0] = MFMA_BF16(al, bh0, acc[mt][0], 0, 0, 0);
            acc[mt][0] = MFMA_BF16(ah, bl0, acc[mt][0], 0, 0, 0);
            acc[mt][1] = MFMA_BF16(ah, bh1, acc[mt][1], 0, 0, 0);
            acc[mt][1] = MFMA_BF16(al, bh1, acc[mt][1], 0, 0, 0);
            acc[mt][1] = MFMA_BF16(ah, bl1, acc[mt][1], 0, 0, 0);
        }
    }
    // epilogue A -> H (bias+relu, split)
    {
        float bb0 = b1a[w * 32 + cl], bb1 = b1a[w * 32 + 16 + cl];
#pragma unroll
        for (int mt = 0; mt < 2; ++mt)
#pragma unroll
            for (int j = 0; j < 4; ++j) {
                int row = mt * 16 + kq * 4 + j;
                float v0 = fmaxf(acc[mt][0][j] + bb0, 0.f);
                float v1 = fmaxf(acc[mt][1][j] + bb1, 0.f);
                ushort h0 = f2bf(v0), h1v = f2bf(v1);
                H_hi[row * 136 + w * 32 + cl]      = h0;
                H_lo[row * 136 + w * 32 + cl]      = f2bf(v0 - bf2f(h0));
                H_hi[row * 136 + w * 32 + 16 + cl] = h1v;
                H_lo[row * 136 + w * 32 + 16 + cl] = f2bf(v1 - bf2f(h1v));
            }
    }
    __syncthreads();

    // phase B: K=128 from H, W1b in two 64-K panels; hi-pass then lo-pass per panel
#pragma unroll
    for (int mt = 0; mt < 2; ++mt) { acc[mt][0] = f32x4{0.f,0.f,0.f,0.f}; acc[mt][1] = f32x4{0.f,0.f,0.f,0.f}; }
    for (int p = 0; p < 2; ++p) {
        for (int i = t; i < 1024; i += 256) {
            int r = i >> 3, ko = (i & 7) * 8;
            *(short8v*)&W_s[r * 72 + ko] = *(const short8v*)&W1b_hi[r * 128 + p * 64 + ko];
        }
        __syncthreads();
        short8v ahk[2][2];
#pragma unroll
        for (int ksl = 0; ksl < 2; ++ksl) {
            int kofW = ksl * 32 + kq * 8;
            int kofH = p * 64 + kofW;
            short8v bh0 = *(short8v*)&W_s[(w * 32 + cl) * 72 + kofW];
            short8v bh1 = *(short8v*)&W_s[(w * 32 + 16 + cl) * 72 + kofW];
#pragma unroll
            for (int mt = 0; mt < 2; ++mt) {
                ahk[ksl][mt] = *(short8v*)&H_hi[(mt * 16 + cl) * 136 + kofH];
                short8v al   = *(short8v*)&H_lo[(mt * 16 + cl) * 136 + kofH];
                acc[mt][0] = MFMA_BF16(ahk[ksl][mt], bh0, acc[mt][0], 0, 0, 0);
                acc[mt][0] = MFMA_BF16(al, bh0, acc[mt][0], 0, 0, 0);
                acc[mt][1] = MFMA_BF16(ahk[ksl][mt], bh1, acc[mt][1], 0, 0, 0);
                acc[mt][1] = MFMA_BF16(al, bh1, acc[mt][1], 0, 0, 0);
            }
        }
        __syncthreads();
        for (int i = t; i < 1024; i += 256) {
            int r = i >> 3, ko = (i & 7) * 8;
            *(short8v*)&W_s[r * 72 + ko] = *(const short8v*)&W1b_lo[r * 128 + p * 64 + ko];
        }
        __syncthreads();
#pragma unroll
        for (int ksl = 0; ksl < 2; ++ksl) {
            int kofW = ksl * 32 + kq * 8;
            short8v bl0 = *(short8v*)&W_s[(w * 32 + cl) * 72 + kofW];
            short8v bl1 = *(short8v*)&W_s[(w * 32 + 16 + cl) * 72 + kofW];
#pragma unroll
            for (int mt = 0; mt < 2; ++mt) {
                acc[mt][0] = MFMA_BF16(ahk[ksl][mt], bl0, acc[mt][0], 0, 0, 0);
                acc[mt][1] = MFMA_BF16(ahk[ksl][mt], bl1, acc[mt][1], 0, 0, 0);
            }
        }
        __syncthreads();
    }
    // epilogue B -> h1out (f32, bias+relu)
    {
        float c0 = b1b[w * 32 + cl], c1 = b1b[w * 32 + 16 + cl];
#pragma unroll
        for (int mt = 0; mt < 2; ++mt)
#pragma unroll
            for (int j = 0; j < 4; ++j) {
                int gn = nbase + mt * 16 + kq * 4 + j;
                if (gn < NN) {
                    h1out[gn * 128 + w * 32 + cl]      = fmaxf(acc[mt][0][j] + c0, 0.f);
                    h1out[gn * 128 + w * 32 + 16 + cl] = fmaxf(acc[mt][1][j] + c1, 0.f);
                }
            }
    }
}

// ---------------- MLP 2 (split-bf16 MFMA) + fused global_add_pool ----------------

#define M2_AHI 0
#define M2_ALO 8704
#define M2_W   17408
#define M2_HHI 35840
#define M2_HLO 44544
#define M2_B   53248
#define M2_SMEM 53376

__global__ __launch_bounds__(256) void k_mlp2(
        const float* __restrict__ h1, const float* __restrict__ agg2,
        const ushort* __restrict__ W2a_hi, const ushort* __restrict__ W2a_lo,
        const float* __restrict__ b2a,
        const ushort* __restrict__ W2b_hi, const ushort* __restrict__ W2b_lo,
        const float* __restrict__ b2b,
        const int* __restrict__ batch, float* __restrict__ pooled) {
    __shared__ __align__(16) char smem[M2_SMEM];
    ushort* A_hi = (ushort*)(smem + M2_AHI);
    ushort* A_lo = (ushort*)(smem + M2_ALO);
    ushort* W_s  = (ushort*)(smem + M2_W);
    ushort* H_hi = (ushort*)(smem + M2_HHI);
    ushort* H_lo = (ushort*)(smem + M2_HLO);
    int* batch_s = (int*)(smem + M2_B);
    int t = threadIdx.x;
    int nbase = blockIdx.x * 32;

    if (t < 32) batch_s[t] = (nbase + t < NN) ? batch[nbase + t] : -1;

    // stage A = h1 + agg2, split hi/lo
    for (int i = t; i < 512; i += 256) {
        int n = i >> 4, cc = (i & 15) * 8;
        int gn = nbase + n;
        short8v vh = {0,0,0,0,0,0,0,0}, vl = {0,0,0,0,0,0,0,0};
        if (gn < NN) {
            const float4* hp = (const float4*)&h1[gn * 128 + cc];
            const float4* gp = (const float4*)&agg2[gn * 128 + cc];
            float s[8];
            float4 a0 = hp[0], a1 = hp[1], g0 = gp[0], g1 = gp[1];
            s[0]=a0.x+g0.x; s[1]=a0.y+g0.y; s[2]=a0.z+g0.z; s[3]=a0.w+g0.w;
            s[4]=a1.x+g1.x; s[5]=a1.y+g1.y; s[6]=a1.z+g1.z; s[7]=a1.w+g1.w;
#pragma unroll
            for (int j = 0; j < 8; ++j) {
                ushort h = f2bf(s[j]);
                vh[j] = (short)h;
                vl[j] = (short)f2bf(s[j] - bf2f(h));
            }
        }
        *(short8v*)&A_hi[n * 136 + cc] = vh;
        *(short8v*)&A_lo[n * 136 + cc] = vl;
    }

    int w = t >> 6, l = t & 63;
    int cl = l & 15, kq = l >> 4;

    f32x4 acc[2][2];
#pragma unroll
    for (int mt = 0; mt < 2; ++mt) { acc[mt][0] = f32x4{0.f,0.f,0.f,0.f}; acc[mt][1] = f32x4{0.f,0.f,0.f,0.f}; }

    // phase A: (h1+agg2) @ W2a, two 64-K panels, hi-pass + lo-pass
    for (int p = 0; p < 2; ++p) {
        for (int i = t; i < 1024; i += 256) {
            int r = i >> 3, ko = (i & 7) * 8;
            *(short8v*)&W_s[r * 72 + ko] = *(const short8v*)&W2a_hi[r * 128 + p * 64 + ko];
        }
        __syncthreads();
        short8v ahk[2][2];
#pragma unroll
        for (int ksl = 0; ksl < 2; ++ksl) {
            int kofW = ksl * 32 + kq * 8;
            int kofA = p * 64 + kofW;
            short8v bh0 = *(short8v*)&W_s[(w * 32 + cl) * 72 + kofW];
            short8v bh1 = *(short8v*)&W_s[(w * 32 + 16 + cl) * 72 + kofW];
#pragma unroll
            for (int mt = 0; mt < 2; ++mt) {
                ahk[ksl][mt] = *(short8v*)&A_hi[(mt * 16 + cl) * 136 + kofA];
                short8v al   = *(short8v*)&A_lo[(mt * 16 + cl) * 136 + kofA];
                acc[mt][0] = MFMA_BF16(ahk[ksl][mt], bh0, acc[mt][0], 0, 0, 0);
                acc[mt][0] = MFMA_BF16(al, bh0, acc[mt][0], 0, 0, 0);
                acc[mt][1] = MFMA_BF16(ahk[ksl][mt], bh1, acc[mt][1], 0, 0, 0);
                acc[mt][1] = MFMA_BF16(al, bh1, acc[mt][1], 0, 0, 0);
            }
        }
        __syncthreads();
        for (int i = t; i < 1024; i += 256) {
            int r = i >> 3, ko = (i & 7) * 8;
            *(short8v*)&W_s[r * 72 + ko] = *(const short8v*)&W2a_lo[r * 128 + p * 64 + ko];
        }
        __syncthreads();
#pragma unroll
        for (int ksl = 0; ksl < 2; ++ksl) {
            int kofW = ksl * 32 + kq * 8;
            short8v bl0 = *(short8v*)&W_s[(w * 32 + cl) * 72 + kofW];
            short8v bl1 = *(short8v*)&W_s[(w * 32 + 16 + cl) * 72 + kofW];
#pragma unroll
            for (int mt = 0; mt < 2; ++mt) {
                acc[mt][0] = MFMA_BF16(ahk[ksl][mt], bl0, acc[mt][0], 0, 0, 0);
                acc[mt][1] = MFMA_BF16(ahk[ksl][mt], bl1, acc[mt][1], 0, 0, 0);
            }
        }
        __syncthreads();
    }
    // epilogue A -> H (bias+relu, split)
    {
        float bb0 = b2a[w * 32 + cl], bb1 = b2a[w * 32 + 16 + cl];
#pragma unroll
        for (int mt = 0; mt < 2; ++mt)
#pragma unroll
            for (int j = 0; j < 4; ++j) {
                int row = mt * 16 + kq * 4 + j;
                float v0 = fmaxf(acc[mt][0][j] + bb0, 0.f);
                float v1 = fmaxf(acc[mt][1][j] + bb1, 0.f);
                ushort h0 = f2bf(v0), h1v = f2bf(v1);
                H_hi[row * 136 + w * 32 + cl]      = h0;
                H_lo[row * 136 + w * 32 + cl]      = f2bf(v0 - bf2f(h0));
                H_hi[row * 136 + w * 32 + 16 + cl] = h1v;
                H_lo[row * 136 + w * 32 + 16 + cl] = f2bf(v1 - bf2f(h1v));
            }
    }
    __syncthreads();

    // phase B: hid @ W2b
#pragma unroll
    for (int mt = 0; mt < 2; ++mt) { acc[mt][0] = f32x4{0.f,0.f,0.f,0.f}; acc[mt][1] = f32x4{0.f,0.f,0.f,0.f}; }
    for (int p = 0; p < 2; ++p) {
        for (int i = t; i < 1024; i += 256) {
            int r = i >> 3, ko = (i & 7) * 8;
            *(short8v*)&W_s[r * 72 + ko] = *(const short8v*)&W2b_hi[r * 128 + p * 64 + ko];
        }
        __syncthreads();
        short8v ahk[2][2];
#pragma unroll
        for (int ksl = 0; ksl < 2; ++ksl) {
            int kofW = ksl * 32 + kq * 8;
            int kofH = p * 64 + kofW;
            short8v bh0 = *(short8v*)&W_s[(w * 32 + cl) * 72 + kofW];
            short8v bh1 = *(short8v*)&W_s[(w * 32 + 16 + cl) * 72 + kofW];
#pragma unroll
            for (int mt = 0; mt < 2; ++mt) {
                ahk[ksl][mt] = *(short8v*)&H_hi[(mt * 16 + cl) * 136 + kofH];
                short8v al   = *(short8v*)&H_lo[(mt * 16 + cl) * 136 + kofH];
                acc[mt][0] = MFMA_BF16(ahk[ksl][mt], bh0, acc[mt][0], 0, 0, 0);
                acc[mt][0] = MFMA_BF16(al, bh0, acc[mt][0], 0, 0, 0);
                acc[mt][1] = MFMA_BF16(ahk[ksl][mt], bh1, acc[mt][1], 0, 0, 0);
                acc[mt][1] = MFMA_BF16(al, bh1, acc[mt][1], 0, 0, 0);
            }
        }
        __syncthreads();
        for (int i = t; i < 1024; i += 256) {
            int r = i >> 3, ko = (i & 7) * 8;
            *(short8v*)&W_s[r * 72 + ko] = *(const short8v*)&W2b_lo[r * 128 + p * 64 + ko];
        }
        __syncthreads();
#pragma unroll
        for (int ksl = 0; ksl < 2; ++ksl) {
            int kofW = ksl * 32 + kq * 8;
            short8v bl0 = *(short8v*)&W_s[(w * 32 + cl) * 72 + kofW];
            short8v bl1 = *(short8v*)&W_s[(w * 32 + 16 + cl) * 72 + kofW];
#pragma unroll
            for (int mt = 0; mt < 2; ++mt) {
                acc[mt][0] = MFMA_BF16(ahk[ksl][mt], bl0, acc[mt][0], 0, 0, 0);
                acc[mt][1] = MFMA_BF16(ahk[ksl][mt], bl1, acc[mt][1], 0, 0, 0);
            }
        }
        __syncthreads();
    }
    // epilogue B -> f32 tile P (aliases A region; all A reads done), then pool
    float* P = (float*)smem;  // [32][132]
    {
        float c0 = b2b[w * 32 + cl], c1 = b2b[w * 32 + 16 + cl];
#pragma unroll
        for (int mt = 0; mt < 2; ++mt)
#pragma unroll
            for (int j = 0; j < 4; ++j) {
                int row = mt * 16 + kq * 4 + j;
                P[row * 132 + w * 32 + cl]      = fmaxf(acc[mt][0][j] + c0, 0.f);
                P[row * 132 + w * 32 + 16 + cl] = fmaxf(acc[mt][1][j] + c1, 0.f);
            }
    }
    __syncthreads();

    // pool: batch sorted; two halves of 16 nodes, run-length + atomics
    {
        int c = t & 127, half = t >> 7;
        int i0 = half * 16;
        float run = 0.f;
        int cur = batch_s[i0];
        if (cur >= 0) {
            for (int i = i0; i < i0 + 16; ++i) {
                int b = batch_s[i];
                if (b < 0) break;
                if (b != cur) { atomicAdd(&pooled[cur * 128 + c], run); run = 0.f; cur = b; }
                run += P[i * 132 + c];
            }
            atomicAdd(&pooled[cur * 128 + c], run);
        }
    }
}

// ---------------- Readout: relu(pooled@Wm1+bm1)@Wm2+bm2 ----------------

__global__ __launch_bounds__(128) void k_readout(
        const float* __restrict__ pooled, const float* __restrict__ Wm1,
        const float* __restrict__ bm1, const float* __restrict__ Wm2,
        const float* __restrict__ bm2, float* __restrict__ out) {
    __shared__ float row[128];
    __shared__ float red[128];
    int g = blockIdx.x, t = threadIdx.x;
    row[t] = pooled[g * 128 + t];
    __syncthreads();
    float acc = bm1[t];
    for (int c = 0; c < 128; ++c) acc = fmaf(row[c], Wm1[c * 128 + t], acc);
    float term = fmaxf(acc, 0.f) * Wm2[t];
    red[t] = term;
    __syncthreads();
    for (int off = 64; off > 0; off >>= 1) {
        if (t < off) red[t] += red[t + off];
        __syncthreads();
    }
    if (t == 0) out[g] = red[0] + bm2[0];
}

// ---------------- Launch ----------------

extern "C" void kernel_launch(void* const* d_in, const int* in_sizes, int n_in,
                              void* d_out, int out_size, void* d_ws, size_t ws_size,
                              hipStream_t stream) {
    const float* x    = (const float*)d_in[0];
    const int* eidx   = (const int*)d_in[1];
    const float* ea   = (const float*)d_in[2];
    const int* batch  = (const int*)d_in[3];
    const float* We1  = (const float*)d_in[4];
    const float* be1  = (const float*)d_in[5];
    const float* W1a  = (const float*)d_in[6];
    const float* b1a  = (const float*)d_in[7];
    const float* W1b  = (const float*)d_in[8];
    const float* b1b  = (const float*)d_in[9];
    const float* We2  = (const float*)d_in[10];
    const float* be2  = (const float*)d_in[11];
    const float* W2a  = (const float*)d_in[12];
    const float* b2a  = (const float*)d_in[13];
    const float* W2b  = (const float*)d_in[14];
    const float* b2b  = (const float*)d_in[15];
    const float* Wm1  = (const float*)d_in[16];
    const float* bm1  = (const float*)d_in[17];
    const float* Wm2  = (const float*)d_in[18];
    const float* bm2  = (const float*)d_in[19];
    float* out = (float*)d_out;

    const int* src = eidx;
    const int* dst = eidx + NE;

    char* w = (char*)d_ws;
    auto alloc = [&](size_t bytes) { void* p = (void*)w; w += (bytes + 255) & ~(size_t)255; return p; };
    int* counts    = (int*)alloc(NN * 4);
    int* row_ptr   = (int*)alloc((NN + 1) * 4);
    int* cursor    = (int*)alloc(NN * 4);
    int* bsum      = (int*)alloc(512 * 4);
    float4* csr    = (float4*)alloc((size_t)NE * 16);
    float* agg1    = (float*)alloc((size_t)NN * 32 * 4);
    float* h1      = (float*)alloc((size_t)NN * 128 * 4);
    float* agg2    = (float*)alloc((size_t)NN * 128 * 4);
    float* pooled  = (float*)alloc((size_t)NG * 128 * 4);
    ushort* W1a_hi = (ushort*)alloc(4096 * 2);
    ushort* W1a_lo = (ushort*)alloc(4096 * 2);
    ushort* W1b_hi = (ushort*)alloc(16384 * 2);
    ushort* W1b_lo = (ushort*)alloc(16384 * 2);
    ushort* W2a_hi = (ushort*)alloc(16384 * 2);
    ushort* W2a_lo = (ushort*)alloc(16384 * 2);
    ushort* W2b_hi = (ushort*)alloc(16384 * 2);
    ushort* W2b_lo = (ushort*)alloc(16384 * 2);

    hipMemsetAsync(counts, 0, NN * 4, stream);
    hipMemsetAsync(pooled, 0, (size_t)NG * 128 * 4, stream);

    const int EB = (NE + 255) / 256;       // 6250
    const int NB = (NN + 255) / 256;       // 391
    const int MB = (NN + 31) / 32;         // 3125

    k_prep<<<208, 256, 0, stream>>>(W1a, W1b, W2a, W2b,
                                    W1a_hi, W1a_lo, W1b_hi, W1b_lo,
                                    W2a_hi, W2a_lo, W2b_hi, W2b_lo);
    k_count<<<EB, 256, 0, stream>>>(dst, counts);
    k_bsum<<<NB, 256, 0, stream>>>(counts, bsum);
    k_scan512<<<1, 512, 0, stream>>>(bsum, NB);
    k_scan_counts<<<NB, 256, 0, stream>>>(counts, bsum, row_ptr, cursor);
    k_fill<<<EB, 256, 0, stream>>>(src, dst, ea, cursor, csr);

    k_agg1<<<NN / 8, 256, 0, stream>>>(x, csr, row_ptr, We1, be1, agg1);
    k_mlp1<<<MB, 256, 0, stream>>>(x, agg1, W1a_hi, W1a_lo, b1a, W1b_hi, W1b_lo, b1b, h1);
    k_agg2<<<NN / 2, 256, 0, stream>>>(h1, csr, row_ptr, We2, be2, agg2);
    k_mlp2<<<MB, 256, 0, stream>>>(h1, agg2, W2a_hi, W2a_lo, b2a, W2b_hi, W2b_lo, b2b, batch, pooled);
    k_readout<<<NG, 128, 0, stream>>>(pooled, Wm1, bm1, Wm2, bm2, out);
}

// Round 6
// 567.480 us; speedup vs baseline: 3.3006x; 1.0452x over previous
//
#include <hip/hip_runtime.h>
#include <hip/hip_bf16.h>

#define NN 100000
#define NE 1600000
#define NG 2048

typedef __attribute__((ext_vector_type(8))) short short8v;
typedef __attribute__((ext_vector_type(4))) float f32x4;

__device__ inline ushort f2bf(float f) {
    // round-to-nearest-even f32 -> bf16
    uint u = __float_as_uint(f);
    uint r = (u + 0x7fffu + ((u >> 16) & 1u)) >> 16;
    return (ushort)r;
}
__device__ inline float bf2f(ushort h) {
    return __uint_as_float(((uint)h) << 16);
}

#define MFMA_BF16 __builtin_amdgcn_mfma_f32_16x16x32_bf16

// ---------------- CSR build ----------------

__global__ void k_count(const int* __restrict__ dst, int* __restrict__ counts) {
    int e = blockIdx.x * 256 + threadIdx.x;
    if (e < NE) atomicAdd(&counts[dst[e]], 1);
}

__global__ void k_bsum(const int* __restrict__ counts, int* __restrict__ bsum) {
    __shared__ int s[256];
    int t = threadIdx.x;
    int i = blockIdx.x * 256 + t;
    s[t] = (i < NN) ? counts[i] : 0;
    __syncthreads();
    for (int off = 128; off > 0; off >>= 1) {
        if (t < off) s[t] += s[t + off];
        __syncthreads();
    }
    if (t == 0) bsum[blockIdx.x] = s[0];
}

__global__ void k_scan512(int* __restrict__ data, int n) {
    __shared__ int s[512];
    int t = threadIdx.x;
    int v = (t < n) ? data[t] : 0;
    s[t] = v;
    __syncthreads();
    for (int off = 1; off < 512; off <<= 1) {
        int add = (t >= off) ? s[t - off] : 0;
        __syncthreads();
        s[t] += add;
        __syncthreads();
    }
    if (t < n) data[t] = s[t] - v;  // exclusive
}

__global__ void k_scan_counts(const int* __restrict__ counts, const int* __restrict__ bsum,
                              int* __restrict__ row_ptr, int* __restrict__ cursor) {
    __shared__ int s[256];
    int t = threadIdx.x, i = blockIdx.x * 256 + t;
    int v = (i < NN) ? counts[i] : 0;
    s[t] = v;
    __syncthreads();
    for (int off = 1; off < 256; off <<= 1) {
        int add = (t >= off) ? s[t - off] : 0;
        __syncthreads();
        s[t] += add;
        __syncthreads();
    }
    int excl = s[t] - v + bsum[blockIdx.x];
    if (i < NN) { row_ptr[i] = excl; cursor[i] = excl; }
    if (i == NN - 1) row_ptr[NN] = excl + v;
}

__global__ void k_fill(const int* __restrict__ src, const int* __restrict__ dst,
                       const float* __restrict__ ea, int* __restrict__ cursor,
                       float4* __restrict__ csr) {
    int e = blockIdx.x * 256 + threadIdx.x;
    if (e >= NE) return;
    int d = dst[e];
    int p = atomicAdd(&cursor[d], 1);
    csr[p] = make_float4(__int_as_float(src[e]), ea[3 * e], ea[3 * e + 1], ea[3 * e + 2]);
}

// ---------------- weight prep: f32 [K][C] -> bf16 hi/lo transposed [C][K] ----------------

__global__ void k_prep(const float* __restrict__ W1a, const float* __restrict__ W1b,
                       const float* __restrict__ W2a, const float* __restrict__ W2b,
                       ushort* __restrict__ W1a_hi, ushort* __restrict__ W1a_lo,
                       ushort* __restrict__ W1b_hi, ushort* __restrict__ W1b_lo,
                       ushort* __restrict__ W2a_hi, ushort* __restrict__ W2a_lo,
                       ushort* __restrict__ W2b_hi, ushort* __restrict__ W2b_lo) {
    int i = blockIdx.x * 256 + threadIdx.x;
    float v; ushort* ph; ushort* pl; int idx;
    if (i < 4096) {                       // W1a: 32x128
        int k = i >> 7, c = i & 127;
        v = W1a[i]; ph = W1a_hi; pl = W1a_lo; idx = c * 32 + k;
    } else if (i < 20480) {               // W1b: 128x128
        int j = i - 4096; int k = j >> 7, c = j & 127;
        v = W1b[j]; ph = W1b_hi; pl = W1b_lo; idx = c * 128 + k;
    } else if (i < 36864) {               // W2a
        int j = i - 20480; int k = j >> 7, c = j & 127;
        v = W2a[j]; ph = W2a_hi; pl = W2a_lo; idx = c * 128 + k;
    } else if (i < 53248) {               // W2b
        int j = i - 36864; int k = j >> 7, c = j & 127;
        v = W2b[j]; ph = W2b_hi; pl = W2b_lo; idx = c * 128 + k;
    } else return;
    ushort h = f2bf(v);
    ph[idx] = h;
    pl[idx] = f2bf(v - bf2f(h));
}

// ---------------- Layer 1 aggregation (gather, 32 ch), 8-deep pipelined ----------------

__global__ __launch_bounds__(256) void k_agg1(
        const float* __restrict__ x, const float4* __restrict__ csr,
        const int* __restrict__ row_ptr,
        const float* __restrict__ We1, const float* __restrict__ be1,
        float* __restrict__ agg1) {
    int lane = threadIdx.x & 31;
    int node = blockIdx.x * 8 + (threadIdx.x >> 5);
    float w0 = We1[lane], w1 = We1[32 + lane], w2 = We1[64 + lane], b = be1[lane];
    int p0 = row_ptr[node], p1 = row_ptr[node + 1];
    float acc = 0.f;
    int p = p0;
    for (; p + 8 <= p1; p += 8) {
        float4 e[8]; float v[8];
#pragma unroll
        for (int j = 0; j < 8; ++j) e[j] = csr[p + j];
#pragma unroll
        for (int j = 0; j < 8; ++j) v[j] = x[__float_as_int(e[j].x) * 32 + lane];
#pragma unroll
        for (int j = 0; j < 8; ++j) {
            float el = fmaf(e[j].y, w0, fmaf(e[j].z, w1, fmaf(e[j].w, w2, b)));
            acc += fmaxf(v[j] + el, 0.f);
        }
    }
    for (; p + 4 <= p1; p += 4) {
        float4 e[4]; float v[4];
#pragma unroll
        for (int j = 0; j < 4; ++j) e[j] = csr[p + j];
#pragma unroll
        for (int j = 0; j < 4; ++j) v[j] = x[__float_as_int(e[j].x) * 32 + lane];
#pragma unroll
        for (int j = 0; j < 4; ++j) {
            float el = fmaf(e[j].y, w0, fmaf(e[j].z, w1, fmaf(e[j].w, w2, b)));
            acc += fmaxf(v[j] + el, 0.f);
        }
    }
    for (; p < p1; ++p) {
        float4 ed = csr[p];
        int s = __float_as_int(ed.x);
        float el = fmaf(ed.y, w0, fmaf(ed.z, w1, fmaf(ed.w, w2, b)));
        acc += fmaxf(x[s * 32 + lane] + el, 0.f);
    }
    agg1[node * 32 + lane] = acc;
}

// ---------------- Layer 2 aggregation (gather, 128 ch), 8-deep pipelined ----------------

__global__ __launch_bounds__(256) void k_agg2(
        const float* __restrict__ h1, const float4* __restrict__ csr,
        const int* __restrict__ row_ptr,
        const float* __restrict__ We2, const float* __restrict__ be2,
        float* __restrict__ agg2) {
    int lane = threadIdx.x & 127;
    int node = blockIdx.x * 2 + (threadIdx.x >> 7);
    float w0 = We2[lane], w1 = We2[128 + lane], w2 = We2[256 + lane], b = be2[lane];
    int p0 = row_ptr[node], p1 = row_ptr[node + 1];
    float acc = 0.f;
    int p = p0;
    for (; p + 8 <= p1; p += 8) {
        float4 e[8]; float v[8];
#pragma unroll
        for (int j = 0; j < 8; ++j) e[j] = csr[p + j];
#pragma unroll
        for (int j = 0; j < 8; ++j) v[j] = h1[__float_as_int(e[j].x) * 128 + lane];
#pragma unroll
        for (int j = 0; j < 8; ++j) {
            float el = fmaf(e[j].y, w0, fmaf(e[j].z, w1, fmaf(e[j].w, w2, b)));
            acc += fmaxf(v[j] + el, 0.f);
        }
    }
    for (; p + 4 <= p1; p += 4) {
        float4 e[4]; float v[4];
#pragma unroll
        for (int j = 0; j < 4; ++j) e[j] = csr[p + j];
#pragma unroll
        for (int j = 0; j < 4; ++j) v[j] = h1[__float_as_int(e[j].x) * 128 + lane];
#pragma unroll
        for (int j = 0; j < 4; ++j) {
            float el = fmaf(e[j].y, w0, fmaf(e[j].z, w1, fmaf(e[j].w, w2, b)));
            acc += fmaxf(v[j] + el, 0.f);
        }
    }
    for (; p < p1; ++p) {
        float4 ed = csr[p];
        int s = __float_as_int(ed.x);
        float el = fmaf(ed.y, w0, fmaf(ed.z, w1, fmaf(ed.w, w2, b)));
        acc += fmaxf(h1[s * 128 + lane] + el, 0.f);
    }
    agg2[node * 128 + lane] = acc;
}

// ---------------- MLP 1 (split-bf16 MFMA, W direct from global) ----------------
// 32 nodes/block, 4 waves; wave w owns out-ch [w*32, w*32+32), m-tiles 0..1.
// W fragments (16 B/lane, contiguous) read straight from L2-resident weight arrays.

#define M1_AHI 0
#define M1_ALO 2560
#define M1_HHI 5120
#define M1_HLO 13824
#define M1_SMEM 22528

__global__ __launch_bounds__(256) void k_mlp1(
        const float* __restrict__ x, const float* __restrict__ agg1,
        const ushort* __restrict__ W1a_hi, const ushort* __restrict__ W1a_lo,
        const float* __restrict__ b1a,
        const ushort* __restrict__ W1b_hi, const ushort* __restrict__ W1b_lo,
        const float* __restrict__ b1b,
        float* __restrict__ h1out) {
    __shared__ __align__(16) char smem[M1_SMEM];
    ushort* A_hi = (ushort*)(smem + M1_AHI);   // [32][40]
    ushort* A_lo = (ushort*)(smem + M1_ALO);   // [32][40]
    ushort* H_hi = (ushort*)(smem + M1_HHI);   // [32][136]
    ushort* H_lo = (ushort*)(smem + M1_HLO);   // [32][136]
    int t = threadIdx.x;
    int nbase = blockIdx.x * 32;

    // stage A = x + agg1, split hi/lo
    if (t < 128) {
        int n = t >> 2, cc = (t & 3) * 8;
        int gn = nbase + n;
        short8v vh = {0,0,0,0,0,0,0,0}, vl = {0,0,0,0,0,0,0,0};
        if (gn < NN) {
            const float4* xp = (const float4*)&x[gn * 32 + cc];
            const float4* gp = (const float4*)&agg1[gn * 32 + cc];
            float s[8];
            float4 x0 = xp[0], x1 = xp[1], g0 = gp[0], g1 = gp[1];
            s[0]=x0.x+g0.x; s[1]=x0.y+g0.y; s[2]=x0.z+g0.z; s[3]=x0.w+g0.w;
            s[4]=x1.x+g1.x; s[5]=x1.y+g1.y; s[6]=x1.z+g1.z; s[7]=x1.w+g1.w;
#pragma unroll
            for (int j = 0; j < 8; ++j) {
                ushort h = f2bf(s[j]);
                vh[j] = (short)h;
                vl[j] = (short)f2bf(s[j] - bf2f(h));
            }
        }
        *(short8v*)&A_hi[n * 40 + cc] = vh;
        *(short8v*)&A_lo[n * 40 + cc] = vl;
    }
    __syncthreads();

    int w = t >> 6, l = t & 63;
    int cl = l & 15, kq = l >> 4;
    int row0 = w * 32 + cl, row1 = w * 32 + 16 + cl;

    f32x4 acc[2][2];
#pragma unroll
    for (int mt = 0; mt < 2; ++mt) { acc[mt][0] = f32x4{0.f,0.f,0.f,0.f}; acc[mt][1] = f32x4{0.f,0.f,0.f,0.f}; }

    // phase A: K=32, single k-step, 3-term split; W1a direct from global
    {
        int kof = kq * 8;
        short8v bh0 = *(const short8v*)&W1a_hi[row0 * 32 + kof];
        short8v bh1 = *(const short8v*)&W1a_hi[row1 * 32 + kof];
        short8v bl0 = *(const short8v*)&W1a_lo[row0 * 32 + kof];
        short8v bl1 = *(const short8v*)&W1a_lo[row1 * 32 + kof];
#pragma unroll
        for (int mt = 0; mt < 2; ++mt) {
            short8v ah = *(short8v*)&A_hi[(mt * 16 + cl) * 40 + kof];
            short8v al = *(short8v*)&A_lo[(mt * 16 + cl) * 40 + kof];
            acc[mt][0] = MFMA_BF16(ah, bh0, acc[mt][0], 0, 0, 0);
            acc[mt][0] = MFMA_BF16(al, bh0, acc[mt][0], 0, 0, 0);
            acc[mt][0] = MFMA_BF16(ah, bl0, acc[mt][0], 0, 0, 0);
            acc[mt][1] = MFMA_BF16(ah, bh1, acc[mt][1], 0, 0, 0);
            acc[mt][1] = MFMA_BF16(al, bh1, acc[mt][1], 0, 0, 0);
            acc[mt][1] = MFMA_BF16(ah, bl1, acc[mt][1], 0, 0, 0);
        }
    }
    // epilogue A -> H (bias+relu, split)
    {
        float bb0 = b1a[row0], bb1 = b1a[row1];
#pragma unroll
        for (int mt = 0; mt < 2; ++mt)
#pragma unroll
            for (int j = 0; j < 4; ++j) {
                int row = mt * 16 + kq * 4 + j;
                float v0 = fmaxf(acc[mt][0][j] + bb0, 0.f);
                float v1 = fmaxf(acc[mt][1][j] + bb1, 0.f);
                ushort h0 = f2bf(v0), h1v = f2bf(v1);
                H_hi[row * 136 + row0] = h0;
                H_lo[row * 136 + row0] = f2bf(v0 - bf2f(h0));
                H_hi[row * 136 + row1] = h1v;
                H_lo[row * 136 + row1] = f2bf(v1 - bf2f(h1v));
            }
    }
    __syncthreads();

    // phase B: K=128 from H; W1b direct from global, 4 k-slices
#pragma unroll
    for (int mt = 0; mt < 2; ++mt) { acc[mt][0] = f32x4{0.f,0.f,0.f,0.f}; acc[mt][1] = f32x4{0.f,0.f,0.f,0.f}; }
#pragma unroll
    for (int ksl = 0; ksl < 4; ++ksl) {
        int kof = ksl * 32 + kq * 8;
        short8v bh0 = *(const short8v*)&W1b_hi[row0 * 128 + kof];
        short8v bh1 = *(const short8v*)&W1b_hi[row1 * 128 + kof];
        short8v bl0 = *(const short8v*)&W1b_lo[row0 * 128 + kof];
        short8v bl1 = *(const short8v*)&W1b_lo[row1 * 128 + kof];
#pragma unroll
        for (int mt = 0; mt < 2; ++mt) {
            short8v ah = *(short8v*)&H_hi[(mt * 16 + cl) * 136 + kof];
            short8v al = *(short8v*)&H_lo[(mt * 16 + cl) * 136 + kof];
            acc[mt][0] = MFMA_BF16(ah, bh0, acc[mt][0], 0, 0, 0);
            acc[mt][0] = MFMA_BF16(al, bh0, acc[mt][0], 0, 0, 0);
            acc[mt][0] = MFMA_BF16(ah, bl0, acc[mt][0], 0, 0, 0);
            acc[mt][1] = MFMA_BF16(ah, bh1, acc[mt][1], 0, 0, 0);
            acc[mt][1] = MFMA_BF16(al, bh1, acc[mt][1], 0, 0, 0);
            acc[mt][1] = MFMA_BF16(ah, bl1, acc[mt][1], 0, 0, 0);
        }
    }
    // epilogue B -> h1out (f32, bias+relu)
    {
        float c0 = b1b[row0], c1 = b1b[row1];
#pragma unroll
        for (int mt = 0; mt < 2; ++mt)
#pragma unroll
            for (int j = 0; j < 4; ++j) {
                int gn = nbase + mt * 16 + kq * 4 + j;
                if (gn < NN) {
                    h1out[gn * 128 + row0] = fmaxf(acc[mt][0][j] + c0, 0.f);
                    h1out[gn * 128 + row1] = fmaxf(acc[mt][1][j] + c1, 0.f);
                }
            }
    }
}

// ---------------- MLP 2 (split-bf16 MFMA, W direct from global) + fused pool ----------
// LDS: A_hi@0, A_lo@8704 ([32][136] each); H_hi@17408, H_lo@26112; batch@34816.
// P f32 [32][132] (16896 B) aliases A region after final barrier.

#define M2_AHI 0
#define M2_ALO 8704
#define M2_HHI 17408
#define M2_HLO 26112
#define M2_B   34816
#define M2_SMEM 34944

__global__ __launch_bounds__(256) void k_mlp2(
        const float* __restrict__ h1, const float* __restrict__ agg2,
        const ushort* __restrict__ W2a_hi, const ushort* __restrict__ W2a_lo,
        const float* __restrict__ b2a,
        const ushort* __restrict__ W2b_hi, const ushort* __restrict__ W2b_lo,
        const float* __restrict__ b2b,
        const int* __restrict__ batch, float* __restrict__ pooled) {
    __shared__ __align__(16) char smem[M2_SMEM];
    ushort* A_hi = (ushort*)(smem + M2_AHI);
    ushort* A_lo = (ushort*)(smem + M2_ALO);
    ushort* H_hi = (ushort*)(smem + M2_HHI);
    ushort* H_lo = (ushort*)(smem + M2_HLO);
    int* batch_s = (int*)(smem + M2_B);
    int t = threadIdx.x;
    int nbase = blockIdx.x * 32;

    if (t < 32) batch_s[t] = (nbase + t < NN) ? batch[nbase + t] : -1;

    // stage A = h1 + agg2, split hi/lo
    for (int i = t; i < 512; i += 256) {
        int n = i >> 4, cc = (i & 15) * 8;
        int gn = nbase + n;
        short8v vh = {0,0,0,0,0,0,0,0}, vl = {0,0,0,0,0,0,0,0};
        if (gn < NN) {
            const float4* hp = (const float4*)&h1[gn * 128 + cc];
            const float4* gp = (const float4*)&agg2[gn * 128 + cc];
            float s[8];
            float4 a0 = hp[0], a1 = hp[1], g0 = gp[0], g1 = gp[1];
            s[0]=a0.x+g0.x; s[1]=a0.y+g0.y; s[2]=a0.z+g0.z; s[3]=a0.w+g0.w;
            s[4]=a1.x+g1.x; s[5]=a1.y+g1.y; s[6]=a1.z+g1.z; s[7]=a1.w+g1.w;
#pragma unroll
            for (int j = 0; j < 8; ++j) {
                ushort h = f2bf(s[j]);
                vh[j] = (short)h;
                vl[j] = (short)f2bf(s[j] - bf2f(h));
            }
        }
        *(short8v*)&A_hi[n * 136 + cc] = vh;
        *(short8v*)&A_lo[n * 136 + cc] = vl;
    }
    __syncthreads();

    int w = t >> 6, l = t & 63;
    int cl = l & 15, kq = l >> 4;
    int row0 = w * 32 + cl, row1 = w * 32 + 16 + cl;

    f32x4 acc[2][2];
#pragma unroll
    for (int mt = 0; mt < 2; ++mt) { acc[mt][0] = f32x4{0.f,0.f,0.f,0.f}; acc[mt][1] = f32x4{0.f,0.f,0.f,0.f}; }

    // phase A: (h1+agg2) @ W2a, K=128, W direct from global
#pragma unroll
    for (int ksl = 0; ksl < 4; ++ksl) {
        int kof = ksl * 32 + kq * 8;
        short8v bh0 = *(const short8v*)&W2a_hi[row0 * 128 + kof];
        short8v bh1 = *(const short8v*)&W2a_hi[row1 * 128 + kof];
        short8v bl0 = *(const short8v*)&W2a_lo[row0 * 128 + kof];
        short8v bl1 = *(const short8v*)&W2a_lo[row1 * 128 + kof];
#pragma unroll
        for (int mt = 0; mt < 2; ++mt) {
            short8v ah = *(short8v*)&A_hi[(mt * 16 + cl) * 136 + kof];
            short8v al = *(short8v*)&A_lo[(mt * 16 + cl) * 136 + kof];
            acc[mt][0] = MFMA_BF16(ah, bh0, acc[mt][0], 0, 0, 0);
            acc[mt][0] = MFMA_BF16(al, bh0, acc[mt][0], 0, 0, 0);
            acc[mt][0] = MFMA_BF16(ah, bl0, acc[mt][0], 0, 0, 0);
            acc[mt][1] = MFMA_BF16(ah, bh1, acc[mt][1], 0, 0, 0);
            acc[mt][1] = MFMA_BF16(al, bh1, acc[mt][1], 0, 0, 0);
            acc[mt][1] = MFMA_BF16(ah, bl1, acc[mt][1], 0, 0, 0);
        }
    }
    // epilogue A -> H (bias+relu, split)
    {
        float bb0 = b2a[row0], bb1 = b2a[row1];
#pragma unroll
        for (int mt = 0; mt < 2; ++mt)
#pragma unroll
            for (int j = 0; j < 4; ++j) {
                int row = mt * 16 + kq * 4 + j;
                float v0 = fmaxf(acc[mt][0][j] + bb0, 0.f);
                float v1 = fmaxf(acc[mt][1][j] + bb1, 0.f);
                ushort h0 = f2bf(v0), h1v = f2bf(v1);
                H_hi[row * 136 + row0] = h0;
                H_lo[row * 136 + row0] = f2bf(v0 - bf2f(h0));
                H_hi[row * 136 + row1] = h1v;
                H_lo[row * 136 + row1] = f2bf(v1 - bf2f(h1v));
            }
    }
    __syncthreads();

    // phase B: hid @ W2b, K=128, W direct from global
#pragma unroll
    for (int mt = 0; mt < 2; ++mt) { acc[mt][0] = f32x4{0.f,0.f,0.f,0.f}; acc[mt][1] = f32x4{0.f,0.f,0.f,0.f}; }
#pragma unroll
    for (int ksl = 0; ksl < 4; ++ksl) {
        int kof = ksl * 32 + kq * 8;
        short8v bh0 = *(const short8v*)&W2b_hi[row0 * 128 + kof];
        short8v bh1 = *(const short8v*)&W2b_hi[row1 * 128 + kof];
        short8v bl0 = *(const short8v*)&W2b_lo[row0 * 128 + kof];
        short8v bl1 = *(const short8v*)&W2b_lo[row1 * 128 + kof];
#pragma unroll
        for (int mt = 0; mt < 2; ++mt) {
            short8v ah = *(short8v*)&H_hi[(mt * 16 + cl) * 136 + kof];
            short8v al = *(short8v*)&H_lo[(mt * 16 + cl) * 136 + kof];
            acc[mt][0] = MFMA_BF16(ah, bh0, acc[mt][0], 0, 0, 0);
            acc[mt][0] = MFMA_BF16(al, bh0, acc[mt][0], 0, 0, 0);
            acc[mt][0] = MFMA_BF16(ah, bl0, acc[mt][0], 0, 0, 0);
            acc[mt][1] = MFMA_BF16(ah, bh1, acc[mt][1], 0, 0, 0);
            acc[mt][1] = MFMA_BF16(al, bh1, acc[mt][1], 0, 0, 0);
            acc[mt][1] = MFMA_BF16(ah, bl1, acc[mt][1], 0, 0, 0);
        }
    }
    __syncthreads();   // all H reads done before P overwrites A region? (P aliases A, not H)
    // epilogue B -> f32 tile P (aliases A region; all A reads done), then pool
    float* P = (float*)smem;  // [32][132]
    {
        float c0 = b2b[row0], c1 = b2b[row1];
#pragma unroll
        for (int mt = 0; mt < 2; ++mt)
#pragma unroll
            for (int j = 0; j < 4; ++j) {
                int row = mt * 16 + kq * 4 + j;
                P[row * 132 + row0] = fmaxf(acc[mt][0][j] + c0, 0.f);
                P[row * 132 + row1] = fmaxf(acc[mt][1][j] + c1, 0.f);
            }
    }
    __syncthreads();

    // pool: batch sorted; two halves of 16 nodes, run-length + atomics
    {
        int c = t & 127, half = t >> 7;
        int i0 = half * 16;
        float run = 0.f;
        int cur = batch_s[i0];
        if (cur >= 0) {
            for (int i = i0; i < i0 + 16; ++i) {
                int b = batch_s[i];
                if (b < 0) break;
                if (b != cur) { atomicAdd(&pooled[cur * 128 + c], run); run = 0.f; cur = b; }
                run += P[i * 132 + c];
            }
            atomicAdd(&pooled[cur * 128 + c], run);
        }
    }
}

// ---------------- Readout: relu(pooled@Wm1+bm1)@Wm2+bm2 ----------------

__global__ __launch_bounds__(128) void k_readout(
        const float* __restrict__ pooled, const float* __restrict__ Wm1,
        const float* __restrict__ bm1, const float* __restrict__ Wm2,
        const float* __restrict__ bm2, float* __restrict__ out) {
    __shared__ float row[128];
    __shared__ float red[128];
    int g = blockIdx.x, t = threadIdx.x;
    row[t] = pooled[g * 128 + t];
    __syncthreads();
    float acc = bm1[t];
    for (int c = 0; c < 128; ++c) acc = fmaf(row[c], Wm1[c * 128 + t], acc);
    float term = fmaxf(acc, 0.f) * Wm2[t];
    red[t] = term;
    __syncthreads();
    for (int off = 64; off > 0; off >>= 1) {
        if (t < off) red[t] += red[t + off];
        __syncthreads();
    }
    if (t == 0) out[g] = red[0] + bm2[0];
}

// ---------------- Launch ----------------

extern "C" void kernel_launch(void* const* d_in, const int* in_sizes, int n_in,
                              void* d_out, int out_size, void* d_ws, size_t ws_size,
                              hipStream_t stream) {
    const float* x    = (const float*)d_in[0];
    const int* eidx   = (const int*)d_in[1];
    const float* ea   = (const float*)d_in[2];
    const int* batch  = (const int*)d_in[3];
    const float* We1  = (const float*)d_in[4];
    const float* be1  = (const float*)d_in[5];
    const float* W1a  = (const float*)d_in[6];
    const float* b1a  = (const float*)d_in[7];
    const float* W1b  = (const float*)d_in[8];
    const float* b1b  = (const float*)d_in[9];
    const float* We2  = (const float*)d_in[10];
    const float* be2  = (const float*)d_in[11];
    const float* W2a  = (const float*)d_in[12];
    const float* b2a  = (const float*)d_in[13];
    const float* W2b  = (const float*)d_in[14];
    const float* b2b  = (const float*)d_in[15];
    const float* Wm1  = (const float*)d_in[16];
    const float* bm1  = (const float*)d_in[17];
    const float* Wm2  = (const float*)d_in[18];
    const float* bm2  = (const float*)d_in[19];
    float* out = (float*)d_out;

    const int* src = eidx;
    const int* dst = eidx + NE;

    char* w = (char*)d_ws;
    auto alloc = [&](size_t bytes) { void* p = (void*)w; w += (bytes + 255) & ~(size_t)255; return p; };
    int* counts    = (int*)alloc(NN * 4);
    int* row_ptr   = (int*)alloc((NN + 1) * 4);
    int* cursor    = (int*)alloc(NN * 4);
    int* bsum      = (int*)alloc(512 * 4);
    float4* csr    = (float4*)alloc((size_t)NE * 16);
    float* agg1    = (float*)alloc((size_t)NN * 32 * 4);
    float* h1      = (float*)alloc((size_t)NN * 128 * 4);
    float* agg2    = (float*)alloc((size_t)NN * 128 * 4);
    float* pooled  = (float*)alloc((size_t)NG * 128 * 4);
    ushort* W1a_hi = (ushort*)alloc(4096 * 2);
    ushort* W1a_lo = (ushort*)alloc(4096 * 2);
    ushort* W1b_hi = (ushort*)alloc(16384 * 2);
    ushort* W1b_lo = (ushort*)alloc(16384 * 2);
    ushort* W2a_hi = (ushort*)alloc(16384 * 2);
    ushort* W2a_lo = (ushort*)alloc(16384 * 2);
    ushort* W2b_hi = (ushort*)alloc(16384 * 2);
    ushort* W2b_lo = (ushort*)alloc(16384 * 2);

    hipMemsetAsync(counts, 0, NN * 4, stream);
    hipMemsetAsync(pooled, 0, (size_t)NG * 128 * 4, stream);

    const int EB = (NE + 255) / 256;       // 6250
    const int NB = (NN + 255) / 256;       // 391
    const int MB = (NN + 31) / 32;         // 3125

    k_prep<<<208, 256, 0, stream>>>(W1a, W1b, W2a, W2b,
                                    W1a_hi, W1a_lo, W1b_hi, W1b_lo,
                                    W2a_hi, W2a_lo, W2b_hi, W2b_lo);
    k_count<<<EB, 256, 0, stream>>>(dst, counts);
    k_bsum<<<NB, 256, 0, stream>>>(counts, bsum);
    k_scan512<<<1, 512, 0, stream>>>(bsum, NB);
    k_scan_counts<<<NB, 256, 0, stream>>>(counts, bsum, row_ptr, cursor);
    k_fill<<<EB, 256, 0, stream>>>(src, dst, ea, cursor, csr);

    k_agg1<<<NN / 8, 256, 0, stream>>>(x, csr, row_ptr, We1, be1, agg1);
    k_mlp1<<<MB, 256, 0, stream>>>(x, agg1, W1a_hi, W1a_lo, b1a, W1b_hi, W1b_lo, b1b, h1);
    k_agg2<<<NN / 2, 256, 0, stream>>>(h1, csr, row_ptr, We2, be2, agg2);
    k_mlp2<<<MB, 256, 0, stream>>>(h1, agg2, W2a_hi, W2a_lo, b2a, W2b_hi, W2b_lo, b2b, batch, pooled);
    k_readout<<<NG, 128, 0, stream>>>(pooled, Wm1, bm1, Wm2, bm2, out);
}

// Round 7
// 527.683 us; speedup vs baseline: 3.5496x; 1.0754x over previous
//
#include <hip/hip_runtime.h>
#include <hip/hip_bf16.h>

#define NN 100000
#define NE 1600000
#define NG 2048

typedef __attribute__((ext_vector_type(8))) short short8v;
typedef __attribute__((ext_vector_type(4))) float f32x4;

__device__ inline ushort f2bf(float f) {
    // round-to-nearest-even f32 -> bf16
    uint u = __float_as_uint(f);
    uint r = (u + 0x7fffu + ((u >> 16) & 1u)) >> 16;
    return (ushort)r;
}
__device__ inline float bf2f(ushort h) {
    return __uint_as_float(((uint)h) << 16);
}

#define MFMA_BF16 __builtin_amdgcn_mfma_f32_16x16x32_bf16

// MFMA B-fragment permutation: element (out-ch c, k) -> flat offset.
// Wave w, lane l reads contiguous 16B at ((ksl*4+w)*2+half)*512 + l*8.
__device__ inline int frag128(int k, int c) {
    int w = c >> 5, half = (c >> 4) & 1, cl = c & 15;
    int ksl = k >> 5, kq = (k >> 3) & 3, k0 = k & 7;
    return ((ksl * 4 + w) * 2 + half) * 512 + (kq * 16 + cl) * 8 + k0;
}
__device__ inline int frag32(int k, int c) {
    int w = c >> 5, half = (c >> 4) & 1, cl = c & 15;
    int kq = (k >> 3) & 3, k0 = k & 7;
    return (w * 2 + half) * 512 + (kq * 16 + cl) * 8 + k0;
}

// ---------------- CSR build ----------------

__global__ void k_count(const int* __restrict__ dst, int* __restrict__ counts) {
    int e = blockIdx.x * 256 + threadIdx.x;
    if (e < NE) atomicAdd(&counts[dst[e]], 1);
}

__global__ void k_bsum(const int* __restrict__ counts, int* __restrict__ bsum) {
    __shared__ int s[256];
    int t = threadIdx.x;
    int i = blockIdx.x * 256 + t;
    s[t] = (i < NN) ? counts[i] : 0;
    __syncthreads();
    for (int off = 128; off > 0; off >>= 1) {
        if (t < off) s[t] += s[t + off];
        __syncthreads();
    }
    if (t == 0) bsum[blockIdx.x] = s[0];
}

__global__ void k_scan512(int* __restrict__ data, int n) {
    __shared__ int s[512];
    int t = threadIdx.x;
    int v = (t < n) ? data[t] : 0;
    s[t] = v;
    __syncthreads();
    for (int off = 1; off < 512; off <<= 1) {
        int add = (t >= off) ? s[t - off] : 0;
        __syncthreads();
        s[t] += add;
        __syncthreads();
    }
    if (t < n) data[t] = s[t] - v;  // exclusive
}

__global__ void k_scan_counts(const int* __restrict__ counts, const int* __restrict__ bsum,
                              int* __restrict__ row_ptr, int* __restrict__ cursor) {
    __shared__ int s[256];
    int t = threadIdx.x, i = blockIdx.x * 256 + t;
    int v = (i < NN) ? counts[i] : 0;
    s[t] = v;
    __syncthreads();
    for (int off = 1; off < 256; off <<= 1) {
        int add = (t >= off) ? s[t - off] : 0;
        __syncthreads();
        s[t] += add;
        __syncthreads();
    }
    int excl = s[t] - v + bsum[blockIdx.x];
    if (i < NN) { row_ptr[i] = excl; cursor[i] = excl; }
    if (i == NN - 1) row_ptr[NN] = excl + v;
}

__global__ void k_fill(const int* __restrict__ src, const int* __restrict__ dst,
                       const float* __restrict__ ea, int* __restrict__ cursor,
                       float4* __restrict__ csr) {
    int e = blockIdx.x * 256 + threadIdx.x;
    if (e >= NE) return;
    int d = dst[e];
    int p = atomicAdd(&cursor[d], 1);
    csr[p] = make_float4(__int_as_float(src[e]), ea[3 * e], ea[3 * e + 1], ea[3 * e + 2]);
}

// ---------------- weight prep: f32 [K][C] -> bf16 hi/lo in MFMA-fragment order -------

__global__ void k_prep(const float* __restrict__ W1a, const float* __restrict__ W1b,
                       const float* __restrict__ W2a, const float* __restrict__ W2b,
                       ushort* __restrict__ W1a_hi, ushort* __restrict__ W1a_lo,
                       ushort* __restrict__ W1b_hi, ushort* __restrict__ W1b_lo,
                       ushort* __restrict__ W2a_hi, ushort* __restrict__ W2a_lo,
                       ushort* __restrict__ W2b_hi, ushort* __restrict__ W2b_lo) {
    int i = blockIdx.x * 256 + threadIdx.x;
    float v; ushort* ph; ushort* pl; int off;
    if (i < 4096) {                       // W1a: [32][128]
        int k = i >> 7, c = i & 127;
        v = W1a[i]; ph = W1a_hi; pl = W1a_lo; off = frag32(k, c);
    } else if (i < 20480) {               // W1b: [128][128]
        int j = i - 4096; int k = j >> 7, c = j & 127;
        v = W1b[j]; ph = W1b_hi; pl = W1b_lo; off = frag128(k, c);
    } else if (i < 36864) {               // W2a
        int j = i - 20480; int k = j >> 7, c = j & 127;
        v = W2a[j]; ph = W2a_hi; pl = W2a_lo; off = frag128(k, c);
    } else if (i < 53248) {               // W2b
        int j = i - 36864; int k = j >> 7, c = j & 127;
        v = W2b[j]; ph = W2b_hi; pl = W2b_lo; off = frag128(k, c);
    } else return;
    ushort h = f2bf(v);
    ph[off] = h;
    pl[off] = f2bf(v - bf2f(h));
}

// ---------------- Layer 1 aggregation (gather, 32 ch), 8-deep pipelined ----------------

__global__ __launch_bounds__(256) void k_agg1(
        const float* __restrict__ x, const float4* __restrict__ csr,
        const int* __restrict__ row_ptr,
        const float* __restrict__ We1, const float* __restrict__ be1,
        float* __restrict__ agg1) {
    int lane = threadIdx.x & 31;
    int node = blockIdx.x * 8 + (threadIdx.x >> 5);
    float w0 = We1[lane], w1 = We1[32 + lane], w2 = We1[64 + lane], b = be1[lane];
    int p0 = row_ptr[node], p1 = row_ptr[node + 1];
    float acc = 0.f;
    int p = p0;
    for (; p + 8 <= p1; p += 8) {
        float4 e[8]; float v[8];
#pragma unroll
        for (int j = 0; j < 8; ++j) e[j] = csr[p + j];
#pragma unroll
        for (int j = 0; j < 8; ++j) v[j] = x[__float_as_int(e[j].x) * 32 + lane];
#pragma unroll
        for (int j = 0; j < 8; ++j) {
            float el = fmaf(e[j].y, w0, fmaf(e[j].z, w1, fmaf(e[j].w, w2, b)));
            acc += fmaxf(v[j] + el, 0.f);
        }
    }
    for (; p + 4 <= p1; p += 4) {
        float4 e[4]; float v[4];
#pragma unroll
        for (int j = 0; j < 4; ++j) e[j] = csr[p + j];
#pragma unroll
        for (int j = 0; j < 4; ++j) v[j] = x[__float_as_int(e[j].x) * 32 + lane];
#pragma unroll
        for (int j = 0; j < 4; ++j) {
            float el = fmaf(e[j].y, w0, fmaf(e[j].z, w1, fmaf(e[j].w, w2, b)));
            acc += fmaxf(v[j] + el, 0.f);
        }
    }
    for (; p < p1; ++p) {
        float4 ed = csr[p];
        int s = __float_as_int(ed.x);
        float el = fmaf(ed.y, w0, fmaf(ed.z, w1, fmaf(ed.w, w2, b)));
        acc += fmaxf(x[s * 32 + lane] + el, 0.f);
    }
    agg1[node * 32 + lane] = acc;
}

// ---------------- Layer 2 aggregation (bf16 h1 gather, 128 ch), 8-deep ----------------

__global__ __launch_bounds__(256) void k_agg2(
        const ushort* __restrict__ h1b, const float4* __restrict__ csr,
        const int* __restrict__ row_ptr,
        const float* __restrict__ We2, const float* __restrict__ be2,
        float* __restrict__ agg2) {
    int lane = threadIdx.x & 127;
    int node = blockIdx.x * 2 + (threadIdx.x >> 7);
    float w0 = We2[lane], w1 = We2[128 + lane], w2 = We2[256 + lane], b = be2[lane];
    int p0 = row_ptr[node], p1 = row_ptr[node + 1];
    float acc = 0.f;
    int p = p0;
    for (; p + 8 <= p1; p += 8) {
        float4 e[8]; ushort u[8];
#pragma unroll
        for (int j = 0; j < 8; ++j) e[j] = csr[p + j];
#pragma unroll
        for (int j = 0; j < 8; ++j) u[j] = h1b[__float_as_int(e[j].x) * 128 + lane];
#pragma unroll
        for (int j = 0; j < 8; ++j) {
            float el = fmaf(e[j].y, w0, fmaf(e[j].z, w1, fmaf(e[j].w, w2, b)));
            acc += fmaxf(bf2f(u[j]) + el, 0.f);
        }
    }
    for (; p + 4 <= p1; p += 4) {
        float4 e[4]; ushort u[4];
#pragma unroll
        for (int j = 0; j < 4; ++j) e[j] = csr[p + j];
#pragma unroll
        for (int j = 0; j < 4; ++j) u[j] = h1b[__float_as_int(e[j].x) * 128 + lane];
#pragma unroll
        for (int j = 0; j < 4; ++j) {
            float el = fmaf(e[j].y, w0, fmaf(e[j].z, w1, fmaf(e[j].w, w2, b)));
            acc += fmaxf(bf2f(u[j]) + el, 0.f);
        }
    }
    for (; p < p1; ++p) {
        float4 ed = csr[p];
        int s = __float_as_int(ed.x);
        float el = fmaf(ed.y, w0, fmaf(ed.z, w1, fmaf(ed.w, w2, b)));
        acc += fmaxf(bf2f(h1b[s * 128 + lane]) + el, 0.f);
    }
    agg2[node * 128 + lane] = acc;
}

// ---------------- MLP 1 (split-bf16 MFMA, fragment-coalesced W from global) ----------
// 32 nodes/block, 4 waves; wave w owns out-ch [w*32, w*32+32), m-tiles 0..1.
// Output h1 stored as bf16 only (h1b).

#define M1_AHI 0
#define M1_ALO 2560
#define M1_HHI 5120
#define M1_HLO 13824
#define M1_SMEM 22528

__global__ __launch_bounds__(256) void k_mlp1(
        const float* __restrict__ x, const float* __restrict__ agg1,
        const ushort* __restrict__ W1a_hi, const ushort* __restrict__ W1a_lo,
        const float* __restrict__ b1a,
        const ushort* __restrict__ W1b_hi, const ushort* __restrict__ W1b_lo,
        const float* __restrict__ b1b,
        ushort* __restrict__ h1b) {
    __shared__ __align__(16) char smem[M1_SMEM];
    ushort* A_hi = (ushort*)(smem + M1_AHI);   // [32][40]
    ushort* A_lo = (ushort*)(smem + M1_ALO);   // [32][40]
    ushort* H_hi = (ushort*)(smem + M1_HHI);   // [32][136]
    ushort* H_lo = (ushort*)(smem + M1_HLO);   // [32][136]
    int t = threadIdx.x;
    int nbase = blockIdx.x * 32;

    // stage A = x + agg1, split hi/lo
    if (t < 128) {
        int n = t >> 2, cc = (t & 3) * 8;
        int gn = nbase + n;
        short8v vh = {0,0,0,0,0,0,0,0}, vl = {0,0,0,0,0,0,0,0};
        if (gn < NN) {
            const float4* xp = (const float4*)&x[gn * 32 + cc];
            const float4* gp = (const float4*)&agg1[gn * 32 + cc];
            float s[8];
            float4 x0 = xp[0], x1 = xp[1], g0 = gp[0], g1 = gp[1];
            s[0]=x0.x+g0.x; s[1]=x0.y+g0.y; s[2]=x0.z+g0.z; s[3]=x0.w+g0.w;
            s[4]=x1.x+g1.x; s[5]=x1.y+g1.y; s[6]=x1.z+g1.z; s[7]=x1.w+g1.w;
#pragma unroll
            for (int j = 0; j < 8; ++j) {
                ushort h = f2bf(s[j]);
                vh[j] = (short)h;
                vl[j] = (short)f2bf(s[j] - bf2f(h));
            }
        }
        *(short8v*)&A_hi[n * 40 + cc] = vh;
        *(short8v*)&A_lo[n * 40 + cc] = vl;
    }
    __syncthreads();

    int w = t >> 6, l = t & 63;
    int cl = l & 15, kq = l >> 4;
    int row0 = w * 32 + cl, row1 = w * 32 + 16 + cl;

    f32x4 acc[2][2];
#pragma unroll
    for (int mt = 0; mt < 2; ++mt) { acc[mt][0] = f32x4{0.f,0.f,0.f,0.f}; acc[mt][1] = f32x4{0.f,0.f,0.f,0.f}; }

    // phase A: K=32, 3-term split; W1a fragment-coalesced from global
    {
        int kof = kq * 8;
        int fb = (w * 2) * 512 + l * 8;
        short8v bh0 = *(const short8v*)&W1a_hi[fb];
        short8v bh1 = *(const short8v*)&W1a_hi[fb + 512];
        short8v bl0 = *(const short8v*)&W1a_lo[fb];
        short8v bl1 = *(const short8v*)&W1a_lo[fb + 512];
#pragma unroll
        for (int mt = 0; mt < 2; ++mt) {
            short8v ah = *(short8v*)&A_hi[(mt * 16 + cl) * 40 + kof];
            short8v al = *(short8v*)&A_lo[(mt * 16 + cl) * 40 + kof];
            acc[mt][0] = MFMA_BF16(ah, bh0, acc[mt][0], 0, 0, 0);
            acc[mt][0] = MFMA_BF16(al, bh0, acc[mt][0], 0, 0, 0);
            acc[mt][0] = MFMA_BF16(ah, bl0, acc[mt][0], 0, 0, 0);
            acc[mt][1] = MFMA_BF16(ah, bh1, acc[mt][1], 0, 0, 0);
            acc[mt][1] = MFMA_BF16(al, bh1, acc[mt][1], 0, 0, 0);
            acc[mt][1] = MFMA_BF16(ah, bl1, acc[mt][1], 0, 0, 0);
        }
    }
    // epilogue A -> H (bias+relu, split)
    {
        float bb0 = b1a[row0], bb1 = b1a[row1];
#pragma unroll
        for (int mt = 0; mt < 2; ++mt)
#pragma unroll
            for (int j = 0; j < 4; ++j) {
                int row = mt * 16 + kq * 4 + j;
                float v0 = fmaxf(acc[mt][0][j] + bb0, 0.f);
                float v1 = fmaxf(acc[mt][1][j] + bb1, 0.f);
                ushort h0 = f2bf(v0), h1v = f2bf(v1);
                H_hi[row * 136 + row0] = h0;
                H_lo[row * 136 + row0] = f2bf(v0 - bf2f(h0));
                H_hi[row * 136 + row1] = h1v;
                H_lo[row * 136 + row1] = f2bf(v1 - bf2f(h1v));
            }
    }
    __syncthreads();

    // phase B: K=128 from H; W1b fragment-coalesced, 4 k-slices
#pragma unroll
    for (int mt = 0; mt < 2; ++mt) { acc[mt][0] = f32x4{0.f,0.f,0.f,0.f}; acc[mt][1] = f32x4{0.f,0.f,0.f,0.f}; }
#pragma unroll
    for (int ksl = 0; ksl < 4; ++ksl) {
        int kof = ksl * 32 + kq * 8;
        int fb = ((ksl * 4 + w) * 2) * 512 + l * 8;
        short8v bh0 = *(const short8v*)&W1b_hi[fb];
        short8v bh1 = *(const short8v*)&W1b_hi[fb + 512];
        short8v bl0 = *(const short8v*)&W1b_lo[fb];
        short8v bl1 = *(const short8v*)&W1b_lo[fb + 512];
#pragma unroll
        for (int mt = 0; mt < 2; ++mt) {
            short8v ah = *(short8v*)&H_hi[(mt * 16 + cl) * 136 + kof];
            short8v al = *(short8v*)&H_lo[(mt * 16 + cl) * 136 + kof];
            acc[mt][0] = MFMA_BF16(ah, bh0, acc[mt][0], 0, 0, 0);
            acc[mt][0] = MFMA_BF16(al, bh0, acc[mt][0], 0, 0, 0);
            acc[mt][0] = MFMA_BF16(ah, bl0, acc[mt][0], 0, 0, 0);
            acc[mt][1] = MFMA_BF16(ah, bh1, acc[mt][1], 0, 0, 0);
            acc[mt][1] = MFMA_BF16(al, bh1, acc[mt][1], 0, 0, 0);
            acc[mt][1] = MFMA_BF16(ah, bl1, acc[mt][1], 0, 0, 0);
        }
    }
    // epilogue B -> h1b (bf16, bias+relu)
    {
        float c0 = b1b[row0], c1 = b1b[row1];
#pragma unroll
        for (int mt = 0; mt < 2; ++mt)
#pragma unroll
            for (int j = 0; j < 4; ++j) {
                int gn = nbase + mt * 16 + kq * 4 + j;
                if (gn < NN) {
                    h1b[gn * 128 + row0] = f2bf(fmaxf(acc[mt][0][j] + c0, 0.f));
                    h1b[gn * 128 + row1] = f2bf(fmaxf(acc[mt][1][j] + c1, 0.f));
                }
            }
    }
}

// ---------------- MLP 2 (split-bf16 MFMA, fragment W) + fused pool ----------
// LDS: A_hi@0, A_lo@8704 ([32][136] each); H_hi@17408, H_lo@26112; batch@34816.
// P f32 [32][132] (16896 B) aliases A region after final barrier.

#define M2_AHI 0
#define M2_ALO 8704
#define M2_HHI 17408
#define M2_HLO 26112
#define M2_B   34816
#define M2_SMEM 34944

__global__ __launch_bounds__(256) void k_mlp2(
        const ushort* __restrict__ h1b, const float* __restrict__ agg2,
        const ushort* __restrict__ W2a_hi, const ushort* __restrict__ W2a_lo,
        const float* __restrict__ b2a,
        const ushort* __restrict__ W2b_hi, const ushort* __restrict__ W2b_lo,
        const float* __restrict__ b2b,
        const int* __restrict__ batch, float* __restrict__ pooled) {
    __shared__ __align__(16) char smem[M2_SMEM];
    ushort* A_hi = (ushort*)(smem + M2_AHI);
    ushort* A_lo = (ushort*)(smem + M2_ALO);
    ushort* H_hi = (ushort*)(smem + M2_HHI);
    ushort* H_lo = (ushort*)(smem + M2_HLO);
    int* batch_s = (int*)(smem + M2_B);
    int t = threadIdx.x;
    int nbase = blockIdx.x * 32;

    if (t < 32) batch_s[t] = (nbase + t < NN) ? batch[nbase + t] : -1;

    // stage A = h1(bf16) + agg2, split hi/lo
    for (int i = t; i < 512; i += 256) {
        int n = i >> 4, cc = (i & 15) * 8;
        int gn = nbase + n;
        short8v vh = {0,0,0,0,0,0,0,0}, vl = {0,0,0,0,0,0,0,0};
        if (gn < NN) {
            short8v hb = *(const short8v*)&h1b[gn * 128 + cc];
            const float4* gp = (const float4*)&agg2[gn * 128 + cc];
            float4 g0 = gp[0], g1 = gp[1];
            float s[8];
            s[0]=bf2f((ushort)hb[0])+g0.x; s[1]=bf2f((ushort)hb[1])+g0.y;
            s[2]=bf2f((ushort)hb[2])+g0.z; s[3]=bf2f((ushort)hb[3])+g0.w;
            s[4]=bf2f((ushort)hb[4])+g1.x; s[5]=bf2f((ushort)hb[5])+g1.y;
            s[6]=bf2f((ushort)hb[6])+g1.z; s[7]=bf2f((ushort)hb[7])+g1.w;
#pragma unroll
            for (int j = 0; j < 8; ++j) {
                ushort h = f2bf(s[j]);
                vh[j] = (short)h;
                vl[j] = (short)f2bf(s[j] - bf2f(h));
            }
        }
        *(short8v*)&A_hi[n * 136 + cc] = vh;
        *(short8v*)&A_lo[n * 136 + cc] = vl;
    }
    __syncthreads();

    int w = t >> 6, l = t & 63;
    int cl = l & 15, kq = l >> 4;
    int row0 = w * 32 + cl, row1 = w * 32 + 16 + cl;

    f32x4 acc[2][2];
#pragma unroll
    for (int mt = 0; mt < 2; ++mt) { acc[mt][0] = f32x4{0.f,0.f,0.f,0.f}; acc[mt][1] = f32x4{0.f,0.f,0.f,0.f}; }

    // phase A: (h1+agg2) @ W2a, K=128, fragment W
#pragma unroll
    for (int ksl = 0; ksl < 4; ++ksl) {
        int kof = ksl * 32 + kq * 8;
        int fb = ((ksl * 4 + w) * 2) * 512 + l * 8;
        short8v bh0 = *(const short8v*)&W2a_hi[fb];
        short8v bh1 = *(const short8v*)&W2a_hi[fb + 512];
        short8v bl0 = *(const short8v*)&W2a_lo[fb];
        short8v bl1 = *(const short8v*)&W2a_lo[fb + 512];
#pragma unroll
        for (int mt = 0; mt < 2; ++mt) {
            short8v ah = *(short8v*)&A_hi[(mt * 16 + cl) * 136 + kof];
            short8v al = *(short8v*)&A_lo[(mt * 16 + cl) * 136 + kof];
            acc[mt][0] = MFMA_BF16(ah, bh0, acc[mt][0], 0, 0, 0);
            acc[mt][0] = MFMA_BF16(al, bh0, acc[mt][0], 0, 0, 0);
            acc[mt][0] = MFMA_BF16(ah, bl0, acc[mt][0], 0, 0, 0);
            acc[mt][1] = MFMA_BF16(ah, bh1, acc[mt][1], 0, 0, 0);
            acc[mt][1] = MFMA_BF16(al, bh1, acc[mt][1], 0, 0, 0);
            acc[mt][1] = MFMA_BF16(ah, bl1, acc[mt][1], 0, 0, 0);
        }
    }
    // epilogue A -> H (bias+relu, split)
    {
        float bb0 = b2a[row0], bb1 = b2a[row1];
#pragma unroll
        for (int mt = 0; mt < 2; ++mt)
#pragma unroll
            for (int j = 0; j < 4; ++j) {
                int row = mt * 16 + kq * 4 + j;
                float v0 = fmaxf(acc[mt][0][j] + bb0, 0.f);
                float v1 = fmaxf(acc[mt][1][j] + bb1, 0.f);
                ushort h0 = f2bf(v0), h1v = f2bf(v1);
                H_hi[row * 136 + row0] = h0;
                H_lo[row * 136 + row0] = f2bf(v0 - bf2f(h0));
                H_hi[row * 136 + row1] = h1v;
                H_lo[row * 136 + row1] = f2bf(v1 - bf2f(h1v));
            }
    }
    __syncthreads();

    // phase B: hid @ W2b, K=128, fragment W
#pragma unroll
    for (int mt = 0; mt < 2; ++mt) { acc[mt][0] = f32x4{0.f,0.f,0.f,0.f}; acc[mt][1] = f32x4{0.f,0.f,0.f,0.f}; }
#pragma unroll
    for (int ksl = 0; ksl < 4; ++ksl) {
        int kof = ksl * 32 + kq * 8;
        int fb = ((ksl * 4 + w) * 2) * 512 + l * 8;
        short8v bh0 = *(const short8v*)&W2b_hi[fb];
        short8v bh1 = *(const short8v*)&W2b_hi[fb + 512];
        short8v bl0 = *(const short8v*)&W2b_lo[fb];
        short8v bl1 = *(const short8v*)&W2b_lo[fb + 512];
#pragma unroll
        for (int mt = 0; mt < 2; ++mt) {
            short8v ah = *(short8v*)&H_hi[(mt * 16 + cl) * 136 + kof];
            short8v al = *(short8v*)&H_lo[(mt * 16 + cl) * 136 + kof];
            acc[mt][0] = MFMA_BF16(ah, bh0, acc[mt][0], 0, 0, 0);
            acc[mt][0] = MFMA_BF16(al, bh0, acc[mt][0], 0, 0, 0);
            acc[mt][0] = MFMA_BF16(ah, bl0, acc[mt][0], 0, 0, 0);
            acc[mt][1] = MFMA_BF16(ah, bh1, acc[mt][1], 0, 0, 0);
            acc[mt][1] = MFMA_BF16(al, bh1, acc[mt][1], 0, 0, 0);
            acc[mt][1] = MFMA_BF16(ah, bl1, acc[mt][1], 0, 0, 0);
        }
    }
    __syncthreads();
    // epilogue B -> f32 tile P (aliases A region; all A reads done), then pool
    float* P = (float*)smem;  // [32][132]
    {
        float c0 = b2b[row0], c1 = b2b[row1];
#pragma unroll
        for (int mt = 0; mt < 2; ++mt)
#pragma unroll
            for (int j = 0; j < 4; ++j) {
                int row = mt * 16 + kq * 4 + j;
                P[row * 132 + row0] = fmaxf(acc[mt][0][j] + c0, 0.f);
                P[row * 132 + row1] = fmaxf(acc[mt][1][j] + c1, 0.f);
            }
    }
    __syncthreads();

    // pool: batch sorted; two halves of 16 nodes, run-length + atomics
    {
        int c = t & 127, half = t >> 7;
        int i0 = half * 16;
        float run = 0.f;
        int cur = batch_s[i0];
        if (cur >= 0) {
            for (int i = i0; i < i0 + 16; ++i) {
                int b = batch_s[i];
                if (b < 0) break;
                if (b != cur) { atomicAdd(&pooled[cur * 128 + c], run); run = 0.f; cur = b; }
                run += P[i * 132 + c];
            }
            atomicAdd(&pooled[cur * 128 + c], run);
        }
    }
}

// ---------------- Readout: relu(pooled@Wm1+bm1)@Wm2+bm2 ----------------

__global__ __launch_bounds__(128) void k_readout(
        const float* __restrict__ pooled, const float* __restrict__ Wm1,
        const float* __restrict__ bm1, const float* __restrict__ Wm2,
        const float* __restrict__ bm2, float* __restrict__ out) {
    __shared__ float row[128];
    __shared__ float red[128];
    int g = blockIdx.x, t = threadIdx.x;
    row[t] = pooled[g * 128 + t];
    __syncthreads();
    float acc = bm1[t];
    for (int c = 0; c < 128; ++c) acc = fmaf(row[c], Wm1[c * 128 + t], acc);
    float term = fmaxf(acc, 0.f) * Wm2[t];
    red[t] = term;
    __syncthreads();
    for (int off = 64; off > 0; off >>= 1) {
        if (t < off) red[t] += red[t + off];
        __syncthreads();
    }
    if (t == 0) out[g] = red[0] + bm2[0];
}

// ---------------- Launch ----------------

extern "C" void kernel_launch(void* const* d_in, const int* in_sizes, int n_in,
                              void* d_out, int out_size, void* d_ws, size_t ws_size,
                              hipStream_t stream) {
    const float* x    = (const float*)d_in[0];
    const int* eidx   = (const int*)d_in[1];
    const float* ea   = (const float*)d_in[2];
    const int* batch  = (const int*)d_in[3];
    const float* We1  = (const float*)d_in[4];
    const float* be1  = (const float*)d_in[5];
    const float* W1a  = (const float*)d_in[6];
    const float* b1a  = (const float*)d_in[7];
    const float* W1b  = (const float*)d_in[8];
    const float* b1b  = (const float*)d_in[9];
    const float* We2  = (const float*)d_in[10];
    const float* be2  = (const float*)d_in[11];
    const float* W2a  = (const float*)d_in[12];
    const float* b2a  = (const float*)d_in[13];
    const float* W2b  = (const float*)d_in[14];
    const float* b2b  = (const float*)d_in[15];
    const float* Wm1  = (const float*)d_in[16];
    const float* bm1  = (const float*)d_in[17];
    const float* Wm2  = (const float*)d_in[18];
    const float* bm2  = (const float*)d_in[19];
    float* out = (float*)d_out;

    const int* src = eidx;
    const int* dst = eidx + NE;

    char* w = (char*)d_ws;
    auto alloc = [&](size_t bytes) { void* p = (void*)w; w += (bytes + 255) & ~(size_t)255; return p; };
    int* counts    = (int*)alloc(NN * 4);
    int* row_ptr   = (int*)alloc((NN + 1) * 4);
    int* cursor    = (int*)alloc(NN * 4);
    int* bsum      = (int*)alloc(512 * 4);
    float4* csr    = (float4*)alloc((size_t)NE * 16);
    float* agg1    = (float*)alloc((size_t)NN * 32 * 4);
    ushort* h1b    = (ushort*)alloc((size_t)NN * 128 * 2);
    float* agg2    = (float*)alloc((size_t)NN * 128 * 4);
    float* pooled  = (float*)alloc((size_t)NG * 128 * 4);
    ushort* W1a_hi = (ushort*)alloc(4096 * 2);
    ushort* W1a_lo = (ushort*)alloc(4096 * 2);
    ushort* W1b_hi = (ushort*)alloc(16384 * 2);
    ushort* W1b_lo = (ushort*)alloc(16384 * 2);
    ushort* W2a_hi = (ushort*)alloc(16384 * 2);
    ushort* W2a_lo = (ushort*)alloc(16384 * 2);
    ushort* W2b_hi = (ushort*)alloc(16384 * 2);
    ushort* W2b_lo = (ushort*)alloc(16384 * 2);

    hipMemsetAsync(counts, 0, NN * 4, stream);
    hipMemsetAsync(pooled, 0, (size_t)NG * 128 * 4, stream);

    const int EB = (NE + 255) / 256;       // 6250
    const int NB = (NN + 255) / 256;       // 391
    const int MB = (NN + 31) / 32;         // 3125

    k_prep<<<208, 256, 0, stream>>>(W1a, W1b, W2a, W2b,
                                    W1a_hi, W1a_lo, W1b_hi, W1b_lo,
                                    W2a_hi, W2a_lo, W2b_hi, W2b_lo);
    k_count<<<EB, 256, 0, stream>>>(dst, counts);
    k_bsum<<<NB, 256, 0, stream>>>(counts, bsum);
    k_scan512<<<1, 512, 0, stream>>>(bsum, NB);
    k_scan_counts<<<NB, 256, 0, stream>>>(counts, bsum, row_ptr, cursor);
    k_fill<<<EB, 256, 0, stream>>>(src, dst, ea, cursor, csr);

    k_agg1<<<NN / 8, 256, 0, stream>>>(x, csr, row_ptr, We1, be1, agg1);
    k_mlp1<<<MB, 256, 0, stream>>>(x, agg1, W1a_hi, W1a_lo, b1a, W1b_hi, W1b_lo, b1b, h1b);
    k_agg2<<<NN / 2, 256, 0, stream>>>(h1b, csr, row_ptr, We2, be2, agg2);
    k_mlp2<<<MB, 256, 0, stream>>>(h1b, agg2, W2a_hi, W2a_lo, b2a, W2b_hi, W2b_lo, b2b, batch, pooled);
    k_readout<<<NG, 128, 0, stream>>>(pooled, Wm1, bm1, Wm2, bm2, out);
}

// Round 9
// 475.446 us; speedup vs baseline: 3.9395x; 1.1099x over previous
//
#include <hip/hip_runtime.h>
#include <hip/hip_bf16.h>

#define NN 100000
#define NE 1600000
#define NG 2048

typedef __attribute__((ext_vector_type(8))) short short8v;
typedef __attribute__((ext_vector_type(4))) float f32x4;

__device__ inline ushort f2bf(float f) {
    // round-to-nearest-even f32 -> bf16
    uint u = __float_as_uint(f);
    uint r = (u + 0x7fffu + ((u >> 16) & 1u)) >> 16;
    return (ushort)r;
}
__device__ inline float bf2f(ushort h) {
    return __uint_as_float(((uint)h) << 16);
}

#define MFMA_BF16 __builtin_amdgcn_mfma_f32_16x16x32_bf16

// MFMA B-fragment permutation: element (out-ch c, k) -> flat offset.
// Wave w, lane l reads contiguous 16B at ((ksl*4+w)*2+half)*512 + l*8.
__device__ inline int frag128(int k, int c) {
    int w = c >> 5, half = (c >> 4) & 1, cl = c & 15;
    int ksl = k >> 5, kq = (k >> 3) & 3, k0 = k & 7;
    return ((ksl * 4 + w) * 2 + half) * 512 + (kq * 16 + cl) * 8 + k0;
}
__device__ inline int frag32(int k, int c) {
    int w = c >> 5, half = (c >> 4) & 1, cl = c & 15;
    int kq = (k >> 3) & 3, k0 = k & 7;
    return (w * 2 + half) * 512 + (kq * 16 + cl) * 8 + k0;
}

// ---------------- CSR build ----------------

__global__ void k_count(const int* __restrict__ dst, int* __restrict__ counts) {
    int e = blockIdx.x * 256 + threadIdx.x;
    if (e < NE) atomicAdd(&counts[dst[e]], 1);
}

__global__ void k_bsum(const int* __restrict__ counts, int* __restrict__ bsum) {
    __shared__ int s[256];
    int t = threadIdx.x;
    int i = blockIdx.x * 256 + t;
    s[t] = (i < NN) ? counts[i] : 0;
    __syncthreads();
    for (int off = 128; off > 0; off >>= 1) {
        if (t < off) s[t] += s[t + off];
        __syncthreads();
    }
    if (t == 0) bsum[blockIdx.x] = s[0];
}

__global__ void k_scan512(int* __restrict__ data, int n) {
    __shared__ int s[512];
    int t = threadIdx.x;
    int v = (t < n) ? data[t] : 0;
    s[t] = v;
    __syncthreads();
    for (int off = 1; off < 512; off <<= 1) {
        int add = (t >= off) ? s[t - off] : 0;
        __syncthreads();
        s[t] += add;
        __syncthreads();
    }
    if (t < n) data[t] = s[t] - v;  // exclusive
}

__global__ void k_scan_counts(const int* __restrict__ counts, const int* __restrict__ bsum,
                              int* __restrict__ row_ptr, int* __restrict__ cursor) {
    __shared__ int s[256];
    int t = threadIdx.x, i = blockIdx.x * 256 + t;
    int v = (i < NN) ? counts[i] : 0;
    s[t] = v;
    __syncthreads();
    for (int off = 1; off < 256; off <<= 1) {
        int add = (t >= off) ? s[t - off] : 0;
        __syncthreads();
        s[t] += add;
        __syncthreads();
    }
    int excl = s[t] - v + bsum[blockIdx.x];
    if (i < NN) { row_ptr[i] = excl; cursor[i] = excl; }
    if (i == NN - 1) row_ptr[NN] = excl + v;
}

__global__ void k_fill(const int* __restrict__ src, const int* __restrict__ dst,
                       const float* __restrict__ ea, int* __restrict__ cursor,
                       float4* __restrict__ csr) {
    int e = blockIdx.x * 256 + threadIdx.x;
    if (e >= NE) return;
    int d = dst[e];
    int p = atomicAdd(&cursor[d], 1);
    csr[p] = make_float4(__int_as_float(src[e]), ea[3 * e], ea[3 * e + 1], ea[3 * e + 2]);
}

// ---------------- weight prep: f32 [K][C] -> bf16 hi/lo in MFMA-fragment order -------

__global__ void k_prep(const float* __restrict__ W1a, const float* __restrict__ W1b,
                       const float* __restrict__ W2a, const float* __restrict__ W2b,
                       ushort* __restrict__ W1a_hi, ushort* __restrict__ W1a_lo,
                       ushort* __restrict__ W1b_hi, ushort* __restrict__ W1b_lo,
                       ushort* __restrict__ W2a_hi, ushort* __restrict__ W2a_lo,
                       ushort* __restrict__ W2b_hi, ushort* __restrict__ W2b_lo) {
    int i = blockIdx.x * 256 + threadIdx.x;
    float v; ushort* ph; ushort* pl; int off;
    if (i < 4096) {                       // W1a: [32][128]
        int k = i >> 7, c = i & 127;
        v = W1a[i]; ph = W1a_hi; pl = W1a_lo; off = frag32(k, c);
    } else if (i < 20480) {               // W1b: [128][128]
        int j = i - 4096; int k = j >> 7, c = j & 127;
        v = W1b[j]; ph = W1b_hi; pl = W1b_lo; off = frag128(k, c);
    } else if (i < 36864) {               // W2a
        int j = i - 20480; int k = j >> 7, c = j & 127;
        v = W2a[j]; ph = W2a_hi; pl = W2a_lo; off = frag128(k, c);
    } else if (i < 53248) {               // W2b
        int j = i - 36864; int k = j >> 7, c = j & 127;
        v = W2b[j]; ph = W2b_hi; pl = W2b_lo; off = frag128(k, c);
    } else return;
    ushort h = f2bf(v);
    ph[off] = h;
    pl[off] = f2bf(v - bf2f(h));
}

// ---------------- Layer 1 aggregation (gather, 32 ch), 8-deep pipelined ----------------

__global__ __launch_bounds__(256) void k_agg1(
        const float* __restrict__ x, const float4* __restrict__ csr,
        const int* __restrict__ row_ptr,
        const float* __restrict__ We1, const float* __restrict__ be1,
        float* __restrict__ agg1) {
    int lane = threadIdx.x & 31;
    int node = blockIdx.x * 8 + (threadIdx.x >> 5);
    float w0 = We1[lane], w1 = We1[32 + lane], w2 = We1[64 + lane], b = be1[lane];
    int p0 = row_ptr[node], p1 = row_ptr[node + 1];
    float acc = 0.f;
    int p = p0;
    for (; p + 8 <= p1; p += 8) {
        float4 e[8]; float v[8];
#pragma unroll
        for (int j = 0; j < 8; ++j) e[j] = csr[p + j];
#pragma unroll
        for (int j = 0; j < 8; ++j) v[j] = x[__float_as_int(e[j].x) * 32 + lane];
#pragma unroll
        for (int j = 0; j < 8; ++j) {
            float el = fmaf(e[j].y, w0, fmaf(e[j].z, w1, fmaf(e[j].w, w2, b)));
            acc += fmaxf(v[j] + el, 0.f);
        }
    }
    for (; p + 4 <= p1; p += 4) {
        float4 e[4]; float v[4];
#pragma unroll
        for (int j = 0; j < 4; ++j) e[j] = csr[p + j];
#pragma unroll
        for (int j = 0; j < 4; ++j) v[j] = x[__float_as_int(e[j].x) * 32 + lane];
#pragma unroll
        for (int j = 0; j < 4; ++j) {
            float el = fmaf(e[j].y, w0, fmaf(e[j].z, w1, fmaf(e[j].w, w2, b)));
            acc += fmaxf(v[j] + el, 0.f);
        }
    }
    for (; p < p1; ++p) {
        float4 ed = csr[p];
        int s = __float_as_int(ed.x);
        float el = fmaf(ed.y, w0, fmaf(ed.z, w1, fmaf(ed.w, w2, b)));
        acc += fmaxf(x[s * 32 + lane] + el, 0.f);
    }
    agg1[node * 32 + lane] = acc;
}

// ---------------- Layer 2 aggregation: 1 wave/node, 2 ch/lane (ushort2) --------------
// Wave's 64 lanes x 4B cover the full 256B h1b row -> ONE gather instr per edge.

__global__ __launch_bounds__(256) void k_agg2(
        const ushort* __restrict__ h1b, const float4* __restrict__ csr,
        const int* __restrict__ row_ptr,
        const float* __restrict__ We2, const float* __restrict__ be2,
        float* __restrict__ agg2) {
    int lane = threadIdx.x & 63;
    int node = blockIdx.x * 4 + (threadIdx.x >> 6);
    int c = lane * 2;
    float w0a = We2[c],       w0b = We2[c + 1];
    float w1a = We2[128 + c], w1b = We2[129 + c];
    float w2a = We2[256 + c], w2b = We2[257 + c];
    float ba  = be2[c],       bb  = be2[c + 1];
    const uint* h1u = (const uint*)h1b;   // ushort2 as uint; rows of 64 uints
    int p0 = row_ptr[node], p1 = row_ptr[node + 1];
    float accA = 0.f, accB = 0.f;
    int p = p0;
    for (; p + 8 <= p1; p += 8) {
        float4 e[8]; uint u[8];
#pragma unroll
        for (int j = 0; j < 8; ++j) e[j] = csr[p + j];
#pragma unroll
        for (int j = 0; j < 8; ++j) u[j] = h1u[__float_as_int(e[j].x) * 64 + lane];
#pragma unroll
        for (int j = 0; j < 8; ++j) {
            float elA = fmaf(e[j].y, w0a, fmaf(e[j].z, w1a, fmaf(e[j].w, w2a, ba)));
            float elB = fmaf(e[j].y, w0b, fmaf(e[j].z, w1b, fmaf(e[j].w, w2b, bb)));
            accA += fmaxf(bf2f((ushort)(u[j] & 0xffffu)) + elA, 0.f);
            accB += fmaxf(bf2f((ushort)(u[j] >> 16)) + elB, 0.f);
        }
    }
    for (; p + 4 <= p1; p += 4) {
        float4 e[4]; uint u[4];
#pragma unroll
        for (int j = 0; j < 4; ++j) e[j] = csr[p + j];
#pragma unroll
        for (int j = 0; j < 4; ++j) u[j] = h1u[__float_as_int(e[j].x) * 64 + lane];
#pragma unroll
        for (int j = 0; j < 4; ++j) {
            float elA = fmaf(e[j].y, w0a, fmaf(e[j].z, w1a, fmaf(e[j].w, w2a, ba)));
            float elB = fmaf(e[j].y, w0b, fmaf(e[j].z, w1b, fmaf(e[j].w, w2b, bb)));
            accA += fmaxf(bf2f((ushort)(u[j] & 0xffffu)) + elA, 0.f);
            accB += fmaxf(bf2f((ushort)(u[j] >> 16)) + elB, 0.f);
        }
    }
    for (; p < p1; ++p) {
        float4 ed = csr[p];
        uint u = h1u[__float_as_int(ed.x) * 64 + lane];
        float elA = fmaf(ed.y, w0a, fmaf(ed.z, w1a, fmaf(ed.w, w2a, ba)));
        float elB = fmaf(ed.y, w0b, fmaf(ed.z, w1b, fmaf(ed.w, w2b, bb)));
        accA += fmaxf(bf2f((ushort)(u & 0xffffu)) + elA, 0.f);
        accB += fmaxf(bf2f((ushort)(u >> 16)) + elB, 0.f);
    }
    *(float2*)&agg2[node * 128 + c] = make_float2(accA, accB);
}

// ---------------- MLP 1 (split-bf16 MFMA, fragment-coalesced W from global) ----------
// 32 nodes/block, 4 waves; wave w owns out-ch [w*32, w*32+32), m-tiles 0..1.
// Output h1 stored as bf16 only (h1b).

#define M1_AHI 0
#define M1_ALO 2560
#define M1_HHI 5120
#define M1_HLO 13824
#define M1_SMEM 22528

__global__ __launch_bounds__(256) void k_mlp1(
        const float* __restrict__ x, const float* __restrict__ agg1,
        const ushort* __restrict__ W1a_hi, const ushort* __restrict__ W1a_lo,
        const float* __restrict__ b1a,
        const ushort* __restrict__ W1b_hi, const ushort* __restrict__ W1b_lo,
        const float* __restrict__ b1b,
        ushort* __restrict__ h1b) {
    __shared__ __align__(16) char smem[M1_SMEM];
    ushort* A_hi = (ushort*)(smem + M1_AHI);   // [32][40]
    ushort* A_lo = (ushort*)(smem + M1_ALO);   // [32][40]
    ushort* H_hi = (ushort*)(smem + M1_HHI);   // [32][136]
    ushort* H_lo = (ushort*)(smem + M1_HLO);   // [32][136]
    int t = threadIdx.x;
    int nbase = blockIdx.x * 32;

    // stage A = x + agg1, split hi/lo
    if (t < 128) {
        int n = t >> 2, cc = (t & 3) * 8;
        int gn = nbase + n;
        short8v vh = {0,0,0,0,0,0,0,0}, vl = {0,0,0,0,0,0,0,0};
        if (gn < NN) {
            const float4* xp = (const float4*)&x[gn * 32 + cc];
            const float4* gp = (const float4*)&agg1[gn * 32 + cc];
            float s[8];
            float4 x0 = xp[0], x1 = xp[1], g0 = gp[0], g1 = gp[1];
            s[0]=x0.x+g0.x; s[1]=x0.y+g0.y; s[2]=x0.z+g0.z; s[3]=x0.w+g0.w;
            s[4]=x1.x+g1.x; s[5]=x1.y+g1.y; s[6]=x1.z+g1.z; s[7]=x1.w+g1.w;
#pragma unroll
            for (int j = 0; j < 8; ++j) {
                ushort h = f2bf(s[j]);
                vh[j] = (short)h;
                vl[j] = (short)f2bf(s[j] - bf2f(h));
            }
        }
        *(short8v*)&A_hi[n * 40 + cc] = vh;
        *(short8v*)&A_lo[n * 40 + cc] = vl;
    }
    __syncthreads();

    int w = t >> 6, l = t & 63;
    int cl = l & 15, kq = l >> 4;
    int row0 = w * 32 + cl, row1 = w * 32 + 16 + cl;

    f32x4 acc[2][2];
#pragma unroll
    for (int mt = 0; mt < 2; ++mt) { acc[mt][0] = f32x4{0.f,0.f,0.f,0.f}; acc[mt][1] = f32x4{0.f,0.f,0.f,0.f}; }

    // phase A: K=32, 3-term split; W1a fragment-coalesced from global
    {
        int kof = kq * 8;
        int fb = (w * 2) * 512 + l * 8;
        short8v bh0 = *(const short8v*)&W1a_hi[fb];
        short8v bh1 = *(const short8v*)&W1a_hi[fb + 512];
        short8v bl0 = *(const short8v*)&W1a_lo[fb];
        short8v bl1 = *(const short8v*)&W1a_lo[fb + 512];
#pragma unroll
        for (int mt = 0; mt < 2; ++mt) {
            short8v ah = *(short8v*)&A_hi[(mt * 16 + cl) * 40 + kof];
            short8v al = *(short8v*)&A_lo[(mt * 16 + cl) * 40 + kof];
            acc[mt][0] = MFMA_BF16(ah, bh0, acc[mt][0], 0, 0, 0);
            acc[mt][0] = MFMA_BF16(al, bh0, acc[mt][0], 0, 0, 0);
            acc[mt][0] = MFMA_BF16(ah, bl0, acc[mt][0], 0, 0, 0);
            acc[mt][1] = MFMA_BF16(ah, bh1, acc[mt][1], 0, 0, 0);
            acc[mt][1] = MFMA_BF16(al, bh1, acc[mt][1], 0, 0, 0);
            acc[mt][1] = MFMA_BF16(ah, bl1, acc[mt][1], 0, 0, 0);
        }
    }
    // epilogue A -> H (bias+relu, split)
    {
        float bb0 = b1a[row0], bb1 = b1a[row1];
#pragma unroll
        for (int mt = 0; mt < 2; ++mt)
#pragma unroll
            for (int j = 0; j < 4; ++j) {
                int row = mt * 16 + kq * 4 + j;
                float v0 = fmaxf(acc[mt][0][j] + bb0, 0.f);
                float v1 = fmaxf(acc[mt][1][j] + bb1, 0.f);
                ushort h0 = f2bf(v0), h1v = f2bf(v1);
                H_hi[row * 136 + row0] = h0;
                H_lo[row * 136 + row0] = f2bf(v0 - bf2f(h0));
                H_hi[row * 136 + row1] = h1v;
                H_lo[row * 136 + row1] = f2bf(v1 - bf2f(h1v));
            }
    }
    __syncthreads();

    // phase B: K=128 from H; W1b fragment-coalesced, 4 k-slices
#pragma unroll
    for (int mt = 0; mt < 2; ++mt) { acc[mt][0] = f32x4{0.f,0.f,0.f,0.f}; acc[mt][1] = f32x4{0.f,0.f,0.f,0.f}; }
#pragma unroll
    for (int ksl = 0; ksl < 4; ++ksl) {
        int kof = ksl * 32 + kq * 8;
        int fb = ((ksl * 4 + w) * 2) * 512 + l * 8;
        short8v bh0 = *(const short8v*)&W1b_hi[fb];
        short8v bh1 = *(const short8v*)&W1b_hi[fb + 512];
        short8v bl0 = *(const short8v*)&W1b_lo[fb];
        short8v bl1 = *(const short8v*)&W1b_lo[fb + 512];
#pragma unroll
        for (int mt = 0; mt < 2; ++mt) {
            short8v ah = *(short8v*)&H_hi[(mt * 16 + cl) * 136 + kof];
            short8v al = *(short8v*)&H_lo[(mt * 16 + cl) * 136 + kof];
            acc[mt][0] = MFMA_BF16(ah, bh0, acc[mt][0], 0, 0, 0);
            acc[mt][0] = MFMA_BF16(al, bh0, acc[mt][0], 0, 0, 0);
            acc[mt][0] = MFMA_BF16(ah, bl0, acc[mt][0], 0, 0, 0);
            acc[mt][1] = MFMA_BF16(ah, bh1, acc[mt][1], 0, 0, 0);
            acc[mt][1] = MFMA_BF16(al, bh1, acc[mt][1], 0, 0, 0);
            acc[mt][1] = MFMA_BF16(ah, bl1, acc[mt][1], 0, 0, 0);
        }
    }
    // epilogue B -> h1b (bf16, bias+relu)
    {
        float c0 = b1b[row0], c1 = b1b[row1];
#pragma unroll
        for (int mt = 0; mt < 2; ++mt)
#pragma unroll
            for (int j = 0; j < 4; ++j) {
                int gn = nbase + mt * 16 + kq * 4 + j;
                if (gn < NN) {
                    h1b[gn * 128 + row0] = f2bf(fmaxf(acc[mt][0][j] + c0, 0.f));
                    h1b[gn * 128 + row1] = f2bf(fmaxf(acc[mt][1][j] + c1, 0.f));
                }
            }
    }
}

// ---------------- MLP 2 (split-bf16 MFMA, fragment W) + fused pool ----------
// LDS: A_hi@0, A_lo@8704 ([32][136] each); H_hi@17408, H_lo@26112; batch@34816.
// P f32 [32][132] (16896 B) aliases A region after final barrier.

#define M2_AHI 0
#define M2_ALO 8704
#define M2_HHI 17408
#define M2_HLO 26112
#define M2_B   34816
#define M2_SMEM 34944

__global__ __launch_bounds__(256) void k_mlp2(
        const ushort* __restrict__ h1b, const float* __restrict__ agg2,
        const ushort* __restrict__ W2a_hi, const ushort* __restrict__ W2a_lo,
        const float* __restrict__ b2a,
        const ushort* __restrict__ W2b_hi, const ushort* __restrict__ W2b_lo,
        const float* __restrict__ b2b,
        const int* __restrict__ batch, float* __restrict__ pooled) {
    __shared__ __align__(16) char smem[M2_SMEM];
    ushort* A_hi = (ushort*)(smem + M2_AHI);
    ushort* A_lo = (ushort*)(smem + M2_ALO);
    ushort* H_hi = (ushort*)(smem + M2_HHI);
    ushort* H_lo = (ushort*)(smem + M2_HLO);
    int* batch_s = (int*)(smem + M2_B);
    int t = threadIdx.x;
    int nbase = blockIdx.x * 32;

    if (t < 32) batch_s[t] = (nbase + t < NN) ? batch[nbase + t] : -1;

    // stage A = h1(bf16) + agg2, split hi/lo
    for (int i = t; i < 512; i += 256) {
        int n = i >> 4, cc = (i & 15) * 8;
        int gn = nbase + n;
        short8v vh = {0,0,0,0,0,0,0,0}, vl = {0,0,0,0,0,0,0,0};
        if (gn < NN) {
            short8v hb = *(const short8v*)&h1b[gn * 128 + cc];
            const float4* gp = (const float4*)&agg2[gn * 128 + cc];
            float4 g0 = gp[0], g1 = gp[1];
            float s[8];
            s[0]=bf2f((ushort)hb[0])+g0.x; s[1]=bf2f((ushort)hb[1])+g0.y;
            s[2]=bf2f((ushort)hb[2])+g0.z; s[3]=bf2f((ushort)hb[3])+g0.w;
            s[4]=bf2f((ushort)hb[4])+g1.x; s[5]=bf2f((ushort)hb[5])+g1.y;
            s[6]=bf2f((ushort)hb[6])+g1.z; s[7]=bf2f((ushort)hb[7])+g1.w;
#pragma unroll
            for (int j = 0; j < 8; ++j) {
                ushort h = f2bf(s[j]);
                vh[j] = (short)h;
                vl[j] = (short)f2bf(s[j] - bf2f(h));
            }
        }
        *(short8v*)&A_hi[n * 136 + cc] = vh;
        *(short8v*)&A_lo[n * 136 + cc] = vl;
    }
    __syncthreads();

    int w = t >> 6, l = t & 63;
    int cl = l & 15, kq = l >> 4;
    int row0 = w * 32 + cl, row1 = w * 32 + 16 + cl;

    f32x4 acc[2][2];
#pragma unroll
    for (int mt = 0; mt < 2; ++mt) { acc[mt][0] = f32x4{0.f,0.f,0.f,0.f}; acc[mt][1] = f32x4{0.f,0.f,0.f,0.f}; }

    // phase A: (h1+agg2) @ W2a, K=128, fragment W
#pragma unroll
    for (int ksl = 0; ksl < 4; ++ksl) {
        int kof = ksl * 32 + kq * 8;
        int fb = ((ksl * 4 + w) * 2) * 512 + l * 8;
        short8v bh0 = *(const short8v*)&W2a_hi[fb];
        short8v bh1 = *(const short8v*)&W2a_hi[fb + 512];
        short8v bl0 = *(const short8v*)&W2a_lo[fb];
        short8v bl1 = *(const short8v*)&W2a_lo[fb + 512];
#pragma unroll
        for (int mt = 0; mt < 2; ++mt) {
            short8v ah = *(short8v*)&A_hi[(mt * 16 + cl) * 136 + kof];
            short8v al = *(short8v*)&A_lo[(mt * 16 + cl) * 136 + kof];
            acc[mt][0] = MFMA_BF16(ah, bh0, acc[mt][0], 0, 0, 0);
            acc[mt][0] = MFMA_BF16(al, bh0, acc[mt][0], 0, 0, 0);
            acc[mt][0] = MFMA_BF16(ah, bl0, acc[mt][0], 0, 0, 0);
            acc[mt][1] = MFMA_BF16(ah, bh1, acc[mt][1], 0, 0, 0);
            acc[mt][1] = MFMA_BF16(al, bh1, acc[mt][1], 0, 0, 0);
            acc[mt][1] = MFMA_BF16(ah, bl1, acc[mt][1], 0, 0, 0);
        }
    }
    // epilogue A -> H (bias+relu, split)
    {
        float bb0 = b2a[row0], bb1 = b2a[row1];
#pragma unroll
        for (int mt = 0; mt < 2; ++mt)
#pragma unroll
            for (int j = 0; j < 4; ++j) {
                int row = mt * 16 + kq * 4 + j;
                float v0 = fmaxf(acc[mt][0][j] + bb0, 0.f);
                float v1 = fmaxf(acc[mt][1][j] + bb1, 0.f);
                ushort h0 = f2bf(v0), h1v = f2bf(v1);
                H_hi[row * 136 + row0] = h0;
                H_lo[row * 136 + row0] = f2bf(v0 - bf2f(h0));
                H_hi[row * 136 + row1] = h1v;
                H_lo[row * 136 + row1] = f2bf(v1 - bf2f(h1v));
            }
    }
    __syncthreads();

    // phase B: hid @ W2b, K=128, fragment W
#pragma unroll
    for (int mt = 0; mt < 2; ++mt) { acc[mt][0] = f32x4{0.f,0.f,0.f,0.f}; acc[mt][1] = f32x4{0.f,0.f,0.f,0.f}; }
#pragma unroll
    for (int ksl = 0; ksl < 4; ++ksl) {
        int kof = ksl * 32 + kq * 8;
        int fb = ((ksl * 4 + w) * 2) * 512 + l * 8;
        short8v bh0 = *(const short8v*)&W2b_hi[fb];
        short8v bh1 = *(const short8v*)&W2b_hi[fb + 512];
        short8v bl0 = *(const short8v*)&W2b_lo[fb];
        short8v bl1 = *(const short8v*)&W2b_lo[fb + 512];
#pragma unroll
        for (int mt = 0; mt < 2; ++mt) {
            short8v ah = *(short8v*)&H_hi[(mt * 16 + cl) * 136 + kof];
            short8v al = *(short8v*)&H_lo[(mt * 16 + cl) * 136 + kof];
            acc[mt][0] = MFMA_BF16(ah, bh0, acc[mt][0], 0, 0, 0);
            acc[mt][0] = MFMA_BF16(al, bh0, acc[mt][0], 0, 0, 0);
            acc[mt][0] = MFMA_BF16(ah, bl0, acc[mt][0], 0, 0, 0);
            acc[mt][1] = MFMA_BF16(ah, bh1, acc[mt][1], 0, 0, 0);
            acc[mt][1] = MFMA_BF16(al, bh1, acc[mt][1], 0, 0, 0);
            acc[mt][1] = MFMA_BF16(ah, bl1, acc[mt][1], 0, 0, 0);
        }
    }
    __syncthreads();
    // epilogue B -> f32 tile P (aliases A region; all A reads done), then pool
    float* P = (float*)smem;  // [32][132]
    {
        float c0 = b2b[row0], c1 = b2b[row1];
#pragma unroll
        for (int mt = 0; mt < 2; ++mt)
#pragma unroll
            for (int j = 0; j < 4; ++j) {
                int row = mt * 16 + kq * 4 + j;
                P[row * 132 + row0] = fmaxf(acc[mt][0][j] + c0, 0.f);
                P[row * 132 + row1] = fmaxf(acc[mt][1][j] + c1, 0.f);
            }
    }
    __syncthreads();

    // pool: batch sorted; two halves of 16 nodes, run-length + atomics
    {
        int c = t & 127, half = t >> 7;
        int i0 = half * 16;
        float run = 0.f;
        int cur = batch_s[i0];
        if (cur >= 0) {
            for (int i = i0; i < i0 + 16; ++i) {
                int b = batch_s[i];
                if (b < 0) break;
                if (b != cur) { atomicAdd(&pooled[cur * 128 + c], run); run = 0.f; cur = b; }
                run += P[i * 132 + c];
            }
            atomicAdd(&pooled[cur * 128 + c], run);
        }
    }
}

// ---------------- Readout: relu(pooled@Wm1+bm1)@Wm2+bm2 ----------------

__global__ __launch_bounds__(128) void k_readout(
        const float* __restrict__ pooled, const float* __restrict__ Wm1,
        const float* __restrict__ bm1, const float* __restrict__ Wm2,
        const float* __restrict__ bm2, float* __restrict__ out) {
    __shared__ float row[128];
    __shared__ float red[128];
    int g = blockIdx.x, t = threadIdx.x;
    row[t] = pooled[g * 128 + t];
    __syncthreads();
    float acc = bm1[t];
    for (int c = 0; c < 128; ++c) acc = fmaf(row[c], Wm1[c * 128 + t], acc);
    float term = fmaxf(acc, 0.f) * Wm2[t];
    red[t] = term;
    __syncthreads();
    for (int off = 64; off > 0; off >>= 1) {
        if (t < off) red[t] += red[t + off];
        __syncthreads();
    }
    if (t == 0) out[g] = red[0] + bm2[0];
}

// ---------------- Launch ----------------

extern "C" void kernel_launch(void* const* d_in, const int* in_sizes, int n_in,
                              void* d_out, int out_size, void* d_ws, size_t ws_size,
                              hipStream_t stream) {
    const float* x    = (const float*)d_in[0];
    const int* eidx   = (const int*)d_in[1];
    const float* ea   = (const float*)d_in[2];
    const int* batch  = (const int*)d_in[3];
    const float* We1  = (const float*)d_in[4];
    const float* be1  = (const float*)d_in[5];
    const float* W1a  = (const float*)d_in[6];
    const float* b1a  = (const float*)d_in[7];
    const float* W1b  = (const float*)d_in[8];
    const float* b1b  = (const float*)d_in[9];
    const float* We2  = (const float*)d_in[10];
    const float* be2  = (const float*)d_in[11];
    const float* W2a  = (const float*)d_in[12];
    const float* b2a  = (const float*)d_in[13];
    const float* W2b  = (const float*)d_in[14];
    const float* b2b  = (const float*)d_in[15];
    const float* Wm1  = (const float*)d_in[16];
    const float* bm1  = (const float*)d_in[17];
    const float* Wm2  = (const float*)d_in[18];
    const float* bm2  = (const float*)d_in[19];
    float* out = (float*)d_out;

    const int* src = eidx;
    const int* dst = eidx + NE;

    char* w = (char*)d_ws;
    auto alloc = [&](size_t bytes) { void* p = (void*)w; w += (bytes + 255) & ~(size_t)255; return p; };
    int* counts    = (int*)alloc(NN * 4);
    int* row_ptr   = (int*)alloc((NN + 1) * 4);
    int* cursor    = (int*)alloc(NN * 4);
    int* bsum      = (int*)alloc(512 * 4);
    float4* csr    = (float4*)alloc((size_t)NE * 16);
    float* agg1    = (float*)alloc((size_t)NN * 32 * 4);
    ushort* h1b    = (ushort*)alloc((size_t)NN * 128 * 2);
    float* agg2    = (float*)alloc((size_t)NN * 128 * 4);
    float* pooled  = (float*)alloc((size_t)NG * 128 * 4);
    ushort* W1a_hi = (ushort*)alloc(4096 * 2);
    ushort* W1a_lo = (ushort*)alloc(4096 * 2);
    ushort* W1b_hi = (ushort*)alloc(16384 * 2);
    ushort* W1b_lo = (ushort*)alloc(16384 * 2);
    ushort* W2a_hi = (ushort*)alloc(16384 * 2);
    ushort* W2a_lo = (ushort*)alloc(16384 * 2);
    ushort* W2b_hi = (ushort*)alloc(16384 * 2);
    ushort* W2b_lo = (ushort*)alloc(16384 * 2);

    hipMemsetAsync(counts, 0, NN * 4, stream);
    hipMemsetAsync(pooled, 0, (size_t)NG * 128 * 4, stream);

    const int EB = (NE + 255) / 256;       // 6250
    const int NB = (NN + 255) / 256;       // 391
    const int MB = (NN + 31) / 32;         // 3125

    k_prep<<<208, 256, 0, stream>>>(W1a, W1b, W2a, W2b,
                                    W1a_hi, W1a_lo, W1b_hi, W1b_lo,
                                    W2a_hi, W2a_lo, W2b_hi, W2b_lo);
    k_count<<<EB, 256, 0, stream>>>(dst, counts);
    k_bsum<<<NB, 256, 0, stream>>>(counts, bsum);
    k_scan512<<<1, 512, 0, stream>>>(bsum, NB);
    k_scan_counts<<<NB, 256, 0, stream>>>(counts, bsum, row_ptr, cursor);
    k_fill<<<EB, 256, 0, stream>>>(src, dst, ea, cursor, csr);

    k_agg1<<<NN / 8, 256, 0, stream>>>(x, csr, row_ptr, We1, be1, agg1);
    k_mlp1<<<MB, 256, 0, stream>>>(x, agg1, W1a_hi, W1a_lo, b1a, W1b_hi, W1b_lo, b1b, h1b);
    k_agg2<<<NN / 4, 256, 0, stream>>>(h1b, csr, row_ptr, We2, be2, agg2);
    k_mlp2<<<MB, 256, 0, stream>>>(h1b, agg2, W2a_hi, W2a_lo, b2a, W2b_hi, W2b_lo, b2b, batch, pooled);
    k_readout<<<NG, 128, 0, stream>>>(pooled, Wm1, bm1, Wm2, bm2, out);
}

// Round 10
// 454.709 us; speedup vs baseline: 4.1192x; 1.0456x over previous
//
#include <hip/hip_runtime.h>
#include <hip/hip_bf16.h>

#define NN 100000
#define NE 1600000
#define NG 2048

typedef __attribute__((ext_vector_type(8))) short short8v;
typedef __attribute__((ext_vector_type(4))) float f32x4;

__device__ inline ushort f2bf(float f) {
    // round-to-nearest-even f32 -> bf16
    uint u = __float_as_uint(f);
    uint r = (u + 0x7fffu + ((u >> 16) & 1u)) >> 16;
    return (ushort)r;
}
__device__ inline float bf2f(ushort h) {
    return __uint_as_float(((uint)h) << 16);
}

#define MFMA_BF16 __builtin_amdgcn_mfma_f32_16x16x32_bf16

// MFMA B-fragment permutation: element (out-ch c, k) -> flat offset.
__device__ inline int frag128(int k, int c) {
    int w = c >> 5, half = (c >> 4) & 1, cl = c & 15;
    int ksl = k >> 5, kq = (k >> 3) & 3, k0 = k & 7;
    return ((ksl * 4 + w) * 2 + half) * 512 + (kq * 16 + cl) * 8 + k0;
}
__device__ inline int frag32(int k, int c) {
    int w = c >> 5, half = (c >> 4) & 1, cl = c & 15;
    int kq = (k >> 3) & 3, k0 = k & 7;
    return (w * 2 + half) * 512 + (kq * 16 + cl) * 8 + k0;
}

// ---------------- CSR build ----------------

__global__ void k_count(const int* __restrict__ dst, int* __restrict__ counts) {
    int e = blockIdx.x * 256 + threadIdx.x;
    if (e < NE) atomicAdd(&counts[dst[e]], 1);
}

__global__ void k_bsum(const int* __restrict__ counts, int* __restrict__ bsum) {
    __shared__ int s[256];
    int t = threadIdx.x;
    int i = blockIdx.x * 256 + t;
    s[t] = (i < NN) ? counts[i] : 0;
    __syncthreads();
    for (int off = 128; off > 0; off >>= 1) {
        if (t < off) s[t] += s[t + off];
        __syncthreads();
    }
    if (t == 0) bsum[blockIdx.x] = s[0];
}

__global__ void k_scan512(int* __restrict__ data, int n) {
    __shared__ int s[512];
    int t = threadIdx.x;
    int v = (t < n) ? data[t] : 0;
    s[t] = v;
    __syncthreads();
    for (int off = 1; off < 512; off <<= 1) {
        int add = (t >= off) ? s[t - off] : 0;
        __syncthreads();
        s[t] += add;
        __syncthreads();
    }
    if (t < n) data[t] = s[t] - v;  // exclusive
}

__global__ void k_scan_counts(const int* __restrict__ counts, const int* __restrict__ bsum,
                              int* __restrict__ row_ptr, int* __restrict__ cursor) {
    __shared__ int s[256];
    int t = threadIdx.x, i = blockIdx.x * 256 + t;
    int v = (i < NN) ? counts[i] : 0;
    s[t] = v;
    __syncthreads();
    for (int off = 1; off < 256; off <<= 1) {
        int add = (t >= off) ? s[t - off] : 0;
        __syncthreads();
        s[t] += add;
        __syncthreads();
    }
    int excl = s[t] - v + bsum[blockIdx.x];
    if (i < NN) { row_ptr[i] = excl; cursor[i] = excl; }
    if (i == NN - 1) row_ptr[NN] = excl + v;
}

// 8-byte CSR entry: {src, ea packed as 3x10-bit fixed point (x1023)}
__global__ void k_fill(const int* __restrict__ src, const int* __restrict__ dst,
                       const float* __restrict__ ea, int* __restrict__ cursor,
                       uint2* __restrict__ csr) {
    int e = blockIdx.x * 256 + threadIdx.x;
    if (e >= NE) return;
    int d = dst[e];
    int p = atomicAdd(&cursor[d], 1);
    uint q0 = (uint)__float2int_rn(ea[3 * e]     * 1023.f);
    uint q1 = (uint)__float2int_rn(ea[3 * e + 1] * 1023.f);
    uint q2 = (uint)__float2int_rn(ea[3 * e + 2] * 1023.f);
    csr[p] = make_uint2((uint)src[e], (q0 << 20) | (q1 << 10) | q2);
}

// ---------------- x -> bf16 copy (for agg1 gather) ----------------

__global__ void k_xcast(const float* __restrict__ x, ushort* __restrict__ xb) {
    int i = blockIdx.x * 256 + threadIdx.x;
    if (i < NN * 32 / 4) {
        float4 v = ((const float4*)x)[i];
        ushort4 o;
        o.x = f2bf(v.x); o.y = f2bf(v.y); o.z = f2bf(v.z); o.w = f2bf(v.w);
        ((ushort4*)xb)[i] = o;
    }
}

// ---------------- weight prep: f32 [K][C] -> bf16 hi/lo in MFMA-fragment order -------

__global__ void k_prep(const float* __restrict__ W1a, const float* __restrict__ W1b,
                       const float* __restrict__ W2a, const float* __restrict__ W2b,
                       ushort* __restrict__ W1a_hi, ushort* __restrict__ W1a_lo,
                       ushort* __restrict__ W1b_hi, ushort* __restrict__ W1b_lo,
                       ushort* __restrict__ W2a_hi, ushort* __restrict__ W2a_lo,
                       ushort* __restrict__ W2b_hi, ushort* __restrict__ W2b_lo) {
    int i = blockIdx.x * 256 + threadIdx.x;
    float v; ushort* ph; ushort* pl; int off;
    if (i < 4096) {                       // W1a: [32][128]
        int k = i >> 7, c = i & 127;
        v = W1a[i]; ph = W1a_hi; pl = W1a_lo; off = frag32(k, c);
    } else if (i < 20480) {               // W1b: [128][128]
        int j = i - 4096; int k = j >> 7, c = j & 127;
        v = W1b[j]; ph = W1b_hi; pl = W1b_lo; off = frag128(k, c);
    } else if (i < 36864) {               // W2a
        int j = i - 20480; int k = j >> 7, c = j & 127;
        v = W2a[j]; ph = W2a_hi; pl = W2a_lo; off = frag128(k, c);
    } else if (i < 53248) {               // W2b
        int j = i - 36864; int k = j >> 7, c = j & 127;
        v = W2b[j]; ph = W2b_hi; pl = W2b_lo; off = frag128(k, c);
    } else return;
    ushort h = f2bf(v);
    ph[off] = h;
    pl[off] = f2bf(v - bf2f(h));
}

// ---------------- Layer 1 aggregation (bf16 x gather, 32 ch), 8-deep ----------------

__global__ __launch_bounds__(256) void k_agg1(
        const ushort* __restrict__ xb, const uint2* __restrict__ csr,
        const int* __restrict__ row_ptr,
        const float* __restrict__ We1, const float* __restrict__ be1,
        float* __restrict__ agg1) {
    int lane = threadIdx.x & 31;
    int node = blockIdx.x * 8 + (threadIdx.x >> 5);
    const float qs = 1.f / 1023.f;
    float w0 = We1[lane] * qs, w1 = We1[32 + lane] * qs, w2 = We1[64 + lane] * qs;
    float b = be1[lane];
    int p0 = row_ptr[node], p1 = row_ptr[node + 1];
    float acc = 0.f;
    int p = p0;
    for (; p + 8 <= p1; p += 8) {
        uint2 e[8]; ushort v[8];
#pragma unroll
        for (int j = 0; j < 8; ++j) e[j] = csr[p + j];
#pragma unroll
        for (int j = 0; j < 8; ++j) v[j] = xb[e[j].x * 32 + lane];
#pragma unroll
        for (int j = 0; j < 8; ++j) {
            float a0 = (float)(e[j].y >> 20);
            float a1 = (float)((e[j].y >> 10) & 1023u);
            float a2 = (float)(e[j].y & 1023u);
            float el = fmaf(a0, w0, fmaf(a1, w1, fmaf(a2, w2, b)));
            acc += fmaxf(bf2f(v[j]) + el, 0.f);
        }
    }
    for (; p + 4 <= p1; p += 4) {
        uint2 e[4]; ushort v[4];
#pragma unroll
        for (int j = 0; j < 4; ++j) e[j] = csr[p + j];
#pragma unroll
        for (int j = 0; j < 4; ++j) v[j] = xb[e[j].x * 32 + lane];
#pragma unroll
        for (int j = 0; j < 4; ++j) {
            float a0 = (float)(e[j].y >> 20);
            float a1 = (float)((e[j].y >> 10) & 1023u);
            float a2 = (float)(e[j].y & 1023u);
            float el = fmaf(a0, w0, fmaf(a1, w1, fmaf(a2, w2, b)));
            acc += fmaxf(bf2f(v[j]) + el, 0.f);
        }
    }
    for (; p < p1; ++p) {
        uint2 ed = csr[p];
        ushort v = xb[ed.x * 32 + lane];
        float a0 = (float)(ed.y >> 20);
        float a1 = (float)((ed.y >> 10) & 1023u);
        float a2 = (float)(ed.y & 1023u);
        float el = fmaf(a0, w0, fmaf(a1, w1, fmaf(a2, w2, b)));
        acc += fmaxf(bf2f(v) + el, 0.f);
    }
    agg1[node * 32 + lane] = acc;
}

// ---------------- Layer 2 aggregation: 1 wave/node, 2 ch/lane (ushort2) --------------

__global__ __launch_bounds__(256) void k_agg2(
        const ushort* __restrict__ h1b, const uint2* __restrict__ csr,
        const int* __restrict__ row_ptr,
        const float* __restrict__ We2, const float* __restrict__ be2,
        float* __restrict__ agg2) {
    int lane = threadIdx.x & 63;
    int node = blockIdx.x * 4 + (threadIdx.x >> 6);
    int c = lane * 2;
    const float qs = 1.f / 1023.f;
    float w0a = We2[c] * qs,       w0b = We2[c + 1] * qs;
    float w1a = We2[128 + c] * qs, w1b = We2[129 + c] * qs;
    float w2a = We2[256 + c] * qs, w2b = We2[257 + c] * qs;
    float ba  = be2[c],            bb  = be2[c + 1];
    const uint* h1u = (const uint*)h1b;   // ushort2 as uint; rows of 64 uints
    int p0 = row_ptr[node], p1 = row_ptr[node + 1];
    float accA = 0.f, accB = 0.f;
    int p = p0;
    for (; p + 8 <= p1; p += 8) {
        uint2 e[8]; uint u[8];
#pragma unroll
        for (int j = 0; j < 8; ++j) e[j] = csr[p + j];
#pragma unroll
        for (int j = 0; j < 8; ++j) u[j] = h1u[e[j].x * 64 + lane];
#pragma unroll
        for (int j = 0; j < 8; ++j) {
            float a0 = (float)(e[j].y >> 20);
            float a1 = (float)((e[j].y >> 10) & 1023u);
            float a2 = (float)(e[j].y & 1023u);
            float elA = fmaf(a0, w0a, fmaf(a1, w1a, fmaf(a2, w2a, ba)));
            float elB = fmaf(a0, w0b, fmaf(a1, w1b, fmaf(a2, w2b, bb)));
            accA += fmaxf(bf2f((ushort)(u[j] & 0xffffu)) + elA, 0.f);
            accB += fmaxf(bf2f((ushort)(u[j] >> 16)) + elB, 0.f);
        }
    }
    for (; p + 4 <= p1; p += 4) {
        uint2 e[4]; uint u[4];
#pragma unroll
        for (int j = 0; j < 4; ++j) e[j] = csr[p + j];
#pragma unroll
        for (int j = 0; j < 4; ++j) u[j] = h1u[e[j].x * 64 + lane];
#pragma unroll
        for (int j = 0; j < 4; ++j) {
            float a0 = (float)(e[j].y >> 20);
            float a1 = (float)((e[j].y >> 10) & 1023u);
            float a2 = (float)(e[j].y & 1023u);
            float elA = fmaf(a0, w0a, fmaf(a1, w1a, fmaf(a2, w2a, ba)));
            float elB = fmaf(a0, w0b, fmaf(a1, w1b, fmaf(a2, w2b, bb)));
            accA += fmaxf(bf2f((ushort)(u[j] & 0xffffu)) + elA, 0.f);
            accB += fmaxf(bf2f((ushort)(u[j] >> 16)) + elB, 0.f);
        }
    }
    for (; p < p1; ++p) {
        uint2 ed = csr[p];
        uint u = h1u[ed.x * 64 + lane];
        float a0 = (float)(ed.y >> 20);
        float a1 = (float)((ed.y >> 10) & 1023u);
        float a2 = (float)(ed.y & 1023u);
        float elA = fmaf(a0, w0a, fmaf(a1, w1a, fmaf(a2, w2a, ba)));
        float elB = fmaf(a0, w0b, fmaf(a1, w1b, fmaf(a2, w2b, bb)));
        accA += fmaxf(bf2f((ushort)(u & 0xffffu)) + elA, 0.f);
        accB += fmaxf(bf2f((ushort)(u >> 16)) + elB, 0.f);
    }
    *(float2*)&agg2[node * 128 + c] = make_float2(accA, accB);
}

// ---------------- MLP 1 (split-bf16 MFMA, fragment-coalesced W from global) ----------

#define M1_AHI 0
#define M1_ALO 2560
#define M1_HHI 5120
#define M1_HLO 13824
#define M1_SMEM 22528

__global__ __launch_bounds__(256) void k_mlp1(
        const float* __restrict__ x, const float* __restrict__ agg1,
        const ushort* __restrict__ W1a_hi, const ushort* __restrict__ W1a_lo,
        const float* __restrict__ b1a,
        const ushort* __restrict__ W1b_hi, const ushort* __restrict__ W1b_lo,
        const float* __restrict__ b1b,
        ushort* __restrict__ h1b) {
    __shared__ __align__(16) char smem[M1_SMEM];
    ushort* A_hi = (ushort*)(smem + M1_AHI);   // [32][40]
    ushort* A_lo = (ushort*)(smem + M1_ALO);   // [32][40]
    ushort* H_hi = (ushort*)(smem + M1_HHI);   // [32][136]
    ushort* H_lo = (ushort*)(smem + M1_HLO);   // [32][136]
    int t = threadIdx.x;
    int nbase = blockIdx.x * 32;

    // stage A = x + agg1, split hi/lo
    if (t < 128) {
        int n = t >> 2, cc = (t & 3) * 8;
        int gn = nbase + n;
        short8v vh = {0,0,0,0,0,0,0,0}, vl = {0,0,0,0,0,0,0,0};
        if (gn < NN) {
            const float4* xp = (const float4*)&x[gn * 32 + cc];
            const float4* gp = (const float4*)&agg1[gn * 32 + cc];
            float s[8];
            float4 x0 = xp[0], x1 = xp[1], g0 = gp[0], g1 = gp[1];
            s[0]=x0.x+g0.x; s[1]=x0.y+g0.y; s[2]=x0.z+g0.z; s[3]=x0.w+g0.w;
            s[4]=x1.x+g1.x; s[5]=x1.y+g1.y; s[6]=x1.z+g1.z; s[7]=x1.w+g1.w;
#pragma unroll
            for (int j = 0; j < 8; ++j) {
                ushort h = f2bf(s[j]);
                vh[j] = (short)h;
                vl[j] = (short)f2bf(s[j] - bf2f(h));
            }
        }
        *(short8v*)&A_hi[n * 40 + cc] = vh;
        *(short8v*)&A_lo[n * 40 + cc] = vl;
    }
    __syncthreads();

    int w = t >> 6, l = t & 63;
    int cl = l & 15, kq = l >> 4;
    int row0 = w * 32 + cl, row1 = w * 32 + 16 + cl;

    f32x4 acc[2][2];
#pragma unroll
    for (int mt = 0; mt < 2; ++mt) { acc[mt][0] = f32x4{0.f,0.f,0.f,0.f}; acc[mt][1] = f32x4{0.f,0.f,0.f,0.f}; }

    // phase A: K=32, 3-term split; W1a fragment-coalesced from global
    {
        int kof = kq * 8;
        int fb = (w * 2) * 512 + l * 8;
        short8v bh0 = *(const short8v*)&W1a_hi[fb];
        short8v bh1 = *(const short8v*)&W1a_hi[fb + 512];
        short8v bl0 = *(const short8v*)&W1a_lo[fb];
        short8v bl1 = *(const short8v*)&W1a_lo[fb + 512];
#pragma unroll
        for (int mt = 0; mt < 2; ++mt) {
            short8v ah = *(short8v*)&A_hi[(mt * 16 + cl) * 40 + kof];
            short8v al = *(short8v*)&A_lo[(mt * 16 + cl) * 40 + kof];
            acc[mt][0] = MFMA_BF16(ah, bh0, acc[mt][0], 0, 0, 0);
            acc[mt][0] = MFMA_BF16(al, bh0, acc[mt][0], 0, 0, 0);
            acc[mt][0] = MFMA_BF16(ah, bl0, acc[mt][0], 0, 0, 0);
            acc[mt][1] = MFMA_BF16(ah, bh1, acc[mt][1], 0, 0, 0);
            acc[mt][1] = MFMA_BF16(al, bh1, acc[mt][1], 0, 0, 0);
            acc[mt][1] = MFMA_BF16(ah, bl1, acc[mt][1], 0, 0, 0);
        }
    }
    // epilogue A -> H (bias+relu, split)
    {
        float bb0 = b1a[row0], bb1 = b1a[row1];
#pragma unroll
        for (int mt = 0; mt < 2; ++mt)
#pragma unroll
            for (int j = 0; j < 4; ++j) {
                int row = mt * 16 + kq * 4 + j;
                float v0 = fmaxf(acc[mt][0][j] + bb0, 0.f);
                float v1 = fmaxf(acc[mt][1][j] + bb1, 0.f);
                ushort h0 = f2bf(v0), h1v = f2bf(v1);
                H_hi[row * 136 + row0] = h0;
                H_lo[row * 136 + row0] = f2bf(v0 - bf2f(h0));
                H_hi[row * 136 + row1] = h1v;
                H_lo[row * 136 + row1] = f2bf(v1 - bf2f(h1v));
            }
    }
    __syncthreads();

    // phase B: K=128 from H; W1b fragment-coalesced, 4 k-slices
#pragma unroll
    for (int mt = 0; mt < 2; ++mt) { acc[mt][0] = f32x4{0.f,0.f,0.f,0.f}; acc[mt][1] = f32x4{0.f,0.f,0.f,0.f}; }
#pragma unroll
    for (int ksl = 0; ksl < 4; ++ksl) {
        int kof = ksl * 32 + kq * 8;
        int fb = ((ksl * 4 + w) * 2) * 512 + l * 8;
        short8v bh0 = *(const short8v*)&W1b_hi[fb];
        short8v bh1 = *(const short8v*)&W1b_hi[fb + 512];
        short8v bl0 = *(const short8v*)&W1b_lo[fb];
        short8v bl1 = *(const short8v*)&W1b_lo[fb + 512];
#pragma unroll
        for (int mt = 0; mt < 2; ++mt) {
            short8v ah = *(short8v*)&H_hi[(mt * 16 + cl) * 136 + kof];
            short8v al = *(short8v*)&H_lo[(mt * 16 + cl) * 136 + kof];
            acc[mt][0] = MFMA_BF16(ah, bh0, acc[mt][0], 0, 0, 0);
            acc[mt][0] = MFMA_BF16(al, bh0, acc[mt][0], 0, 0, 0);
            acc[mt][0] = MFMA_BF16(ah, bl0, acc[mt][0], 0, 0, 0);
            acc[mt][1] = MFMA_BF16(ah, bh1, acc[mt][1], 0, 0, 0);
            acc[mt][1] = MFMA_BF16(al, bh1, acc[mt][1], 0, 0, 0);
            acc[mt][1] = MFMA_BF16(ah, bl1, acc[mt][1], 0, 0, 0);
        }
    }
    // epilogue B -> h1b (bf16, bias+relu)
    {
        float c0 = b1b[row0], c1 = b1b[row1];
#pragma unroll
        for (int mt = 0; mt < 2; ++mt)
#pragma unroll
            for (int j = 0; j < 4; ++j) {
                int gn = nbase + mt * 16 + kq * 4 + j;
                if (gn < NN) {
                    h1b[gn * 128 + row0] = f2bf(fmaxf(acc[mt][0][j] + c0, 0.f));
                    h1b[gn * 128 + row1] = f2bf(fmaxf(acc[mt][1][j] + c1, 0.f));
                }
            }
    }
}

// ---------------- MLP 2 (split-bf16 MFMA, fragment W) + fused pool ----------

#define M2_AHI 0
#define M2_ALO 8704
#define M2_HHI 17408
#define M2_HLO 26112
#define M2_B   34816
#define M2_SMEM 34944

__global__ __launch_bounds__(256) void k_mlp2(
        const ushort* __restrict__ h1b, const float* __restrict__ agg2,
        const ushort* __restrict__ W2a_hi, const ushort* __restrict__ W2a_lo,
        const float* __restrict__ b2a,
        const ushort* __restrict__ W2b_hi, const ushort* __restrict__ W2b_lo,
        const float* __restrict__ b2b,
        const int* __restrict__ batch, float* __restrict__ pooled) {
    __shared__ __align__(16) char smem[M2_SMEM];
    ushort* A_hi = (ushort*)(smem + M2_AHI);
    ushort* A_lo = (ushort*)(smem + M2_ALO);
    ushort* H_hi = (ushort*)(smem + M2_HHI);
    ushort* H_lo = (ushort*)(smem + M2_HLO);
    int* batch_s = (int*)(smem + M2_B);
    int t = threadIdx.x;
    int nbase = blockIdx.x * 32;

    if (t < 32) batch_s[t] = (nbase + t < NN) ? batch[nbase + t] : -1;

    // stage A = h1(bf16) + agg2, split hi/lo
    for (int i = t; i < 512; i += 256) {
        int n = i >> 4, cc = (i & 15) * 8;
        int gn = nbase + n;
        short8v vh = {0,0,0,0,0,0,0,0}, vl = {0,0,0,0,0,0,0,0};
        if (gn < NN) {
            short8v hb = *(const short8v*)&h1b[gn * 128 + cc];
            const float4* gp = (const float4*)&agg2[gn * 128 + cc];
            float4 g0 = gp[0], g1 = gp[1];
            float s[8];
            s[0]=bf2f((ushort)hb[0])+g0.x; s[1]=bf2f((ushort)hb[1])+g0.y;
            s[2]=bf2f((ushort)hb[2])+g0.z; s[3]=bf2f((ushort)hb[3])+g0.w;
            s[4]=bf2f((ushort)hb[4])+g1.x; s[5]=bf2f((ushort)hb[5])+g1.y;
            s[6]=bf2f((ushort)hb[6])+g1.z; s[7]=bf2f((ushort)hb[7])+g1.w;
#pragma unroll
            for (int j = 0; j < 8; ++j) {
                ushort h = f2bf(s[j]);
                vh[j] = (short)h;
                vl[j] = (short)f2bf(s[j] - bf2f(h));
            }
        }
        *(short8v*)&A_hi[n * 136 + cc] = vh;
        *(short8v*)&A_lo[n * 136 + cc] = vl;
    }
    __syncthreads();

    int w = t >> 6, l = t & 63;
    int cl = l & 15, kq = l >> 4;
    int row0 = w * 32 + cl, row1 = w * 32 + 16 + cl;

    f32x4 acc[2][2];
#pragma unroll
    for (int mt = 0; mt < 2; ++mt) { acc[mt][0] = f32x4{0.f,0.f,0.f,0.f}; acc[mt][1] = f32x4{0.f,0.f,0.f,0.f}; }

    // phase A: (h1+agg2) @ W2a, K=128, fragment W
#pragma unroll
    for (int ksl = 0; ksl < 4; ++ksl) {
        int kof = ksl * 32 + kq * 8;
        int fb = ((ksl * 4 + w) * 2) * 512 + l * 8;
        short8v bh0 = *(const short8v*)&W2a_hi[fb];
        short8v bh1 = *(const short8v*)&W2a_hi[fb + 512];
        short8v bl0 = *(const short8v*)&W2a_lo[fb];
        short8v bl1 = *(const short8v*)&W2a_lo[fb + 512];
#pragma unroll
        for (int mt = 0; mt < 2; ++mt) {
            short8v ah = *(short8v*)&A_hi[(mt * 16 + cl) * 136 + kof];
            short8v al = *(short8v*)&A_lo[(mt * 16 + cl) * 136 + kof];
            acc[mt][0] = MFMA_BF16(ah, bh0, acc[mt][0], 0, 0, 0);
            acc[mt][0] = MFMA_BF16(al, bh0, acc[mt][0], 0, 0, 0);
            acc[mt][0] = MFMA_BF16(ah, bl0, acc[mt][0], 0, 0, 0);
            acc[mt][1] = MFMA_BF16(ah, bh1, acc[mt][1], 0, 0, 0);
            acc[mt][1] = MFMA_BF16(al, bh1, acc[mt][1], 0, 0, 0);
            acc[mt][1] = MFMA_BF16(ah, bl1, acc[mt][1], 0, 0, 0);
        }
    }
    // epilogue A -> H (bias+relu, split)
    {
        float bb0 = b2a[row0], bb1 = b2a[row1];
#pragma unroll
        for (int mt = 0; mt < 2; ++mt)
#pragma unroll
            for (int j = 0; j < 4; ++j) {
                int row = mt * 16 + kq * 4 + j;
                float v0 = fmaxf(acc[mt][0][j] + bb0, 0.f);
                float v1 = fmaxf(acc[mt][1][j] + bb1, 0.f);
                ushort h0 = f2bf(v0), h1v = f2bf(v1);
                H_hi[row * 136 + row0] = h0;
                H_lo[row * 136 + row0] = f2bf(v0 - bf2f(h0));
                H_hi[row * 136 + row1] = h1v;
                H_lo[row * 136 + row1] = f2bf(v1 - bf2f(h1v));
            }
    }
    __syncthreads();

    // phase B: hid @ W2b, K=128, fragment W
#pragma unroll
    for (int mt = 0; mt < 2; ++mt) { acc[mt][0] = f32x4{0.f,0.f,0.f,0.f}; acc[mt][1] = f32x4{0.f,0.f,0.f,0.f}; }
#pragma unroll
    for (int ksl = 0; ksl < 4; ++ksl) {
        int kof = ksl * 32 + kq * 8;
        int fb = ((ksl * 4 + w) * 2) * 512 + l * 8;
        short8v bh0 = *(const short8v*)&W2b_hi[fb];
        short8v bh1 = *(const short8v*)&W2b_hi[fb + 512];
        short8v bl0 = *(const short8v*)&W2b_lo[fb];
        short8v bl1 = *(const short8v*)&W2b_lo[fb + 512];
#pragma unroll
        for (int mt = 0; mt < 2; ++mt) {
            short8v ah = *(short8v*)&H_hi[(mt * 16 + cl) * 136 + kof];
            short8v al = *(short8v*)&H_lo[(mt * 16 + cl) * 136 + kof];
            acc[mt][0] = MFMA_BF16(ah, bh0, acc[mt][0], 0, 0, 0);
            acc[mt][0] = MFMA_BF16(al, bh0, acc[mt][0], 0, 0, 0);
            acc[mt][0] = MFMA_BF16(ah, bl0, acc[mt][0], 0, 0, 0);
            acc[mt][1] = MFMA_BF16(ah, bh1, acc[mt][1], 0, 0, 0);
            acc[mt][1] = MFMA_BF16(al, bh1, acc[mt][1], 0, 0, 0);
            acc[mt][1] = MFMA_BF16(ah, bl1, acc[mt][1], 0, 0, 0);
        }
    }
    __syncthreads();
    // epilogue B -> f32 tile P (aliases A region; all A reads done), then pool
    float* P = (float*)smem;  // [32][132]
    {
        float c0 = b2b[row0], c1 = b2b[row1];
#pragma unroll
        for (int mt = 0; mt < 2; ++mt)
#pragma unroll
            for (int j = 0; j < 4; ++j) {
                int row = mt * 16 + kq * 4 + j;
                P[row * 132 + row0] = fmaxf(acc[mt][0][j] + c0, 0.f);
                P[row * 132 + row1] = fmaxf(acc[mt][1][j] + c1, 0.f);
            }
    }
    __syncthreads();

    // pool: batch sorted; two halves of 16 nodes, run-length + atomics
    {
        int c = t & 127, half = t >> 7;
        int i0 = half * 16;
        float run = 0.f;
        int cur = batch_s[i0];
        if (cur >= 0) {
            for (int i = i0; i < i0 + 16; ++i) {
                int b = batch_s[i];
                if (b < 0) break;
                if (b != cur) { atomicAdd(&pooled[cur * 128 + c], run); run = 0.f; cur = b; }
                run += P[i * 132 + c];
            }
            atomicAdd(&pooled[cur * 128 + c], run);
        }
    }
}

// ---------------- Readout: relu(pooled@Wm1+bm1)@Wm2+bm2 ----------------

__global__ __launch_bounds__(128) void k_readout(
        const float* __restrict__ pooled, const float* __restrict__ Wm1,
        const float* __restrict__ bm1, const float* __restrict__ Wm2,
        const float* __restrict__ bm2, float* __restrict__ out) {
    __shared__ float row[128];
    __shared__ float red[128];
    int g = blockIdx.x, t = threadIdx.x;
    row[t] = pooled[g * 128 + t];
    __syncthreads();
    float acc = bm1[t];
    for (int c = 0; c < 128; ++c) acc = fmaf(row[c], Wm1[c * 128 + t], acc);
    float term = fmaxf(acc, 0.f) * Wm2[t];
    red[t] = term;
    __syncthreads();
    for (int off = 64; off > 0; off >>= 1) {
        if (t < off) red[t] += red[t + off];
        __syncthreads();
    }
    if (t == 0) out[g] = red[0] + bm2[0];
}

// ---------------- Launch ----------------

extern "C" void kernel_launch(void* const* d_in, const int* in_sizes, int n_in,
                              void* d_out, int out_size, void* d_ws, size_t ws_size,
                              hipStream_t stream) {
    const float* x    = (const float*)d_in[0];
    const int* eidx   = (const int*)d_in[1];
    const float* ea   = (const float*)d_in[2];
    const int* batch  = (const int*)d_in[3];
    const float* We1  = (const float*)d_in[4];
    const float* be1  = (const float*)d_in[5];
    const float* W1a  = (const float*)d_in[6];
    const float* b1a  = (const float*)d_in[7];
    const float* W1b  = (const float*)d_in[8];
    const float* b1b  = (const float*)d_in[9];
    const float* We2  = (const float*)d_in[10];
    const float* be2  = (const float*)d_in[11];
    const float* W2a  = (const float*)d_in[12];
    const float* b2a  = (const float*)d_in[13];
    const float* W2b  = (const float*)d_in[14];
    const float* b2b  = (const float*)d_in[15];
    const float* Wm1  = (const float*)d_in[16];
    const float* bm1  = (const float*)d_in[17];
    const float* Wm2  = (const float*)d_in[18];
    const float* bm2  = (const float*)d_in[19];
    float* out = (float*)d_out;

    const int* src = eidx;
    const int* dst = eidx + NE;

    char* w = (char*)d_ws;
    auto alloc = [&](size_t bytes) { void* p = (void*)w; w += (bytes + 255) & ~(size_t)255; return p; };
    int* counts    = (int*)alloc(NN * 4);
    int* row_ptr   = (int*)alloc((NN + 1) * 4);
    int* cursor    = (int*)alloc(NN * 4);
    int* bsum      = (int*)alloc(512 * 4);
    uint2* csr     = (uint2*)alloc((size_t)NE * 8);
    float* agg1    = (float*)alloc((size_t)NN * 32 * 4);
    ushort* h1b    = (ushort*)alloc((size_t)NN * 128 * 2);
    float* agg2    = (float*)alloc((size_t)NN * 128 * 4);
    float* pooled  = (float*)alloc((size_t)NG * 128 * 4);
    ushort* xb     = (ushort*)alloc((size_t)NN * 32 * 2);
    ushort* W1a_hi = (ushort*)alloc(4096 * 2);
    ushort* W1a_lo = (ushort*)alloc(4096 * 2);
    ushort* W1b_hi = (ushort*)alloc(16384 * 2);
    ushort* W1b_lo = (ushort*)alloc(16384 * 2);
    ushort* W2a_hi = (ushort*)alloc(16384 * 2);
    ushort* W2a_lo = (ushort*)alloc(16384 * 2);
    ushort* W2b_hi = (ushort*)alloc(16384 * 2);
    ushort* W2b_lo = (ushort*)alloc(16384 * 2);

    hipMemsetAsync(counts, 0, NN * 4, stream);
    hipMemsetAsync(pooled, 0, (size_t)NG * 128 * 4, stream);

    const int EB = (NE + 255) / 256;       // 6250
    const int NB = (NN + 255) / 256;       // 391
    const int MB = (NN + 31) / 32;         // 3125

    k_prep<<<208, 256, 0, stream>>>(W1a, W1b, W2a, W2b,
                                    W1a_hi, W1a_lo, W1b_hi, W1b_lo,
                                    W2a_hi, W2a_lo, W2b_hi, W2b_lo);
    k_xcast<<<3125, 256, 0, stream>>>(x, xb);
    k_count<<<EB, 256, 0, stream>>>(dst, counts);
    k_bsum<<<NB, 256, 0, stream>>>(counts, bsum);
    k_scan512<<<1, 512, 0, stream>>>(bsum, NB);
    k_scan_counts<<<NB, 256, 0, stream>>>(counts, bsum, row_ptr, cursor);
    k_fill<<<EB, 256, 0, stream>>>(src, dst, ea, cursor, csr);

    k_agg1<<<NN / 8, 256, 0, stream>>>(xb, csr, row_ptr, We1, be1, agg1);
    k_mlp1<<<MB, 256, 0, stream>>>(x, agg1, W1a_hi, W1a_lo, b1a, W1b_hi, W1b_lo, b1b, h1b);
    k_agg2<<<NN / 4, 256, 0, stream>>>(h1b, csr, row_ptr, We2, be2, agg2);
    k_mlp2<<<MB, 256, 0, stream>>>(h1b, agg2, W2a_hi, W2a_lo, b2a, W2b_hi, W2b_lo, b2b, batch, pooled);
    k_readout<<<NG, 128, 0, stream>>>(pooled, Wm1, bm1, Wm2, bm2, out);
}

// Round 11
// 438.884 us; speedup vs baseline: 4.2677x; 1.0361x over previous
//
#include <hip/hip_runtime.h>
#include <hip/hip_bf16.h>

#define NN 100000
#define NE 1600000
#define NG 2048
#define NBKT 196          // buckets of 512 nodes (dst>>9)
#define EPB 4096          // edges per binfill block
#define BINBLKS ((NE + EPB - 1) / EPB)   // 391

typedef __attribute__((ext_vector_type(8))) short short8v;
typedef __attribute__((ext_vector_type(4))) float f32x4;

__device__ inline ushort f2bf(float f) {
    uint u = __float_as_uint(f);
    uint r = (u + 0x7fffu + ((u >> 16) & 1u)) >> 16;
    return (ushort)r;
}
__device__ inline float bf2f(ushort h) {
    return __uint_as_float(((uint)h) << 16);
}

#define MFMA_BF16 __builtin_amdgcn_mfma_f32_16x16x32_bf16

// MFMA B-fragment permutation: element (out-ch c, k) -> flat offset.
__device__ inline int frag128(int k, int c) {
    int w = c >> 5, half = (c >> 4) & 1, cl = c & 15;
    int ksl = k >> 5, kq = (k >> 3) & 3, k0 = k & 7;
    return ((ksl * 4 + w) * 2 + half) * 512 + (kq * 16 + cl) * 8 + k0;
}
__device__ inline int frag32(int k, int c) {
    int w = c >> 5, half = (c >> 4) & 1, cl = c & 15;
    int kq = (k >> 3) & 3, k0 = k & 7;
    return (w * 2 + half) * 512 + (kq * 16 + cl) * 8 + k0;
}

// ---------------- per-node counts + row_ptr ----------------

__global__ void k_count(const int* __restrict__ dst, int* __restrict__ counts) {
    int e = blockIdx.x * 256 + threadIdx.x;
    if (e < NE) atomicAdd(&counts[dst[e]], 1);
}

__global__ void k_bsum(const int* __restrict__ counts, int* __restrict__ bsum) {
    __shared__ int s[256];
    int t = threadIdx.x;
    int i = blockIdx.x * 256 + t;
    s[t] = (i < NN) ? counts[i] : 0;
    __syncthreads();
    for (int off = 128; off > 0; off >>= 1) {
        if (t < off) s[t] += s[t + off];
        __syncthreads();
    }
    if (t == 0) bsum[blockIdx.x] = s[0];
}

__global__ void k_scan512(int* __restrict__ data, int n) {
    __shared__ int s[512];
    int t = threadIdx.x;
    int v = (t < n) ? data[t] : 0;
    s[t] = v;
    __syncthreads();
    for (int off = 1; off < 512; off <<= 1) {
        int add = (t >= off) ? s[t - off] : 0;
        __syncthreads();
        s[t] += add;
        __syncthreads();
    }
    if (t < n) data[t] = s[t] - v;  // exclusive
}

__global__ void k_scan_counts(const int* __restrict__ counts, const int* __restrict__ bsum,
                              int* __restrict__ row_ptr, int* __restrict__ cursor) {
    __shared__ int s[256];
    int t = threadIdx.x, i = blockIdx.x * 256 + t;
    int v = (i < NN) ? counts[i] : 0;
    s[t] = v;
    __syncthreads();
    for (int off = 1; off < 256; off <<= 1) {
        int add = (t >= off) ? s[t - off] : 0;
        __syncthreads();
        s[t] += add;
        __syncthreads();
    }
    int excl = s[t] - v + bsum[blockIdx.x];
    if (i < NN) { row_ptr[i] = excl; cursor[i] = excl; }
    if (i == NN - 1) row_ptr[NN] = excl + v;
}

// ---------------- bucket histogram + scan ----------------

__global__ __launch_bounds__(256) void k_bhist(const int* __restrict__ dst,
                                               int* __restrict__ bhist) {
    __shared__ int h[NBKT];
    int t = threadIdx.x;
    for (int i = t; i < NBKT; i += 256) h[i] = 0;
    __syncthreads();
    int e0 = blockIdx.x * EPB;
    int n = NE - e0; if (n > EPB) n = EPB;
    for (int i = t; i < n; i += 256)
        atomicAdd(&h[dst[e0 + i] >> 9], 1);
    __syncthreads();
    for (int i = t; i < NBKT; i += 256)
        if (h[i]) atomicAdd(&bhist[i], h[i]);
}

__global__ void k_bscan(const int* __restrict__ bhist,
                        int* __restrict__ bkt_off, int* __restrict__ bkt_cursor) {
    __shared__ int s[256];
    int t = threadIdx.x;
    int v = (t < NBKT) ? bhist[t] : 0;
    s[t] = v;
    __syncthreads();
    for (int off = 1; off < 256; off <<= 1) {
        int add = (t >= off) ? s[t - off] : 0;
        __syncthreads();
        s[t] += add;
        __syncthreads();
    }
    int excl = s[t] - v;
    if (t < NBKT) { bkt_off[t] = excl; bkt_cursor[t] = excl; }
    if (t == NBKT - 1) bkt_off[NBKT] = excl + v;
}

// ---------------- binfill: LDS-group edges by bucket, flush coalesced -------------
// edge record: lo = src(17) | dstLow15<<17 ; hi = dstHigh2 | ea30<<2

__global__ __launch_bounds__(256) void k_binfill(
        const int* __restrict__ src, const int* __restrict__ dst,
        const float* __restrict__ ea,
        int* __restrict__ bkt_cursor, uint2* __restrict__ tmp) {
    __shared__ int hist[NBKT];
    __shared__ int boff[NBKT];
    __shared__ int base[NBKT];
    __shared__ int s[256];
    __shared__ uint2 stage[EPB];
    __shared__ unsigned char stage_bkt[EPB];
    int t = threadIdx.x;
    int e0 = blockIdx.x * EPB;
    int n = NE - e0; if (n > EPB) n = EPB;

    for (int i = t; i < NBKT; i += 256) hist[i] = 0;
    __syncthreads();

    uint lo[16], hi[16]; int bk[16], pos[16];
#pragma unroll
    for (int j = 0; j < 16; ++j) {
        int i = j * 256 + t;
        bk[j] = -1;
        if (i < n) {
            int e = e0 + i;
            int sn = src[e], d = dst[e];
            uint q0 = (uint)__float2int_rn(ea[3 * e]     * 1023.f);
            uint q1 = (uint)__float2int_rn(ea[3 * e + 1] * 1023.f);
            uint q2 = (uint)__float2int_rn(ea[3 * e + 2] * 1023.f);
            uint q = (q0 << 20) | (q1 << 10) | q2;
            lo[j] = (uint)sn | ((uint)(d & 0x7FFF) << 17);
            hi[j] = (uint)(d >> 15) | (q << 2);
            bk[j] = d >> 9;
            pos[j] = atomicAdd(&hist[bk[j]], 1);
        }
    }
    __syncthreads();
    // exclusive scan of hist -> boff; reserve global ranges -> base
    int v = (t < NBKT) ? hist[t] : 0;
    s[t] = v;
    __syncthreads();
    for (int off = 1; off < 256; off <<= 1) {
        int add = (t >= off) ? s[t - off] : 0;
        __syncthreads();
        s[t] += add;
        __syncthreads();
    }
    if (t < NBKT) {
        boff[t] = s[t] - v;
        base[t] = v ? atomicAdd(&bkt_cursor[t], v) : 0;
    }
    __syncthreads();
    // scatter records into bucket-grouped LDS
#pragma unroll
    for (int j = 0; j < 16; ++j) {
        if (bk[j] >= 0) {
            int slot = boff[bk[j]] + pos[j];
            stage[slot] = make_uint2(lo[j], hi[j]);
            stage_bkt[slot] = (unsigned char)bk[j];
        }
    }
    __syncthreads();
    // flush: consecutive slots in a bucket -> consecutive global targets (coalesced runs)
    for (int i = t; i < n; i += 256) {
        int b = stage_bkt[i];
        tmp[base[b] + (i - boff[b])] = stage[i];
    }
}

// ---------------- scatter: one block per bucket, L2-local per-node placement ------

__global__ __launch_bounds__(256) void k_scatter(
        const uint2* __restrict__ tmp, const int* __restrict__ bkt_off,
        int* __restrict__ cursor, uint2* __restrict__ csr) {
    int b = blockIdx.x;
    int start = bkt_off[b], end = bkt_off[b + 1];
    for (int i = start + (int)threadIdx.x; i < end; i += 256) {
        uint2 r = tmp[i];
        int sn = (int)(r.x & 0x1FFFFu);
        int d  = (int)((r.x >> 17) | ((r.y & 3u) << 15));
        uint q = r.y >> 2;
        int p = atomicAdd(&cursor[d], 1);
        csr[p] = make_uint2((uint)sn, q);
    }
}

// ---------------- x -> bf16 copy (for agg1 gather) ----------------

__global__ void k_xcast(const float* __restrict__ x, ushort* __restrict__ xb) {
    int i = blockIdx.x * 256 + threadIdx.x;
    if (i < NN * 32 / 4) {
        float4 v = ((const float4*)x)[i];
        ushort4 o;
        o.x = f2bf(v.x); o.y = f2bf(v.y); o.z = f2bf(v.z); o.w = f2bf(v.w);
        ((ushort4*)xb)[i] = o;
    }
}

// ---------------- weight prep: f32 [K][C] -> bf16 hi/lo in MFMA-fragment order -------

__global__ void k_prep(const float* __restrict__ W1a, const float* __restrict__ W1b,
                       const float* __restrict__ W2a, const float* __restrict__ W2b,
                       ushort* __restrict__ W1a_hi, ushort* __restrict__ W1a_lo,
                       ushort* __restrict__ W1b_hi, ushort* __restrict__ W1b_lo,
                       ushort* __restrict__ W2a_hi, ushort* __restrict__ W2a_lo,
                       ushort* __restrict__ W2b_hi, ushort* __restrict__ W2b_lo) {
    int i = blockIdx.x * 256 + threadIdx.x;
    float v; ushort* ph; ushort* pl; int off;
    if (i < 4096) {
        int k = i >> 7, c = i & 127;
        v = W1a[i]; ph = W1a_hi; pl = W1a_lo; off = frag32(k, c);
    } else if (i < 20480) {
        int j = i - 4096; int k = j >> 7, c = j & 127;
        v = W1b[j]; ph = W1b_hi; pl = W1b_lo; off = frag128(k, c);
    } else if (i < 36864) {
        int j = i - 20480; int k = j >> 7, c = j & 127;
        v = W2a[j]; ph = W2a_hi; pl = W2a_lo; off = frag128(k, c);
    } else if (i < 53248) {
        int j = i - 36864; int k = j >> 7, c = j & 127;
        v = W2b[j]; ph = W2b_hi; pl = W2b_lo; off = frag128(k, c);
    } else return;
    ushort h = f2bf(v);
    ph[off] = h;
    pl[off] = f2bf(v - bf2f(h));
}

// ---------------- Layer 1 aggregation (bf16 x gather, 32 ch), 8-deep ----------------

__global__ __launch_bounds__(256) void k_agg1(
        const ushort* __restrict__ xb, const uint2* __restrict__ csr,
        const int* __restrict__ row_ptr,
        const float* __restrict__ We1, const float* __restrict__ be1,
        float* __restrict__ agg1) {
    int lane = threadIdx.x & 31;
    int node = blockIdx.x * 8 + (threadIdx.x >> 5);
    const float qs = 1.f / 1023.f;
    float w0 = We1[lane] * qs, w1 = We1[32 + lane] * qs, w2 = We1[64 + lane] * qs;
    float b = be1[lane];
    int p0 = row_ptr[node], p1 = row_ptr[node + 1];
    float acc = 0.f;
    int p = p0;
    for (; p + 8 <= p1; p += 8) {
        uint2 e[8]; ushort v[8];
#pragma unroll
        for (int j = 0; j < 8; ++j) e[j] = csr[p + j];
#pragma unroll
        for (int j = 0; j < 8; ++j) v[j] = xb[e[j].x * 32 + lane];
#pragma unroll
        for (int j = 0; j < 8; ++j) {
            float a0 = (float)(e[j].y >> 20);
            float a1 = (float)((e[j].y >> 10) & 1023u);
            float a2 = (float)(e[j].y & 1023u);
            float el = fmaf(a0, w0, fmaf(a1, w1, fmaf(a2, w2, b)));
            acc += fmaxf(bf2f(v[j]) + el, 0.f);
        }
    }
    for (; p + 4 <= p1; p += 4) {
        uint2 e[4]; ushort v[4];
#pragma unroll
        for (int j = 0; j < 4; ++j) e[j] = csr[p + j];
#pragma unroll
        for (int j = 0; j < 4; ++j) v[j] = xb[e[j].x * 32 + lane];
#pragma unroll
        for (int j = 0; j < 4; ++j) {
            float a0 = (float)(e[j].y >> 20);
            float a1 = (float)((e[j].y >> 10) & 1023u);
            float a2 = (float)(e[j].y & 1023u);
            float el = fmaf(a0, w0, fmaf(a1, w1, fmaf(a2, w2, b)));
            acc += fmaxf(bf2f(v[j]) + el, 0.f);
        }
    }
    for (; p < p1; ++p) {
        uint2 ed = csr[p];
        ushort v = xb[ed.x * 32 + lane];
        float a0 = (float)(ed.y >> 20);
        float a1 = (float)((ed.y >> 10) & 1023u);
        float a2 = (float)(ed.y & 1023u);
        float el = fmaf(a0, w0, fmaf(a1, w1, fmaf(a2, w2, b)));
        acc += fmaxf(bf2f(v) + el, 0.f);
    }
    agg1[node * 32 + lane] = acc;
}

// ---------------- Layer 2 aggregation: 1 wave/node, 2 ch/lane (ushort2) --------------

__global__ __launch_bounds__(256) void k_agg2(
        const ushort* __restrict__ h1b, const uint2* __restrict__ csr,
        const int* __restrict__ row_ptr,
        const float* __restrict__ We2, const float* __restrict__ be2,
        float* __restrict__ agg2) {
    int lane = threadIdx.x & 63;
    int node = blockIdx.x * 4 + (threadIdx.x >> 6);
    int c = lane * 2;
    const float qs = 1.f / 1023.f;
    float w0a = We2[c] * qs,       w0b = We2[c + 1] * qs;
    float w1a = We2[128 + c] * qs, w1b = We2[129 + c] * qs;
    float w2a = We2[256 + c] * qs, w2b = We2[257 + c] * qs;
    float ba  = be2[c],            bb  = be2[c + 1];
    const uint* h1u = (const uint*)h1b;
    int p0 = row_ptr[node], p1 = row_ptr[node + 1];
    float accA = 0.f, accB = 0.f;
    int p = p0;
    for (; p + 8 <= p1; p += 8) {
        uint2 e[8]; uint u[8];
#pragma unroll
        for (int j = 0; j < 8; ++j) e[j] = csr[p + j];
#pragma unroll
        for (int j = 0; j < 8; ++j) u[j] = h1u[e[j].x * 64 + lane];
#pragma unroll
        for (int j = 0; j < 8; ++j) {
            float a0 = (float)(e[j].y >> 20);
            float a1 = (float)((e[j].y >> 10) & 1023u);
            float a2 = (float)(e[j].y & 1023u);
            float elA = fmaf(a0, w0a, fmaf(a1, w1a, fmaf(a2, w2a, ba)));
            float elB = fmaf(a0, w0b, fmaf(a1, w1b, fmaf(a2, w2b, bb)));
            accA += fmaxf(bf2f((ushort)(u[j] & 0xffffu)) + elA, 0.f);
            accB += fmaxf(bf2f((ushort)(u[j] >> 16)) + elB, 0.f);
        }
    }
    for (; p + 4 <= p1; p += 4) {
        uint2 e[4]; uint u[4];
#pragma unroll
        for (int j = 0; j < 4; ++j) e[j] = csr[p + j];
#pragma unroll
        for (int j = 0; j < 4; ++j) u[j] = h1u[e[j].x * 64 + lane];
#pragma unroll
        for (int j = 0; j < 4; ++j) {
            float a0 = (float)(e[j].y >> 20);
            float a1 = (float)((e[j].y >> 10) & 1023u);
            float a2 = (float)(e[j].y & 1023u);
            float elA = fmaf(a0, w0a, fmaf(a1, w1a, fmaf(a2, w2a, ba)));
            float elB = fmaf(a0, w0b, fmaf(a1, w1b, fmaf(a2, w2b, bb)));
            accA += fmaxf(bf2f((ushort)(u[j] & 0xffffu)) + elA, 0.f);
            accB += fmaxf(bf2f((ushort)(u[j] >> 16)) + elB, 0.f);
        }
    }
    for (; p < p1; ++p) {
        uint2 ed = csr[p];
        uint u = h1u[ed.x * 64 + lane];
        float a0 = (float)(ed.y >> 20);
        float a1 = (float)((ed.y >> 10) & 1023u);
        float a2 = (float)(ed.y & 1023u);
        float elA = fmaf(a0, w0a, fmaf(a1, w1a, fmaf(a2, w2a, ba)));
        float elB = fmaf(a0, w0b, fmaf(a1, w1b, fmaf(a2, w2b, bb)));
        accA += fmaxf(bf2f((ushort)(u & 0xffffu)) + elA, 0.f);
        accB += fmaxf(bf2f((ushort)(u >> 16)) + elB, 0.f);
    }
    *(float2*)&agg2[node * 128 + c] = make_float2(accA, accB);
}

// ---------------- MLP 1 (split-bf16 MFMA, fragment-coalesced W from global) ----------

#define M1_AHI 0
#define M1_ALO 2560
#define M1_HHI 5120
#define M1_HLO 13824
#define M1_SMEM 22528

__global__ __launch_bounds__(256) void k_mlp1(
        const float* __restrict__ x, const float* __restrict__ agg1,
        const ushort* __restrict__ W1a_hi, const ushort* __restrict__ W1a_lo,
        const float* __restrict__ b1a,
        const ushort* __restrict__ W1b_hi, const ushort* __restrict__ W1b_lo,
        const float* __restrict__ b1b,
        ushort* __restrict__ h1b) {
    __shared__ __align__(16) char smem[M1_SMEM];
    ushort* A_hi = (ushort*)(smem + M1_AHI);
    ushort* A_lo = (ushort*)(smem + M1_ALO);
    ushort* H_hi = (ushort*)(smem + M1_HHI);
    ushort* H_lo = (ushort*)(smem + M1_HLO);
    int t = threadIdx.x;
    int nbase = blockIdx.x * 32;

    if (t < 128) {
        int n = t >> 2, cc = (t & 3) * 8;
        int gn = nbase + n;
        short8v vh = {0,0,0,0,0,0,0,0}, vl = {0,0,0,0,0,0,0,0};
        if (gn < NN) {
            const float4* xp = (const float4*)&x[gn * 32 + cc];
            const float4* gp = (const float4*)&agg1[gn * 32 + cc];
            float s[8];
            float4 x0 = xp[0], x1 = xp[1], g0 = gp[0], g1 = gp[1];
            s[0]=x0.x+g0.x; s[1]=x0.y+g0.y; s[2]=x0.z+g0.z; s[3]=x0.w+g0.w;
            s[4]=x1.x+g1.x; s[5]=x1.y+g1.y; s[6]=x1.z+g1.z; s[7]=x1.w+g1.w;
#pragma unroll
            for (int j = 0; j < 8; ++j) {
                ushort h = f2bf(s[j]);
                vh[j] = (short)h;
                vl[j] = (short)f2bf(s[j] - bf2f(h));
            }
        }
        *(short8v*)&A_hi[n * 40 + cc] = vh;
        *(short8v*)&A_lo[n * 40 + cc] = vl;
    }
    __syncthreads();

    int w = t >> 6, l = t & 63;
    int cl = l & 15, kq = l >> 4;
    int row0 = w * 32 + cl, row1 = w * 32 + 16 + cl;

    f32x4 acc[2][2];
#pragma unroll
    for (int mt = 0; mt < 2; ++mt) { acc[mt][0] = f32x4{0.f,0.f,0.f,0.f}; acc[mt][1] = f32x4{0.f,0.f,0.f,0.f}; }

    {
        int kof = kq * 8;
        int fb = (w * 2) * 512 + l * 8;
        short8v bh0 = *(const short8v*)&W1a_hi[fb];
        short8v bh1 = *(const short8v*)&W1a_hi[fb + 512];
        short8v bl0 = *(const short8v*)&W1a_lo[fb];
        short8v bl1 = *(const short8v*)&W1a_lo[fb + 512];
#pragma unroll
        for (int mt = 0; mt < 2; ++mt) {
            short8v ah = *(short8v*)&A_hi[(mt * 16 + cl) * 40 + kof];
            short8v al = *(short8v*)&A_lo[(mt * 16 + cl) * 40 + kof];
            acc[mt][0] = MFMA_BF16(ah, bh0, acc[mt][0], 0, 0, 0);
            acc[mt][0] = MFMA_BF16(al, bh0, acc[mt][0], 0, 0, 0);
            acc[mt][0] = MFMA_BF16(ah, bl0, acc[mt][0], 0, 0, 0);
            acc[mt][1] = MFMA_BF16(ah, bh1, acc[mt][1], 0, 0, 0);
            acc[mt][1] = MFMA_BF16(al, bh1, acc[mt][1], 0, 0, 0);
            acc[mt][1] = MFMA_BF16(ah, bl1, acc[mt][1], 0, 0, 0);
        }
    }
    {
        float bb0 = b1a[row0], bb1 = b1a[row1];
#pragma unroll
        for (int mt = 0; mt < 2; ++mt)
#pragma unroll
            for (int j = 0; j < 4; ++j) {
                int row = mt * 16 + kq * 4 + j;
                float v0 = fmaxf(acc[mt][0][j] + bb0, 0.f);
                float v1 = fmaxf(acc[mt][1][j] + bb1, 0.f);
                ushort h0 = f2bf(v0), h1v = f2bf(v1);
                H_hi[row * 136 + row0] = h0;
                H_lo[row * 136 + row0] = f2bf(v0 - bf2f(h0));
                H_hi[row * 136 + row1] = h1v;
                H_lo[row * 136 + row1] = f2bf(v1 - bf2f(h1v));
            }
    }
    __syncthreads();

#pragma unroll
    for (int mt = 0; mt < 2; ++mt) { acc[mt][0] = f32x4{0.f,0.f,0.f,0.f}; acc[mt][1] = f32x4{0.f,0.f,0.f,0.f}; }
#pragma unroll
    for (int ksl = 0; ksl < 4; ++ksl) {
        int kof = ksl * 32 + kq * 8;
        int fb = ((ksl * 4 + w) * 2) * 512 + l * 8;
        short8v bh0 = *(const short8v*)&W1b_hi[fb];
        short8v bh1 = *(const short8v*)&W1b_hi[fb + 512];
        short8v bl0 = *(const short8v*)&W1b_lo[fb];
        short8v bl1 = *(const short8v*)&W1b_lo[fb + 512];
#pragma unroll
        for (int mt = 0; mt < 2; ++mt) {
            short8v ah = *(short8v*)&H_hi[(mt * 16 + cl) * 136 + kof];
            short8v al = *(short8v*)&H_lo[(mt * 16 + cl) * 136 + kof];
            acc[mt][0] = MFMA_BF16(ah, bh0, acc[mt][0], 0, 0, 0);
            acc[mt][0] = MFMA_BF16(al, bh0, acc[mt][0], 0, 0, 0);
            acc[mt][0] = MFMA_BF16(ah, bl0, acc[mt][0], 0, 0, 0);
            acc[mt][1] = MFMA_BF16(ah, bh1, acc[mt][1], 0, 0, 0);
            acc[mt][1] = MFMA_BF16(al, bh1, acc[mt][1], 0, 0, 0);
            acc[mt][1] = MFMA_BF16(ah, bl1, acc[mt][1], 0, 0, 0);
        }
    }
    {
        float c0 = b1b[row0], c1 = b1b[row1];
#pragma unroll
        for (int mt = 0; mt < 2; ++mt)
#pragma unroll
            for (int j = 0; j < 4; ++j) {
                int gn = nbase + mt * 16 + kq * 4 + j;
                if (gn < NN) {
                    h1b[gn * 128 + row0] = f2bf(fmaxf(acc[mt][0][j] + c0, 0.f));
                    h1b[gn * 128 + row1] = f2bf(fmaxf(acc[mt][1][j] + c1, 0.f));
                }
            }
    }
}

// ---------------- MLP 2 (split-bf16 MFMA, fragment W) + fused pool ----------

#define M2_AHI 0
#define M2_ALO 8704
#define M2_HHI 17408
#define M2_HLO 26112
#define M2_B   34816
#define M2_SMEM 34944

__global__ __launch_bounds__(256) void k_mlp2(
        const ushort* __restrict__ h1b, const float* __restrict__ agg2,
        const ushort* __restrict__ W2a_hi, const ushort* __restrict__ W2a_lo,
        const float* __restrict__ b2a,
        const ushort* __restrict__ W2b_hi, const ushort* __restrict__ W2b_lo,
        const float* __restrict__ b2b,
        const int* __restrict__ batch, float* __restrict__ pooled) {
    __shared__ __align__(16) char smem[M2_SMEM];
    ushort* A_hi = (ushort*)(smem + M2_AHI);
    ushort* A_lo = (ushort*)(smem + M2_ALO);
    ushort* H_hi = (ushort*)(smem + M2_HHI);
    ushort* H_lo = (ushort*)(smem + M2_HLO);
    int* batch_s = (int*)(smem + M2_B);
    int t = threadIdx.x;
    int nbase = blockIdx.x * 32;

    if (t < 32) batch_s[t] = (nbase + t < NN) ? batch[nbase + t] : -1;

    for (int i = t; i < 512; i += 256) {
        int n = i >> 4, cc = (i & 15) * 8;
        int gn = nbase + n;
        short8v vh = {0,0,0,0,0,0,0,0}, vl = {0,0,0,0,0,0,0,0};
        if (gn < NN) {
            short8v hb = *(const short8v*)&h1b[gn * 128 + cc];
            const float4* gp = (const float4*)&agg2[gn * 128 + cc];
            float4 g0 = gp[0], g1 = gp[1];
            float s[8];
            s[0]=bf2f((ushort)hb[0])+g0.x; s[1]=bf2f((ushort)hb[1])+g0.y;
            s[2]=bf2f((ushort)hb[2])+g0.z; s[3]=bf2f((ushort)hb[3])+g0.w;
            s[4]=bf2f((ushort)hb[4])+g1.x; s[5]=bf2f((ushort)hb[5])+g1.y;
            s[6]=bf2f((ushort)hb[6])+g1.z; s[7]=bf2f((ushort)hb[7])+g1.w;
#pragma unroll
            for (int j = 0; j < 8; ++j) {
                ushort h = f2bf(s[j]);
                vh[j] = (short)h;
                vl[j] = (short)f2bf(s[j] - bf2f(h));
            }
        }
        *(short8v*)&A_hi[n * 136 + cc] = vh;
        *(short8v*)&A_lo[n * 136 + cc] = vl;
    }
    __syncthreads();

    int w = t >> 6, l = t & 63;
    int cl = l & 15, kq = l >> 4;
    int row0 = w * 32 + cl, row1 = w * 32 + 16 + cl;

    f32x4 acc[2][2];
#pragma unroll
    for (int mt = 0; mt < 2; ++mt) { acc[mt][0] = f32x4{0.f,0.f,0.f,0.f}; acc[mt][1] = f32x4{0.f,0.f,0.f,0.f}; }

#pragma unroll
    for (int ksl = 0; ksl < 4; ++ksl) {
        int kof = ksl * 32 + kq * 8;
        int fb = ((ksl * 4 + w) * 2) * 512 + l * 8;
        short8v bh0 = *(const short8v*)&W2a_hi[fb];
        short8v bh1 = *(const short8v*)&W2a_hi[fb + 512];
        short8v bl0 = *(const short8v*)&W2a_lo[fb];
        short8v bl1 = *(const short8v*)&W2a_lo[fb + 512];
#pragma unroll
        for (int mt = 0; mt < 2; ++mt) {
            short8v ah = *(short8v*)&A_hi[(mt * 16 + cl) * 136 + kof];
            short8v al = *(short8v*)&A_lo[(mt * 16 + cl) * 136 + kof];
            acc[mt][0] = MFMA_BF16(ah, bh0, acc[mt][0], 0, 0, 0);
            acc[mt][0] = MFMA_BF16(al, bh0, acc[mt][0], 0, 0, 0);
            acc[mt][0] = MFMA_BF16(ah, bl0, acc[mt][0], 0, 0, 0);
            acc[mt][1] = MFMA_BF16(ah, bh1, acc[mt][1], 0, 0, 0);
            acc[mt][1] = MFMA_BF16(al, bh1, acc[mt][1], 0, 0, 0);
            acc[mt][1] = MFMA_BF16(ah, bl1, acc[mt][1], 0, 0, 0);
        }
    }
    {
        float bb0 = b2a[row0], bb1 = b2a[row1];
#pragma unroll
        for (int mt = 0; mt < 2; ++mt)
#pragma unroll
            for (int j = 0; j < 4; ++j) {
                int row = mt * 16 + kq * 4 + j;
                float v0 = fmaxf(acc[mt][0][j] + bb0, 0.f);
                float v1 = fmaxf(acc[mt][1][j] + bb1, 0.f);
                ushort h0 = f2bf(v0), h1v = f2bf(v1);
                H_hi[row * 136 + row0] = h0;
                H_lo[row * 136 + row0] = f2bf(v0 - bf2f(h0));
                H_hi[row * 136 + row1] = h1v;
                H_lo[row * 136 + row1] = f2bf(v1 - bf2f(h1v));
            }
    }
    __syncthreads();

#pragma unroll
    for (int mt = 0; mt < 2; ++mt) { acc[mt][0] = f32x4{0.f,0.f,0.f,0.f}; acc[mt][1] = f32x4{0.f,0.f,0.f,0.f}; }
#pragma unroll
    for (int ksl = 0; ksl < 4; ++ksl) {
        int kof = ksl * 32 + kq * 8;
        int fb = ((ksl * 4 + w) * 2) * 512 + l * 8;
        short8v bh0 = *(const short8v*)&W2b_hi[fb];
        short8v bh1 = *(const short8v*)&W2b_hi[fb + 512];
        short8v bl0 = *(const short8v*)&W2b_lo[fb];
        short8v bl1 = *(const short8v*)&W2b_lo[fb + 512];
#pragma unroll
        for (int mt = 0; mt < 2; ++mt) {
            short8v ah = *(short8v*)&H_hi[(mt * 16 + cl) * 136 + kof];
            short8v al = *(short8v*)&H_lo[(mt * 16 + cl) * 136 + kof];
            acc[mt][0] = MFMA_BF16(ah, bh0, acc[mt][0], 0, 0, 0);
            acc[mt][0] = MFMA_BF16(al, bh0, acc[mt][0], 0, 0, 0);
            acc[mt][0] = MFMA_BF16(ah, bl0, acc[mt][0], 0, 0, 0);
            acc[mt][1] = MFMA_BF16(ah, bh1, acc[mt][1], 0, 0, 0);
            acc[mt][1] = MFMA_BF16(al, bh1, acc[mt][1], 0, 0, 0);
            acc[mt][1] = MFMA_BF16(ah, bl1, acc[mt][1], 0, 0, 0);
        }
    }
    __syncthreads();
    float* P = (float*)smem;  // [32][132]
    {
        float c0 = b2b[row0], c1 = b2b[row1];
#pragma unroll
        for (int mt = 0; mt < 2; ++mt)
#pragma unroll
            for (int j = 0; j < 4; ++j) {
                int row = mt * 16 + kq * 4 + j;
                P[row * 132 + row0] = fmaxf(acc[mt][0][j] + c0, 0.f);
                P[row * 132 + row1] = fmaxf(acc[mt][1][j] + c1, 0.f);
            }
    }
    __syncthreads();

    {
        int c = t & 127, half = t >> 7;
        int i0 = half * 16;
        float run = 0.f;
        int cur = batch_s[i0];
        if (cur >= 0) {
            for (int i = i0; i < i0 + 16; ++i) {
                int b = batch_s[i];
                if (b < 0) break;
                if (b != cur) { atomicAdd(&pooled[cur * 128 + c], run); run = 0.f; cur = b; }
                run += P[i * 132 + c];
            }
            atomicAdd(&pooled[cur * 128 + c], run);
        }
    }
}

// ---------------- Readout: relu(pooled@Wm1+bm1)@Wm2+bm2 ----------------

__global__ __launch_bounds__(128) void k_readout(
        const float* __restrict__ pooled, const float* __restrict__ Wm1,
        const float* __restrict__ bm1, const float* __restrict__ Wm2,
        const float* __restrict__ bm2, float* __restrict__ out) {
    __shared__ float row[128];
    __shared__ float red[128];
    int g = blockIdx.x, t = threadIdx.x;
    row[t] = pooled[g * 128 + t];
    __syncthreads();
    float acc = bm1[t];
    for (int c = 0; c < 128; ++c) acc = fmaf(row[c], Wm1[c * 128 + t], acc);
    float term = fmaxf(acc, 0.f) * Wm2[t];
    red[t] = term;
    __syncthreads();
    for (int off = 64; off > 0; off >>= 1) {
        if (t < off) red[t] += red[t + off];
        __syncthreads();
    }
    if (t == 0) out[g] = red[0] + bm2[0];
}

// ---------------- Launch ----------------

extern "C" void kernel_launch(void* const* d_in, const int* in_sizes, int n_in,
                              void* d_out, int out_size, void* d_ws, size_t ws_size,
                              hipStream_t stream) {
    const float* x    = (const float*)d_in[0];
    const int* eidx   = (const int*)d_in[1];
    const float* ea   = (const float*)d_in[2];
    const int* batch  = (const int*)d_in[3];
    const float* We1  = (const float*)d_in[4];
    const float* be1  = (const float*)d_in[5];
    const float* W1a  = (const float*)d_in[6];
    const float* b1a  = (const float*)d_in[7];
    const float* W1b  = (const float*)d_in[8];
    const float* b1b  = (const float*)d_in[9];
    const float* We2  = (const float*)d_in[10];
    const float* be2  = (const float*)d_in[11];
    const float* W2a  = (const float*)d_in[12];
    const float* b2a  = (const float*)d_in[13];
    const float* W2b  = (const float*)d_in[14];
    const float* b2b  = (const float*)d_in[15];
    const float* Wm1  = (const float*)d_in[16];
    const float* bm1  = (const float*)d_in[17];
    const float* Wm2  = (const float*)d_in[18];
    const float* bm2  = (const float*)d_in[19];
    float* out = (float*)d_out;

    const int* src = eidx;
    const int* dst = eidx + NE;

    char* w = (char*)d_ws;
    auto alloc = [&](size_t bytes) { void* p = (void*)w; w += (bytes + 255) & ~(size_t)255; return p; };
    int* counts     = (int*)alloc(NN * 4);
    int* row_ptr    = (int*)alloc((NN + 1) * 4);
    int* cursor     = (int*)alloc(NN * 4);
    int* bsum       = (int*)alloc(512 * 4);
    int* bhist      = (int*)alloc(256 * 4);
    int* bkt_off    = (int*)alloc(256 * 4);
    int* bkt_cursor = (int*)alloc(256 * 4);
    uint2* csr      = (uint2*)alloc((size_t)NE * 8);
    uint2* tmp      = (uint2*)alloc((size_t)NE * 8);
    float* agg1     = (float*)alloc((size_t)NN * 32 * 4);
    ushort* h1b     = (ushort*)alloc((size_t)NN * 128 * 2);
    float* agg2     = (float*)alloc((size_t)NN * 128 * 4);
    float* pooled   = (float*)alloc((size_t)NG * 128 * 4);
    ushort* xb      = (ushort*)alloc((size_t)NN * 32 * 2);
    ushort* W1a_hi  = (ushort*)alloc(4096 * 2);
    ushort* W1a_lo  = (ushort*)alloc(4096 * 2);
    ushort* W1b_hi  = (ushort*)alloc(16384 * 2);
    ushort* W1b_lo  = (ushort*)alloc(16384 * 2);
    ushort* W2a_hi  = (ushort*)alloc(16384 * 2);
    ushort* W2a_lo  = (ushort*)alloc(16384 * 2);
    ushort* W2b_hi  = (ushort*)alloc(16384 * 2);
    ushort* W2b_lo  = (ushort*)alloc(16384 * 2);

    hipMemsetAsync(counts, 0, NN * 4, stream);
    hipMemsetAsync(bhist, 0, 256 * 4, stream);
    hipMemsetAsync(pooled, 0, (size_t)NG * 128 * 4, stream);

    const int EB = (NE + 255) / 256;       // 6250
    const int NB = (NN + 255) / 256;       // 391
    const int MB = (NN + 31) / 32;         // 3125

    k_prep<<<208, 256, 0, stream>>>(W1a, W1b, W2a, W2b,
                                    W1a_hi, W1a_lo, W1b_hi, W1b_lo,
                                    W2a_hi, W2a_lo, W2b_hi, W2b_lo);
    k_xcast<<<3125, 256, 0, stream>>>(x, xb);
    k_count<<<EB, 256, 0, stream>>>(dst, counts);
    k_bsum<<<NB, 256, 0, stream>>>(counts, bsum);
    k_scan512<<<1, 512, 0, stream>>>(bsum, NB);
    k_scan_counts<<<NB, 256, 0, stream>>>(counts, bsum, row_ptr, cursor);
    k_bhist<<<BINBLKS, 256, 0, stream>>>(dst, bhist);
    k_bscan<<<1, 256, 0, stream>>>(bhist, bkt_off, bkt_cursor);
    k_binfill<<<BINBLKS, 256, 0, stream>>>(src, dst, ea, bkt_cursor, tmp);
    k_scatter<<<NBKT, 256, 0, stream>>>(tmp, bkt_off, cursor, csr);

    k_agg1<<<NN / 8, 256, 0, stream>>>(xb, csr, row_ptr, We1, be1, agg1);
    k_mlp1<<<MB, 256, 0, stream>>>(x, agg1, W1a_hi, W1a_lo, b1a, W1b_hi, W1b_lo, b1b, h1b);
    k_agg2<<<NN / 4, 256, 0, stream>>>(h1b, csr, row_ptr, We2, be2, agg2);
    k_mlp2<<<MB, 256, 0, stream>>>(h1b, agg2, W2a_hi, W2a_lo, b2a, W2b_hi, W2b_lo, b2b, batch, pooled);
    k_readout<<<NG, 128, 0, stream>>>(pooled, Wm1, bm1, Wm2, bm2, out);
}

// Round 12
// 335.279 us; speedup vs baseline: 5.5865x; 1.3090x over previous
//
#include <hip/hip_runtime.h>
#include <hip/hip_bf16.h>

#define NN 100000
#define NE 1600000
#define NG 2048
#define NBKT 196          // buckets of 512 nodes (dst>>9)
#define EPB 4096          // edges per binfill block
#define BINBLKS ((NE + EPB - 1) / EPB)   // 391

typedef __attribute__((ext_vector_type(8))) short short8v;
typedef __attribute__((ext_vector_type(4))) float f32x4;

__device__ inline ushort f2bf(float f) {
    uint u = __float_as_uint(f);
    uint r = (u + 0x7fffu + ((u >> 16) & 1u)) >> 16;
    return (ushort)r;
}
__device__ inline float bf2f(ushort h) {
    return __uint_as_float(((uint)h) << 16);
}

#define MFMA_BF16 __builtin_amdgcn_mfma_f32_16x16x32_bf16

// MFMA B-fragment permutation: element (out-ch c, k) -> flat offset.
__device__ inline int frag128(int k, int c) {
    int w = c >> 5, half = (c >> 4) & 1, cl = c & 15;
    int ksl = k >> 5, kq = (k >> 3) & 3, k0 = k & 7;
    return ((ksl * 4 + w) * 2 + half) * 512 + (kq * 16 + cl) * 8 + k0;
}
__device__ inline int frag32(int k, int c) {
    int w = c >> 5, half = (c >> 4) & 1, cl = c & 15;
    int kq = (k >> 3) & 3, k0 = k & 7;
    return (w * 2 + half) * 512 + (kq * 16 + cl) * 8 + k0;
}

// ---------------- bucket histogram + scan ----------------

__global__ __launch_bounds__(256) void k_bhist(const int* __restrict__ dst,
                                               int* __restrict__ bhist) {
    __shared__ int h[NBKT];
    int t = threadIdx.x;
    for (int i = t; i < NBKT; i += 256) h[i] = 0;
    __syncthreads();
    int e0 = blockIdx.x * EPB;
    int n = NE - e0; if (n > EPB) n = EPB;
    for (int i = t; i < n; i += 256)
        atomicAdd(&h[dst[e0 + i] >> 9], 1);
    __syncthreads();
    for (int i = t; i < NBKT; i += 256)
        if (h[i]) atomicAdd(&bhist[i], h[i]);
}

__global__ void k_bscan(const int* __restrict__ bhist,
                        int* __restrict__ bkt_off, int* __restrict__ bkt_cursor) {
    __shared__ int s[256];
    int t = threadIdx.x;
    int v = (t < NBKT) ? bhist[t] : 0;
    s[t] = v;
    __syncthreads();
    for (int off = 1; off < 256; off <<= 1) {
        int add = (t >= off) ? s[t - off] : 0;
        __syncthreads();
        s[t] += add;
        __syncthreads();
    }
    int excl = s[t] - v;
    if (t < NBKT) { bkt_off[t] = excl; bkt_cursor[t] = excl; }
    if (t == NBKT - 1) bkt_off[NBKT] = excl + v;
}

// ---------------- binfill: LDS-group edges by bucket, flush coalesced -------------
// edge record: lo = src(17) | dstLow15<<17 ; hi = dstHigh2 | ea30<<2

__global__ __launch_bounds__(256) void k_binfill(
        const int* __restrict__ src, const int* __restrict__ dst,
        const float* __restrict__ ea,
        int* __restrict__ bkt_cursor, uint2* __restrict__ tmp) {
    __shared__ int hist[NBKT];
    __shared__ int boff[NBKT];
    __shared__ int base[NBKT];
    __shared__ int s[256];
    __shared__ uint2 stage[EPB];
    __shared__ unsigned char stage_bkt[EPB];
    int t = threadIdx.x;
    int e0 = blockIdx.x * EPB;
    int n = NE - e0; if (n > EPB) n = EPB;

    for (int i = t; i < NBKT; i += 256) hist[i] = 0;
    __syncthreads();

    uint lo[16], hi[16]; int bk[16], pos[16];
#pragma unroll
    for (int j = 0; j < 16; ++j) {
        int i = j * 256 + t;
        bk[j] = -1;
        if (i < n) {
            int e = e0 + i;
            int sn = src[e], d = dst[e];
            uint q0 = (uint)__float2int_rn(ea[3 * e]     * 1023.f);
            uint q1 = (uint)__float2int_rn(ea[3 * e + 1] * 1023.f);
            uint q2 = (uint)__float2int_rn(ea[3 * e + 2] * 1023.f);
            uint q = (q0 << 20) | (q1 << 10) | q2;
            lo[j] = (uint)sn | ((uint)(d & 0x7FFF) << 17);
            hi[j] = (uint)(d >> 15) | (q << 2);
            bk[j] = d >> 9;
            pos[j] = atomicAdd(&hist[bk[j]], 1);
        }
    }
    __syncthreads();
    int v = (t < NBKT) ? hist[t] : 0;
    s[t] = v;
    __syncthreads();
    for (int off = 1; off < 256; off <<= 1) {
        int add = (t >= off) ? s[t - off] : 0;
        __syncthreads();
        s[t] += add;
        __syncthreads();
    }
    if (t < NBKT) {
        boff[t] = s[t] - v;
        base[t] = v ? atomicAdd(&bkt_cursor[t], v) : 0;
    }
    __syncthreads();
#pragma unroll
    for (int j = 0; j < 16; ++j) {
        if (bk[j] >= 0) {
            int slot = boff[bk[j]] + pos[j];
            stage[slot] = make_uint2(lo[j], hi[j]);
            stage_bkt[slot] = (unsigned char)bk[j];
        }
    }
    __syncthreads();
    for (int i = t; i < n; i += 256) {
        int b = stage_bkt[i];
        tmp[base[b] + (i - boff[b])] = stage[i];
    }
}

// ---------------- scatter: one block per bucket; builds row_ptr via LDS hist+scan ---

__global__ __launch_bounds__(256) void k_scatter(
        const uint2* __restrict__ tmp, const int* __restrict__ bkt_off,
        int* __restrict__ row_ptr, uint2* __restrict__ csr) {
    __shared__ int hist[512];
    __shared__ int cur[512];
    __shared__ int s[256];
    int b = blockIdx.x, t = threadIdx.x;
    int start = bkt_off[b], end = bkt_off[b + 1];
    hist[t] = 0; hist[t + 256] = 0;
    __syncthreads();
    for (int i = start + t; i < end; i += 256) {
        uint2 r = tmp[i];
        int d = (int)((r.x >> 17) | ((r.y & 3u) << 15));
        atomicAdd(&hist[d & 511], 1);
    }
    __syncthreads();
    int h0 = hist[2 * t], h1 = hist[2 * t + 1];
    int v = h0 + h1;
    s[t] = v;
    __syncthreads();
    for (int off = 1; off < 256; off <<= 1) {
        int add = (t >= off) ? s[t - off] : 0;
        __syncthreads();
        s[t] += add;
        __syncthreads();
    }
    int e0 = start + s[t] - v;  // exclusive scan base for node pair
    int node0 = b * 512 + 2 * t;
    if (node0 < NN) row_ptr[node0] = e0;
    if (node0 + 1 < NN) row_ptr[node0 + 1] = e0 + h0;
    cur[2 * t] = e0;
    cur[2 * t + 1] = e0 + h0;
    if (b == NBKT - 1 && t == 0) row_ptr[NN] = end;
    __syncthreads();
    for (int i = start + t; i < end; i += 256) {
        uint2 r = tmp[i];
        int sn = (int)(r.x & 0x1FFFFu);
        int d = (int)((r.x >> 17) | ((r.y & 3u) << 15));
        int p = atomicAdd(&cur[d & 511], 1);
        csr[p] = make_uint2((uint)sn, r.y >> 2);
    }
}

// ---------------- x -> bf16 copy (for agg1 gather) ----------------

__global__ void k_xcast(const float* __restrict__ x, ushort* __restrict__ xb) {
    int i = blockIdx.x * 256 + threadIdx.x;
    if (i < NN * 32 / 4) {
        float4 v = ((const float4*)x)[i];
        ushort4 o;
        o.x = f2bf(v.x); o.y = f2bf(v.y); o.z = f2bf(v.z); o.w = f2bf(v.w);
        ((ushort4*)xb)[i] = o;
    }
}

// ---------------- weight prep: f32 [K][C] -> bf16 hi/lo in MFMA-fragment order -------

__global__ void k_prep(const float* __restrict__ W1a, const float* __restrict__ W1b,
                       const float* __restrict__ W2a, const float* __restrict__ W2b,
                       ushort* __restrict__ W1a_hi, ushort* __restrict__ W1a_lo,
                       ushort* __restrict__ W1b_hi, ushort* __restrict__ W1b_lo,
                       ushort* __restrict__ W2a_hi, ushort* __restrict__ W2a_lo,
                       ushort* __restrict__ W2b_hi, ushort* __restrict__ W2b_lo) {
    int i = blockIdx.x * 256 + threadIdx.x;
    float v; ushort* ph; ushort* pl; int off;
    if (i < 4096) {
        int k = i >> 7, c = i & 127;
        v = W1a[i]; ph = W1a_hi; pl = W1a_lo; off = frag32(k, c);
    } else if (i < 20480) {
        int j = i - 4096; int k = j >> 7, c = j & 127;
        v = W1b[j]; ph = W1b_hi; pl = W1b_lo; off = frag128(k, c);
    } else if (i < 36864) {
        int j = i - 20480; int k = j >> 7, c = j & 127;
        v = W2a[j]; ph = W2a_hi; pl = W2a_lo; off = frag128(k, c);
    } else if (i < 53248) {
        int j = i - 36864; int k = j >> 7, c = j & 127;
        v = W2b[j]; ph = W2b_hi; pl = W2b_lo; off = frag128(k, c);
    } else return;
    ushort h = f2bf(v);
    ph[off] = h;
    pl[off] = f2bf(v - bf2f(h));
}

// ---------------- Layer 1 aggregation (bf16 x gather, 32 ch), 8-deep ----------------

__global__ __launch_bounds__(256) void k_agg1(
        const ushort* __restrict__ xb, const uint2* __restrict__ csr,
        const int* __restrict__ row_ptr,
        const float* __restrict__ We1, const float* __restrict__ be1,
        float* __restrict__ agg1) {
    int lane = threadIdx.x & 31;
    int node = blockIdx.x * 8 + (threadIdx.x >> 5);
    const float qs = 1.f / 1023.f;
    float w0 = We1[lane] * qs, w1 = We1[32 + lane] * qs, w2 = We1[64 + lane] * qs;
    float b = be1[lane];
    int p0 = row_ptr[node], p1 = row_ptr[node + 1];
    float acc = 0.f;
    int p = p0;
    for (; p + 8 <= p1; p += 8) {
        uint2 e[8]; ushort v[8];
#pragma unroll
        for (int j = 0; j < 8; ++j) e[j] = csr[p + j];
#pragma unroll
        for (int j = 0; j < 8; ++j) v[j] = xb[e[j].x * 32 + lane];
#pragma unroll
        for (int j = 0; j < 8; ++j) {
            float a0 = (float)(e[j].y >> 20);
            float a1 = (float)((e[j].y >> 10) & 1023u);
            float a2 = (float)(e[j].y & 1023u);
            float el = fmaf(a0, w0, fmaf(a1, w1, fmaf(a2, w2, b)));
            acc += fmaxf(bf2f(v[j]) + el, 0.f);
        }
    }
    for (; p + 4 <= p1; p += 4) {
        uint2 e[4]; ushort v[4];
#pragma unroll
        for (int j = 0; j < 4; ++j) e[j] = csr[p + j];
#pragma unroll
        for (int j = 0; j < 4; ++j) v[j] = xb[e[j].x * 32 + lane];
#pragma unroll
        for (int j = 0; j < 4; ++j) {
            float a0 = (float)(e[j].y >> 20);
            float a1 = (float)((e[j].y >> 10) & 1023u);
            float a2 = (float)(e[j].y & 1023u);
            float el = fmaf(a0, w0, fmaf(a1, w1, fmaf(a2, w2, b)));
            acc += fmaxf(bf2f(v[j]) + el, 0.f);
        }
    }
    for (; p < p1; ++p) {
        uint2 ed = csr[p];
        ushort v = xb[ed.x * 32 + lane];
        float a0 = (float)(ed.y >> 20);
        float a1 = (float)((ed.y >> 10) & 1023u);
        float a2 = (float)(ed.y & 1023u);
        float el = fmaf(a0, w0, fmaf(a1, w1, fmaf(a2, w2, b)));
        acc += fmaxf(bf2f(v) + el, 0.f);
    }
    agg1[node * 32 + lane] = acc;
}

// ---------------- Layer 2 aggregation: 1 wave/node, 2 ch/lane; SCALAR csr stream ----
// node (and thus row_ptr range and every csr entry address) is wave-uniform:
// readfirstlane makes it SGPR-derived so the compiler can emit s_load for csr.

__global__ __launch_bounds__(256) void k_agg2(
        const ushort* __restrict__ h1b, const uint2* __restrict__ csr,
        const int* __restrict__ row_ptr,
        const float* __restrict__ We2, const float* __restrict__ be2,
        float* __restrict__ agg2) {
    int lane = threadIdx.x & 63;
    int node = __builtin_amdgcn_readfirstlane(blockIdx.x * 4 + (threadIdx.x >> 6));
    int c = lane * 2;
    const float qs = 1.f / 1023.f;
    float w0a = We2[c] * qs,       w0b = We2[c + 1] * qs;
    float w1a = We2[128 + c] * qs, w1b = We2[129 + c] * qs;
    float w2a = We2[256 + c] * qs, w2b = We2[257 + c] * qs;
    float ba  = be2[c],            bb  = be2[c + 1];
    const uint* h1u = (const uint*)h1b;
    int p0 = __builtin_amdgcn_readfirstlane(row_ptr[node]);
    int p1 = __builtin_amdgcn_readfirstlane(row_ptr[node + 1]);
    float accA = 0.f, accB = 0.f;
    int p = p0;
    for (; p + 8 <= p1; p += 8) {
        uint2 e[8]; uint u[8];
#pragma unroll
        for (int j = 0; j < 8; ++j) e[j] = csr[p + j];
#pragma unroll
        for (int j = 0; j < 8; ++j) u[j] = h1u[e[j].x * 64 + lane];
#pragma unroll
        for (int j = 0; j < 8; ++j) {
            float a0 = (float)(e[j].y >> 20);
            float a1 = (float)((e[j].y >> 10) & 1023u);
            float a2 = (float)(e[j].y & 1023u);
            float elA = fmaf(a0, w0a, fmaf(a1, w1a, fmaf(a2, w2a, ba)));
            float elB = fmaf(a0, w0b, fmaf(a1, w1b, fmaf(a2, w2b, bb)));
            accA += fmaxf(bf2f((ushort)(u[j] & 0xffffu)) + elA, 0.f);
            accB += fmaxf(bf2f((ushort)(u[j] >> 16)) + elB, 0.f);
        }
    }
    for (; p + 4 <= p1; p += 4) {
        uint2 e[4]; uint u[4];
#pragma unroll
        for (int j = 0; j < 4; ++j) e[j] = csr[p + j];
#pragma unroll
        for (int j = 0; j < 4; ++j) u[j] = h1u[e[j].x * 64 + lane];
#pragma unroll
        for (int j = 0; j < 4; ++j) {
            float a0 = (float)(e[j].y >> 20);
            float a1 = (float)((e[j].y >> 10) & 1023u);
            float a2 = (float)(e[j].y & 1023u);
            float elA = fmaf(a0, w0a, fmaf(a1, w1a, fmaf(a2, w2a, ba)));
            float elB = fmaf(a0, w0b, fmaf(a1, w1b, fmaf(a2, w2b, bb)));
            accA += fmaxf(bf2f((ushort)(u[j] & 0xffffu)) + elA, 0.f);
            accB += fmaxf(bf2f((ushort)(u[j] >> 16)) + elB, 0.f);
        }
    }
    for (; p < p1; ++p) {
        uint2 ed = csr[p];
        uint u = h1u[ed.x * 64 + lane];
        float a0 = (float)(ed.y >> 20);
        float a1 = (float)((ed.y >> 10) & 1023u);
        float a2 = (float)(ed.y & 1023u);
        float elA = fmaf(a0, w0a, fmaf(a1, w1a, fmaf(a2, w2a, ba)));
        float elB = fmaf(a0, w0b, fmaf(a1, w1b, fmaf(a2, w2b, bb)));
        accA += fmaxf(bf2f((ushort)(u & 0xffffu)) + elA, 0.f);
        accB += fmaxf(bf2f((ushort)(u >> 16)) + elB, 0.f);
    }
    *(float2*)&agg2[node * 128 + c] = make_float2(accA, accB);
}

// ---------------- MLP 1 (split-bf16 MFMA, fragment-coalesced W from global) ----------

#define M1_AHI 0
#define M1_ALO 2560
#define M1_HHI 5120
#define M1_HLO 13824
#define M1_SMEM 22528

__global__ __launch_bounds__(256) void k_mlp1(
        const float* __restrict__ x, const float* __restrict__ agg1,
        const ushort* __restrict__ W1a_hi, const ushort* __restrict__ W1a_lo,
        const float* __restrict__ b1a,
        const ushort* __restrict__ W1b_hi, const ushort* __restrict__ W1b_lo,
        const float* __restrict__ b1b,
        ushort* __restrict__ h1b) {
    __shared__ __align__(16) char smem[M1_SMEM];
    ushort* A_hi = (ushort*)(smem + M1_AHI);
    ushort* A_lo = (ushort*)(smem + M1_ALO);
    ushort* H_hi = (ushort*)(smem + M1_HHI);
    ushort* H_lo = (ushort*)(smem + M1_HLO);
    int t = threadIdx.x;
    int nbase = blockIdx.x * 32;

    if (t < 128) {
        int n = t >> 2, cc = (t & 3) * 8;
        int gn = nbase + n;
        short8v vh = {0,0,0,0,0,0,0,0}, vl = {0,0,0,0,0,0,0,0};
        if (gn < NN) {
            const float4* xp = (const float4*)&x[gn * 32 + cc];
            const float4* gp = (const float4*)&agg1[gn * 32 + cc];
            float s[8];
            float4 x0 = xp[0], x1 = xp[1], g0 = gp[0], g1 = gp[1];
            s[0]=x0.x+g0.x; s[1]=x0.y+g0.y; s[2]=x0.z+g0.z; s[3]=x0.w+g0.w;
            s[4]=x1.x+g1.x; s[5]=x1.y+g1.y; s[6]=x1.z+g1.z; s[7]=x1.w+g1.w;
#pragma unroll
            for (int j = 0; j < 8; ++j) {
                ushort h = f2bf(s[j]);
                vh[j] = (short)h;
                vl[j] = (short)f2bf(s[j] - bf2f(h));
            }
        }
        *(short8v*)&A_hi[n * 40 + cc] = vh;
        *(short8v*)&A_lo[n * 40 + cc] = vl;
    }
    __syncthreads();

    int w = t >> 6, l = t & 63;
    int cl = l & 15, kq = l >> 4;
    int row0 = w * 32 + cl, row1 = w * 32 + 16 + cl;

    f32x4 acc[2][2];
#pragma unroll
    for (int mt = 0; mt < 2; ++mt) { acc[mt][0] = f32x4{0.f,0.f,0.f,0.f}; acc[mt][1] = f32x4{0.f,0.f,0.f,0.f}; }

    {
        int kof = kq * 8;
        int fb = (w * 2) * 512 + l * 8;
        short8v bh0 = *(const short8v*)&W1a_hi[fb];
        short8v bh1 = *(const short8v*)&W1a_hi[fb + 512];
        short8v bl0 = *(const short8v*)&W1a_lo[fb];
        short8v bl1 = *(const short8v*)&W1a_lo[fb + 512];
#pragma unroll
        for (int mt = 0; mt < 2; ++mt) {
            short8v ah = *(short8v*)&A_hi[(mt * 16 + cl) * 40 + kof];
            short8v al = *(short8v*)&A_lo[(mt * 16 + cl) * 40 + kof];
            acc[mt][0] = MFMA_BF16(ah, bh0, acc[mt][0], 0, 0, 0);
            acc[mt][0] = MFMA_BF16(al, bh0, acc[mt][0], 0, 0, 0);
            acc[mt][0] = MFMA_BF16(ah, bl0, acc[mt][0], 0, 0, 0);
            acc[mt][1] = MFMA_BF16(ah, bh1, acc[mt][1], 0, 0, 0);
            acc[mt][1] = MFMA_BF16(al, bh1, acc[mt][1], 0, 0, 0);
            acc[mt][1] = MFMA_BF16(ah, bl1, acc[mt][1], 0, 0, 0);
        }
    }
    {
        float bb0 = b1a[row0], bb1 = b1a[row1];
#pragma unroll
        for (int mt = 0; mt < 2; ++mt)
#pragma unroll
            for (int j = 0; j < 4; ++j) {
                int row = mt * 16 + kq * 4 + j;
                float v0 = fmaxf(acc[mt][0][j] + bb0, 0.f);
                float v1 = fmaxf(acc[mt][1][j] + bb1, 0.f);
                ushort h0 = f2bf(v0), h1v = f2bf(v1);
                H_hi[row * 136 + row0] = h0;
                H_lo[row * 136 + row0] = f2bf(v0 - bf2f(h0));
                H_hi[row * 136 + row1] = h1v;
                H_lo[row * 136 + row1] = f2bf(v1 - bf2f(h1v));
            }
    }
    __syncthreads();

#pragma unroll
    for (int mt = 0; mt < 2; ++mt) { acc[mt][0] = f32x4{0.f,0.f,0.f,0.f}; acc[mt][1] = f32x4{0.f,0.f,0.f,0.f}; }
#pragma unroll
    for (int ksl = 0; ksl < 4; ++ksl) {
        int kof = ksl * 32 + kq * 8;
        int fb = ((ksl * 4 + w) * 2) * 512 + l * 8;
        short8v bh0 = *(const short8v*)&W1b_hi[fb];
        short8v bh1 = *(const short8v*)&W1b_hi[fb + 512];
        short8v bl0 = *(const short8v*)&W1b_lo[fb];
        short8v bl1 = *(const short8v*)&W1b_lo[fb + 512];
#pragma unroll
        for (int mt = 0; mt < 2; ++mt) {
            short8v ah = *(short8v*)&H_hi[(mt * 16 + cl) * 136 + kof];
            short8v al = *(short8v*)&H_lo[(mt * 16 + cl) * 136 + kof];
            acc[mt][0] = MFMA_BF16(ah, bh0, acc[mt][0], 0, 0, 0);
            acc[mt][0] = MFMA_BF16(al, bh0, acc[mt][0], 0, 0, 0);
            acc[mt][0] = MFMA_BF16(ah, bl0, acc[mt][0], 0, 0, 0);
            acc[mt][1] = MFMA_BF16(ah, bh1, acc[mt][1], 0, 0, 0);
            acc[mt][1] = MFMA_BF16(al, bh1, acc[mt][1], 0, 0, 0);
            acc[mt][1] = MFMA_BF16(ah, bl1, acc[mt][1], 0, 0, 0);
        }
    }
    {
        float c0 = b1b[row0], c1 = b1b[row1];
#pragma unroll
        for (int mt = 0; mt < 2; ++mt)
#pragma unroll
            for (int j = 0; j < 4; ++j) {
                int gn = nbase + mt * 16 + kq * 4 + j;
                if (gn < NN) {
                    h1b[gn * 128 + row0] = f2bf(fmaxf(acc[mt][0][j] + c0, 0.f));
                    h1b[gn * 128 + row1] = f2bf(fmaxf(acc[mt][1][j] + c1, 0.f));
                }
            }
    }
}

// ---------------- MLP 2 (split-bf16 MFMA, fragment W) + fused pool ----------

#define M2_AHI 0
#define M2_ALO 8704
#define M2_HHI 17408
#define M2_HLO 26112
#define M2_B   34816
#define M2_SMEM 34944

__global__ __launch_bounds__(256) void k_mlp2(
        const ushort* __restrict__ h1b, const float* __restrict__ agg2,
        const ushort* __restrict__ W2a_hi, const ushort* __restrict__ W2a_lo,
        const float* __restrict__ b2a,
        const ushort* __restrict__ W2b_hi, const ushort* __restrict__ W2b_lo,
        const float* __restrict__ b2b,
        const int* __restrict__ batch, float* __restrict__ pooled) {
    __shared__ __align__(16) char smem[M2_SMEM];
    ushort* A_hi = (ushort*)(smem + M2_AHI);
    ushort* A_lo = (ushort*)(smem + M2_ALO);
    ushort* H_hi = (ushort*)(smem + M2_HHI);
    ushort* H_lo = (ushort*)(smem + M2_HLO);
    int* batch_s = (int*)(smem + M2_B);
    int t = threadIdx.x;
    int nbase = blockIdx.x * 32;

    if (t < 32) batch_s[t] = (nbase + t < NN) ? batch[nbase + t] : -1;

    for (int i = t; i < 512; i += 256) {
        int n = i >> 4, cc = (i & 15) * 8;
        int gn = nbase + n;
        short8v vh = {0,0,0,0,0,0,0,0}, vl = {0,0,0,0,0,0,0,0};
        if (gn < NN) {
            short8v hb = *(const short8v*)&h1b[gn * 128 + cc];
            const float4* gp = (const float4*)&agg2[gn * 128 + cc];
            float4 g0 = gp[0], g1 = gp[1];
            float s[8];
            s[0]=bf2f((ushort)hb[0])+g0.x; s[1]=bf2f((ushort)hb[1])+g0.y;
            s[2]=bf2f((ushort)hb[2])+g0.z; s[3]=bf2f((ushort)hb[3])+g0.w;
            s[4]=bf2f((ushort)hb[4])+g1.x; s[5]=bf2f((ushort)hb[5])+g1.y;
            s[6]=bf2f((ushort)hb[6])+g1.z; s[7]=bf2f((ushort)hb[7])+g1.w;
#pragma unroll
            for (int j = 0; j < 8; ++j) {
                ushort h = f2bf(s[j]);
                vh[j] = (short)h;
                vl[j] = (short)f2bf(s[j] - bf2f(h));
            }
        }
        *(short8v*)&A_hi[n * 136 + cc] = vh;
        *(short8v*)&A_lo[n * 136 + cc] = vl;
    }
    __syncthreads();

    int w = t >> 6, l = t & 63;
    int cl = l & 15, kq = l >> 4;
    int row0 = w * 32 + cl, row1 = w * 32 + 16 + cl;

    f32x4 acc[2][2];
#pragma unroll
    for (int mt = 0; mt < 2; ++mt) { acc[mt][0] = f32x4{0.f,0.f,0.f,0.f}; acc[mt][1] = f32x4{0.f,0.f,0.f,0.f}; }

#pragma unroll
    for (int ksl = 0; ksl < 4; ++ksl) {
        int kof = ksl * 32 + kq * 8;
        int fb = ((ksl * 4 + w) * 2) * 512 + l * 8;
        short8v bh0 = *(const short8v*)&W2a_hi[fb];
        short8v bh1 = *(const short8v*)&W2a_hi[fb + 512];
        short8v bl0 = *(const short8v*)&W2a_lo[fb];
        short8v bl1 = *(const short8v*)&W2a_lo[fb + 512];
#pragma unroll
        for (int mt = 0; mt < 2; ++mt) {
            short8v ah = *(short8v*)&A_hi[(mt * 16 + cl) * 136 + kof];
            short8v al = *(short8v*)&A_lo[(mt * 16 + cl) * 136 + kof];
            acc[mt][0] = MFMA_BF16(ah, bh0, acc[mt][0], 0, 0, 0);
            acc[mt][0] = MFMA_BF16(al, bh0, acc[mt][0], 0, 0, 0);
            acc[mt][0] = MFMA_BF16(ah, bl0, acc[mt][0], 0, 0, 0);
            acc[mt][1] = MFMA_BF16(ah, bh1, acc[mt][1], 0, 0, 0);
            acc[mt][1] = MFMA_BF16(al, bh1, acc[mt][1], 0, 0, 0);
            acc[mt][1] = MFMA_BF16(ah, bl1, acc[mt][1], 0, 0, 0);
        }
    }
    {
        float bb0 = b2a[row0], bb1 = b2a[row1];
#pragma unroll
        for (int mt = 0; mt < 2; ++mt)
#pragma unroll
            for (int j = 0; j < 4; ++j) {
                int row = mt * 16 + kq * 4 + j;
                float v0 = fmaxf(acc[mt][0][j] + bb0, 0.f);
                float v1 = fmaxf(acc[mt][1][j] + bb1, 0.f);
                ushort h0 = f2bf(v0), h1v = f2bf(v1);
                H_hi[row * 136 + row0] = h0;
                H_lo[row * 136 + row0] = f2bf(v0 - bf2f(h0));
                H_hi[row * 136 + row1] = h1v;
                H_lo[row * 136 + row1] = f2bf(v1 - bf2f(h1v));
            }
    }
    __syncthreads();

#pragma unroll
    for (int mt = 0; mt < 2; ++mt) { acc[mt][0] = f32x4{0.f,0.f,0.f,0.f}; acc[mt][1] = f32x4{0.f,0.f,0.f,0.f}; }
#pragma unroll
    for (int ksl = 0; ksl < 4; ++ksl) {
        int kof = ksl * 32 + kq * 8;
        int fb = ((ksl * 4 + w) * 2) * 512 + l * 8;
        short8v bh0 = *(const short8v*)&W2b_hi[fb];
        short8v bh1 = *(const short8v*)&W2b_hi[fb + 512];
        short8v bl0 = *(const short8v*)&W2b_lo[fb];
        short8v bl1 = *(const short8v*)&W2b_lo[fb + 512];
#pragma unroll
        for (int mt = 0; mt < 2; ++mt) {
            short8v ah = *(short8v*)&H_hi[(mt * 16 + cl) * 136 + kof];
            short8v al = *(short8v*)&H_lo[(mt * 16 + cl) * 136 + kof];
            acc[mt][0] = MFMA_BF16(ah, bh0, acc[mt][0], 0, 0, 0);
            acc[mt][0] = MFMA_BF16(al, bh0, acc[mt][0], 0, 0, 0);
            acc[mt][0] = MFMA_BF16(ah, bl0, acc[mt][0], 0, 0, 0);
            acc[mt][1] = MFMA_BF16(ah, bh1, acc[mt][1], 0, 0, 0);
            acc[mt][1] = MFMA_BF16(al, bh1, acc[mt][1], 0, 0, 0);
            acc[mt][1] = MFMA_BF16(ah, bl1, acc[mt][1], 0, 0, 0);
        }
    }
    __syncthreads();
    float* P = (float*)smem;  // [32][132]
    {
        float c0 = b2b[row0], c1 = b2b[row1];
#pragma unroll
        for (int mt = 0; mt < 2; ++mt)
#pragma unroll
            for (int j = 0; j < 4; ++j) {
                int row = mt * 16 + kq * 4 + j;
                P[row * 132 + row0] = fmaxf(acc[mt][0][j] + c0, 0.f);
                P[row * 132 + row1] = fmaxf(acc[mt][1][j] + c1, 0.f);
            }
    }
    __syncthreads();

    {
        int c = t & 127, half = t >> 7;
        int i0 = half * 16;
        float run = 0.f;
        int cur = batch_s[i0];
        if (cur >= 0) {
            for (int i = i0; i < i0 + 16; ++i) {
                int b = batch_s[i];
                if (b < 0) break;
                if (b != cur) { atomicAdd(&pooled[cur * 128 + c], run); run = 0.f; cur = b; }
                run += P[i * 132 + c];
            }
            atomicAdd(&pooled[cur * 128 + c], run);
        }
    }
}

// ---------------- Readout: relu(pooled@Wm1+bm1)@Wm2+bm2 ----------------

__global__ __launch_bounds__(128) void k_readout(
        const float* __restrict__ pooled, const float* __restrict__ Wm1,
        const float* __restrict__ bm1, const float* __restrict__ Wm2,
        const float* __restrict__ bm2, float* __restrict__ out) {
    __shared__ float row[128];
    __shared__ float red[128];
    int g = blockIdx.x, t = threadIdx.x;
    row[t] = pooled[g * 128 + t];
    __syncthreads();
    float acc = bm1[t];
    for (int c = 0; c < 128; ++c) acc = fmaf(row[c], Wm1[c * 128 + t], acc);
    float term = fmaxf(acc, 0.f) * Wm2[t];
    red[t] = term;
    __syncthreads();
    for (int off = 64; off > 0; off >>= 1) {
        if (t < off) red[t] += red[t + off];
        __syncthreads();
    }
    if (t == 0) out[g] = red[0] + bm2[0];
}

// ---------------- Launch ----------------

extern "C" void kernel_launch(void* const* d_in, const int* in_sizes, int n_in,
                              void* d_out, int out_size, void* d_ws, size_t ws_size,
                              hipStream_t stream) {
    const float* x    = (const float*)d_in[0];
    const int* eidx   = (const int*)d_in[1];
    const float* ea   = (const float*)d_in[2];
    const int* batch  = (const int*)d_in[3];
    const float* We1  = (const float*)d_in[4];
    const float* be1  = (const float*)d_in[5];
    const float* W1a  = (const float*)d_in[6];
    const float* b1a  = (const float*)d_in[7];
    const float* W1b  = (const float*)d_in[8];
    const float* b1b  = (const float*)d_in[9];
    const float* We2  = (const float*)d_in[10];
    const float* be2  = (const float*)d_in[11];
    const float* W2a  = (const float*)d_in[12];
    const float* b2a  = (const float*)d_in[13];
    const float* W2b  = (const float*)d_in[14];
    const float* b2b  = (const float*)d_in[15];
    const float* Wm1  = (const float*)d_in[16];
    const float* bm1  = (const float*)d_in[17];
    const float* Wm2  = (const float*)d_in[18];
    const float* bm2  = (const float*)d_in[19];
    float* out = (float*)d_out;

    const int* src = eidx;
    const int* dst = eidx + NE;

    char* w = (char*)d_ws;
    auto alloc = [&](size_t bytes) { void* p = (void*)w; w += (bytes + 255) & ~(size_t)255; return p; };
    int* row_ptr    = (int*)alloc((NN + 1) * 4);
    int* bhist      = (int*)alloc(256 * 4);
    int* bkt_off    = (int*)alloc(256 * 4);
    int* bkt_cursor = (int*)alloc(256 * 4);
    uint2* csr      = (uint2*)alloc((size_t)NE * 8);
    uint2* tmp      = (uint2*)alloc((size_t)NE * 8);
    float* agg1     = (float*)alloc((size_t)NN * 32 * 4);
    ushort* h1b     = (ushort*)alloc((size_t)NN * 128 * 2);
    float* agg2     = (float*)alloc((size_t)NN * 128 * 4);
    float* pooled   = (float*)alloc((size_t)NG * 128 * 4);
    ushort* xb      = (ushort*)alloc((size_t)NN * 32 * 2);
    ushort* W1a_hi  = (ushort*)alloc(4096 * 2);
    ushort* W1a_lo  = (ushort*)alloc(4096 * 2);
    ushort* W1b_hi  = (ushort*)alloc(16384 * 2);
    ushort* W1b_lo  = (ushort*)alloc(16384 * 2);
    ushort* W2a_hi  = (ushort*)alloc(16384 * 2);
    ushort* W2a_lo  = (ushort*)alloc(16384 * 2);
    ushort* W2b_hi  = (ushort*)alloc(16384 * 2);
    ushort* W2b_lo  = (ushort*)alloc(16384 * 2);

    hipMemsetAsync(bhist, 0, 256 * 4, stream);
    hipMemsetAsync(pooled, 0, (size_t)NG * 128 * 4, stream);

    const int MB = (NN + 31) / 32;         // 3125

    k_prep<<<208, 256, 0, stream>>>(W1a, W1b, W2a, W2b,
                                    W1a_hi, W1a_lo, W1b_hi, W1b_lo,
                                    W2a_hi, W2a_lo, W2b_hi, W2b_lo);
    k_xcast<<<3125, 256, 0, stream>>>(x, xb);
    k_bhist<<<BINBLKS, 256, 0, stream>>>(dst, bhist);
    k_bscan<<<1, 256, 0, stream>>>(bhist, bkt_off, bkt_cursor);
    k_binfill<<<BINBLKS, 256, 0, stream>>>(src, dst, ea, bkt_cursor, tmp);
    k_scatter<<<NBKT, 256, 0, stream>>>(tmp, bkt_off, row_ptr, csr);

    k_agg1<<<NN / 8, 256, 0, stream>>>(xb, csr, row_ptr, We1, be1, agg1);
    k_mlp1<<<MB, 256, 0, stream>>>(x, agg1, W1a_hi, W1a_lo, b1a, W1b_hi, W1b_lo, b1b, h1b);
    k_agg2<<<NN / 4, 256, 0, stream>>>(h1b, csr, row_ptr, We2, be2, agg2);
    k_mlp2<<<MB, 256, 0, stream>>>(h1b, agg2, W2a_hi, W2a_lo, b2a, W2b_hi, W2b_lo, b2b, batch, pooled);
    k_readout<<<NG, 128, 0, stream>>>(pooled, Wm1, bm1, Wm2, bm2, out);
}